// Round 1
// baseline (11228.265 us; speedup 1.0000x reference)
//
#include <hip/hip_runtime.h>

#define NT 256
static inline int nb(int n) { return (n + NT - 1) / NT; }

// ---- degree histogram over dst (self-loop +1 added later) ----
__global__ __launch_bounds__(NT) void k_deg(const int* __restrict__ dst,
                                            float* __restrict__ deg, int E) {
    int e = blockIdx.x * NT + threadIdx.x;
    if (e < E) atomicAdd(&deg[dst[e]], 1.0f);
}

// ---- dis = rsqrt(deg + 1) (self-loop makes deg >= 1) ----
__global__ __launch_bounds__(NT) void k_dis(float* __restrict__ dis, int N) {
    int n = blockIdx.x * NT + threadIdx.x;
    if (n < N) dis[n] = rsqrtf(dis[n] + 1.0f);
}

// ---- layer 0 per-node: tmp = x@W0 ; acc = tmp*dis^2 (self-loop term) ----
__global__ __launch_bounds__(NT) void k_node0(const float* __restrict__ x,
                                              const float* __restrict__ W,
                                              const float* __restrict__ dis,
                                              float* __restrict__ tmp,
                                              float* __restrict__ acc, int N) {
    int n = blockIdx.x * NT + threadIdx.x;
    if (n >= N) return;
    float x0 = x[2 * n], x1 = x[2 * n + 1];
    float di = dis[n], w2 = di * di;
#pragma unroll
    for (int f = 0; f < 8; ++f) {
        float t = x0 * W[f] + x1 * W[8 + f];
        tmp[8 * n + f] = t;
        acc[8 * n + f] = t * w2;
    }
}

// ---- edge scatter, 8-wide features ----
__global__ __launch_bounds__(NT) void k_scatter8(const int* __restrict__ src,
                                                 const int* __restrict__ dst,
                                                 const float* __restrict__ dis,
                                                 const float* __restrict__ tmp,
                                                 float* __restrict__ acc, int E) {
    int e = blockIdx.x * NT + threadIdx.x;
    if (e >= E) return;
    int s = src[e], d = dst[e];
    float w = dis[s] * dis[d];
    const float4* tp = reinterpret_cast<const float4*>(tmp + 8 * s);
    float4 t0 = tp[0], t1 = tp[1];
    float* o = acc + 8 * d;
    atomicAdd(o + 0, t0.x * w);
    atomicAdd(o + 1, t0.y * w);
    atomicAdd(o + 2, t0.z * w);
    atomicAdd(o + 3, t0.w * w);
    atomicAdd(o + 4, t1.x * w);
    atomicAdd(o + 5, t1.y * w);
    atomicAdd(o + 6, t1.z * w);
    atomicAdd(o + 7, t1.w * w);
}

// ---- mid layers per-node: h = elu(acc + b_prev); tmp = h@W; acc = tmp*dis^2 ----
__global__ __launch_bounds__(NT) void k_nodemid(const float* __restrict__ b_prev,
                                                const float* __restrict__ W,
                                                const float* __restrict__ dis,
                                                float* __restrict__ tmp,
                                                float* __restrict__ acc, int N) {
    int n = blockIdx.x * NT + threadIdx.x;
    if (n >= N) return;
    float h[8];
#pragma unroll
    for (int f = 0; f < 8; ++f) {
        float v = acc[8 * n + f] + b_prev[f];
        h[f] = v > 0.0f ? v : expm1f(v);
    }
    float di = dis[n], w2 = di * di;
#pragma unroll
    for (int fo = 0; fo < 8; ++fo) {
        float t = 0.0f;
#pragma unroll
        for (int fi = 0; fi < 8; ++fi) t += h[fi] * W[8 * fi + fo];
        tmp[8 * n + fo] = t;
        acc[8 * n + fo] = t * w2;
    }
}

// ---- head per-node: h = elu(acc + b3); tmpH = [h.Wv, h.Wp]; accH = tmpH*dis^2 ----
__global__ __launch_bounds__(NT) void k_nodeH(const float* __restrict__ b3,
                                              const float* __restrict__ Wv,
                                              const float* __restrict__ Wp,
                                              const float* __restrict__ dis,
                                              const float* __restrict__ acc,
                                              float* __restrict__ tmpH,
                                              float* __restrict__ accH, int N) {
    int n = blockIdx.x * NT + threadIdx.x;
    if (n >= N) return;
    float tv = 0.0f, tp = 0.0f;
#pragma unroll
    for (int f = 0; f < 8; ++f) {
        float v = acc[8 * n + f] + b3[f];
        float h = v > 0.0f ? v : expm1f(v);
        tv += h * Wv[f];
        tp += h * Wp[f];
    }
    float di = dis[n], w2 = di * di;
    tmpH[2 * n + 0] = tv;
    tmpH[2 * n + 1] = tp;
    accH[2 * n + 0] = tv * w2;
    accH[2 * n + 1] = tp * w2;
}

// ---- edge scatter, 2-wide (value+policy heads together) ----
__global__ __launch_bounds__(NT) void k_scatter2(const int* __restrict__ src,
                                                 const int* __restrict__ dst,
                                                 const float* __restrict__ dis,
                                                 const float* __restrict__ tmpH,
                                                 float* __restrict__ accH, int E) {
    int e = blockIdx.x * NT + threadIdx.x;
    if (e >= E) return;
    int s = src[e], d = dst[e];
    float w = dis[s] * dis[d];
    const float2* tp = reinterpret_cast<const float2*>(tmpH + 2 * s);
    float2 t = tp[0];
    atomicAdd(accH + 2 * d + 0, t.x * w);
    atomicAdd(accH + 2 * d + 1, t.y * w);
}

// ---- head output: proba to d_out, block-reduce value sum ----
__global__ __launch_bounds__(NT) void k_head(const float* __restrict__ accH,
                                             const float* __restrict__ bp,
                                             float* __restrict__ out,
                                             float* __restrict__ vsum, int N) {
    int n = blockIdx.x * NT + threadIdx.x;
    float v = 0.0f;
    if (n < N) {
        out[n] = accH[2 * n + 1] + bp[0];
        v = accH[2 * n + 0];
    }
#pragma unroll
    for (int o = 32; o > 0; o >>= 1) v += __shfl_down(v, o, 64);
    __shared__ float s[NT / 64];
    if ((threadIdx.x & 63) == 0) s[threadIdx.x >> 6] = v;
    __syncthreads();
    if (threadIdx.x == 0) {
        float b = 0.0f;
#pragma unroll
        for (int i = 0; i < NT / 64; ++i) b += s[i];
        atomicAdd(vsum, b);
    }
}

__global__ void k_final(const float* __restrict__ vsum,
                        const float* __restrict__ bv,
                        float* __restrict__ out, int N) {
    out[0] = vsum[0] * (1.0f / (float)N) + bv[0];
}

extern "C" void kernel_launch(void* const* d_in, const int* in_sizes, int n_in,
                              void* d_out, int out_size, void* d_ws, size_t ws_size,
                              hipStream_t stream) {
    const float* x  = (const float*)d_in[0];
    const int* ei   = (const int*)d_in[1];
    const float* W0 = (const float*)d_in[2];
    const float* b0 = (const float*)d_in[3];
    const float* W1 = (const float*)d_in[4];
    const float* b1 = (const float*)d_in[5];
    const float* W2 = (const float*)d_in[6];
    const float* b2 = (const float*)d_in[7];
    const float* W3 = (const float*)d_in[8];
    const float* b3 = (const float*)d_in[9];
    const float* Wv = (const float*)d_in[10];
    const float* bv = (const float*)d_in[11];
    const float* Wp = (const float*)d_in[12];
    const float* bp = (const float*)d_in[13];
    float* out = (float*)d_out;

    int N = in_sizes[0] / 2;
    int E = in_sizes[1] / 2;
    const int* src = ei;
    const int* dst = ei + E;

    float* ws   = (float*)d_ws;
    float* dis  = ws;                 // N
    float* vsum = ws + N;             // 1 (+7 pad)
    float* tmp  = ws + N + 8;         // 8N
    float* acc  = tmp + (size_t)8 * N; // 8N
    float* tmpH = acc + (size_t)8 * N; // 2N
    float* accH = tmpH + (size_t)2 * N; // 2N

    hipMemsetAsync(ws, 0, (size_t)(N + 8) * sizeof(float), stream);

    k_deg<<<nb(E), NT, 0, stream>>>(dst, dis, E);
    k_dis<<<nb(N), NT, 0, stream>>>(dis, N);

    // layer 0
    k_node0<<<nb(N), NT, 0, stream>>>(x, W0, dis, tmp, acc, N);
    k_scatter8<<<nb(E), NT, 0, stream>>>(src, dst, dis, tmp, acc, E);
    // layer 1
    k_nodemid<<<nb(N), NT, 0, stream>>>(b0, W1, dis, tmp, acc, N);
    k_scatter8<<<nb(E), NT, 0, stream>>>(src, dst, dis, tmp, acc, E);
    // layer 2
    k_nodemid<<<nb(N), NT, 0, stream>>>(b1, W2, dis, tmp, acc, N);
    k_scatter8<<<nb(E), NT, 0, stream>>>(src, dst, dis, tmp, acc, E);
    // layer 3
    k_nodemid<<<nb(N), NT, 0, stream>>>(b2, W3, dis, tmp, acc, N);
    k_scatter8<<<nb(E), NT, 0, stream>>>(src, dst, dis, tmp, acc, E);
    // heads (value + policy share one 2-wide edge pass)
    k_nodeH<<<nb(N), NT, 0, stream>>>(b3, Wv, Wp, dis, acc, tmpH, accH, N);
    k_scatter2<<<nb(E), NT, 0, stream>>>(src, dst, dis, tmpH, accH, E);
    k_head<<<nb(N), NT, 0, stream>>>(accH, bp, out, vsum, N);
    k_final<<<1, 1, 0, stream>>>(vsum, bv, out + N, N);
}

// Round 2
// 991.653 us; speedup vs baseline: 11.3228x; 11.3228x over previous
//
#include <hip/hip_runtime.h>

#define NT 256
#define CHUNK 1024

static inline int nbi(long long n) { return (int)((n + NT - 1) / NT); }

// ============================ CSR-gather path ============================

__global__ __launch_bounds__(NT) void k_count(const int* __restrict__ dst,
                                              int* __restrict__ deg, int E) {
    int e = blockIdx.x * NT + threadIdx.x;
    if (e < E) atomicAdd(&deg[dst[e]], 1);
}

__global__ __launch_bounds__(NT) void k_scanA(const int* __restrict__ deg,
                                              int* __restrict__ partial, int N) {
    int t = threadIdx.x;
    int base = blockIdx.x * CHUNK + t * 4;
    int s = 0;
#pragma unroll
    for (int j = 0; j < 4; ++j) { int i = base + j; if (i < N) s += deg[i]; }
    __shared__ int red[NT];
    red[t] = s; __syncthreads();
    for (int o = NT / 2; o > 0; o >>= 1) {
        if (t < o) red[t] += red[t + o];
        __syncthreads();
    }
    if (t == 0) partial[blockIdx.x] = red[0];
}

__global__ void k_scanB(const int* __restrict__ partial, int* __restrict__ chunkoff,
                        int* __restrict__ rowst, int nblk, int N) {
    if (threadIdx.x == 0) {
        int off = 0;
        for (int b = 0; b < nblk; ++b) { chunkoff[b] = off; off += partial[b]; }
        rowst[N] = off; // == E
    }
}

__global__ __launch_bounds__(NT) void k_scanC(const int* __restrict__ deg,
                                              const int* __restrict__ chunkoff,
                                              int* __restrict__ rowst,
                                              float* __restrict__ dis, int N) {
    int t = threadIdx.x;
    int base = blockIdx.x * CHUNK + t * 4;
    int v[4]; int tsum = 0;
#pragma unroll
    for (int j = 0; j < 4; ++j) { int i = base + j; v[j] = (i < N) ? deg[i] : 0; tsum += v[j]; }
    __shared__ int ss[NT];
    ss[t] = tsum; __syncthreads();
    for (int o = 1; o < NT; o <<= 1) {
        int x = (t >= o) ? ss[t - o] : 0;
        __syncthreads();
        ss[t] += x;
        __syncthreads();
    }
    int run = ss[t] - tsum + chunkoff[blockIdx.x];
#pragma unroll
    for (int j = 0; j < 4; ++j) {
        int i = base + j;
        if (i < N) { rowst[i] = run; dis[i] = rsqrtf((float)v[j] + 1.0f); run += v[j]; }
    }
}

__global__ __launch_bounds__(NT) void k_fill(const int* __restrict__ src,
                                             const int* __restrict__ dst,
                                             const int* __restrict__ rowst,
                                             int* __restrict__ deg,
                                             int* __restrict__ csr, int E) {
    int e = blockIdx.x * NT + threadIdx.x;
    if (e >= E) return;
    int s = src[e], d = dst[e];
    int old = atomicSub(&deg[d], 1);
    csr[rowst[d] + old - 1] = s;
}

// u0 = dis * (x @ W0)
__global__ __launch_bounds__(NT) void k_node0n(const float* __restrict__ x,
                                               const float* __restrict__ W,
                                               const float* __restrict__ dis,
                                               float* __restrict__ u, int N) {
    int n = blockIdx.x * NT + threadIdx.x;
    if (n >= N) return;
    float x0 = x[2 * n], x1 = x[2 * n + 1];
    float dn = dis[n];
    float o[8];
#pragma unroll
    for (int f = 0; f < 8; ++f) o[f] = dn * (x0 * W[f] + x1 * W[8 + f]);
    float4* up = reinterpret_cast<float4*>(u + 8 * n);
    up[0] = make_float4(o[0], o[1], o[2], o[3]);
    up[1] = make_float4(o[4], o[5], o[6], o[7]);
}

// gather (4 lanes/node) + fused next layer: g = dis*(sum u[src] + u[self]);
// h = elu(g + b); u_next = dis * (h @ W)
__global__ __launch_bounds__(NT) void k_gather_layer(const int* __restrict__ rowst,
                                                     const int* __restrict__ csr,
                                                     const float* __restrict__ dis,
                                                     const float* __restrict__ u,
                                                     const float* __restrict__ b,
                                                     const float* __restrict__ W,
                                                     float* __restrict__ un, int N) {
    int g = blockIdx.x * NT + threadIdx.x;
    int n = g >> 2, sub = g & 3;
    if (n >= N) return;
    int i = rowst[n] + sub, end = rowst[n + 1];
    float a[8];
#pragma unroll
    for (int k = 0; k < 8; ++k) a[k] = 0.0f;
    for (; i + 4 < end; i += 8) {
        int s0 = csr[i], s1 = csr[i + 4];
        float4 p0 = *reinterpret_cast<const float4*>(u + 8 * s0);
        float4 p1 = *reinterpret_cast<const float4*>(u + 8 * s0 + 4);
        float4 q0 = *reinterpret_cast<const float4*>(u + 8 * s1);
        float4 q1 = *reinterpret_cast<const float4*>(u + 8 * s1 + 4);
        a[0] += p0.x + q0.x; a[1] += p0.y + q0.y;
        a[2] += p0.z + q0.z; a[3] += p0.w + q0.w;
        a[4] += p1.x + q1.x; a[5] += p1.y + q1.y;
        a[6] += p1.z + q1.z; a[7] += p1.w + q1.w;
    }
    if (i < end) {
        int s0 = csr[i];
        float4 p0 = *reinterpret_cast<const float4*>(u + 8 * s0);
        float4 p1 = *reinterpret_cast<const float4*>(u + 8 * s0 + 4);
        a[0] += p0.x; a[1] += p0.y; a[2] += p0.z; a[3] += p0.w;
        a[4] += p1.x; a[5] += p1.y; a[6] += p1.z; a[7] += p1.w;
    }
#pragma unroll
    for (int k = 0; k < 8; ++k) {
        a[k] += __shfl_xor(a[k], 1, 64);
        a[k] += __shfl_xor(a[k], 2, 64);
    }
    if (sub == 0) {
        float4 s0v = *reinterpret_cast<const float4*>(u + 8 * n);
        float4 s1v = *reinterpret_cast<const float4*>(u + 8 * n + 4);
        a[0] += s0v.x; a[1] += s0v.y; a[2] += s0v.z; a[3] += s0v.w;
        a[4] += s1v.x; a[5] += s1v.y; a[6] += s1v.z; a[7] += s1v.w;
        float dn = dis[n];
        float h[8];
#pragma unroll
        for (int f = 0; f < 8; ++f) {
            float gg = a[f] * dn + b[f];
            h[f] = gg > 0.0f ? gg : expm1f(gg);
        }
        float o[8];
#pragma unroll
        for (int fo = 0; fo < 8; ++fo) {
            float t = 0.0f;
#pragma unroll
            for (int fi = 0; fi < 8; ++fi) t += h[fi] * W[fi * 8 + fo];
            o[fo] = dn * t;
        }
        float4* up = reinterpret_cast<float4*>(un + 8 * n);
        up[0] = make_float4(o[0], o[1], o[2], o[3]);
        up[1] = make_float4(o[4], o[5], o[6], o[7]);
    }
}

// gather + fused head: h = elu(g + b3); uH = dis * [h.Wv, h.Wp]
__global__ __launch_bounds__(NT) void k_gather_head(const int* __restrict__ rowst,
                                                    const int* __restrict__ csr,
                                                    const float* __restrict__ dis,
                                                    const float* __restrict__ u,
                                                    const float* __restrict__ b,
                                                    const float* __restrict__ Wv,
                                                    const float* __restrict__ Wp,
                                                    float* __restrict__ uH, int N) {
    int g = blockIdx.x * NT + threadIdx.x;
    int n = g >> 2, sub = g & 3;
    if (n >= N) return;
    int i = rowst[n] + sub, end = rowst[n + 1];
    float a[8];
#pragma unroll
    for (int k = 0; k < 8; ++k) a[k] = 0.0f;
    for (; i + 4 < end; i += 8) {
        int s0 = csr[i], s1 = csr[i + 4];
        float4 p0 = *reinterpret_cast<const float4*>(u + 8 * s0);
        float4 p1 = *reinterpret_cast<const float4*>(u + 8 * s0 + 4);
        float4 q0 = *reinterpret_cast<const float4*>(u + 8 * s1);
        float4 q1 = *reinterpret_cast<const float4*>(u + 8 * s1 + 4);
        a[0] += p0.x + q0.x; a[1] += p0.y + q0.y;
        a[2] += p0.z + q0.z; a[3] += p0.w + q0.w;
        a[4] += p1.x + q1.x; a[5] += p1.y + q1.y;
        a[6] += p1.z + q1.z; a[7] += p1.w + q1.w;
    }
    if (i < end) {
        int s0 = csr[i];
        float4 p0 = *reinterpret_cast<const float4*>(u + 8 * s0);
        float4 p1 = *reinterpret_cast<const float4*>(u + 8 * s0 + 4);
        a[0] += p0.x; a[1] += p0.y; a[2] += p0.z; a[3] += p0.w;
        a[4] += p1.x; a[5] += p1.y; a[6] += p1.z; a[7] += p1.w;
    }
#pragma unroll
    for (int k = 0; k < 8; ++k) {
        a[k] += __shfl_xor(a[k], 1, 64);
        a[k] += __shfl_xor(a[k], 2, 64);
    }
    if (sub == 0) {
        float4 s0v = *reinterpret_cast<const float4*>(u + 8 * n);
        float4 s1v = *reinterpret_cast<const float4*>(u + 8 * n + 4);
        a[0] += s0v.x; a[1] += s0v.y; a[2] += s0v.z; a[3] += s0v.w;
        a[4] += s1v.x; a[5] += s1v.y; a[6] += s1v.z; a[7] += s1v.w;
        float dn = dis[n];
        float tv = 0.0f, tp = 0.0f;
#pragma unroll
        for (int f = 0; f < 8; ++f) {
            float gg = a[f] * dn + b[f];
            float h = gg > 0.0f ? gg : expm1f(gg);
            tv += h * Wv[f];
            tp += h * Wp[f];
        }
        *reinterpret_cast<float2*>(uH + 2 * n) = make_float2(dn * tv, dn * tp);
    }
}

// final 2-wide gather: proba out + value block-reduce
__global__ __launch_bounds__(NT) void k_gather2n(const int* __restrict__ rowst,
                                                 const int* __restrict__ csr,
                                                 const float* __restrict__ dis,
                                                 const float* __restrict__ uH,
                                                 const float* __restrict__ bp,
                                                 float* __restrict__ out,
                                                 float* __restrict__ vsum, int N) {
    int g = blockIdx.x * NT + threadIdx.x;
    int n = g >> 2, sub = g & 3;
    bool valid = n < N;
    int i = 0, end = 0;
    if (valid) { i = rowst[n] + sub; end = rowst[n + 1]; }
    float av = 0.0f, ap = 0.0f;
    for (; i + 4 < end; i += 8) {
        int s0 = csr[i], s1 = csr[i + 4];
        float2 p = *reinterpret_cast<const float2*>(uH + 2 * s0);
        float2 q = *reinterpret_cast<const float2*>(uH + 2 * s1);
        av += p.x + q.x; ap += p.y + q.y;
    }
    if (i < end) {
        int s0 = csr[i];
        float2 p = *reinterpret_cast<const float2*>(uH + 2 * s0);
        av += p.x; ap += p.y;
    }
    av += __shfl_xor(av, 1, 64); av += __shfl_xor(av, 2, 64);
    ap += __shfl_xor(ap, 1, 64); ap += __shfl_xor(ap, 2, 64);
    float contrib = 0.0f;
    if (valid && sub == 0) {
        float2 selfv = *reinterpret_cast<const float2*>(uH + 2 * n);
        av += selfv.x; ap += selfv.y;
        float dn = dis[n];
        out[n] = ap * dn + bp[0];
        contrib = av * dn;
    }
#pragma unroll
    for (int o = 32; o > 0; o >>= 1) contrib += __shfl_down(contrib, o, 64);
    __shared__ float sred[NT / 64];
    if ((threadIdx.x & 63) == 0) sred[threadIdx.x >> 6] = contrib;
    __syncthreads();
    if (threadIdx.x == 0) {
        float bsum = 0.0f;
#pragma unroll
        for (int k = 0; k < NT / 64; ++k) bsum += sred[k];
        atomicAdd(vsum, bsum);
    }
}

__global__ void k_final(const float* __restrict__ vsum,
                        const float* __restrict__ bv,
                        float* __restrict__ out, int N) {
    out[0] = vsum[0] * (1.0f / (float)N) + bv[0];
}

// ===================== fallback (round-1 atomic path) =====================

__global__ __launch_bounds__(NT) void k_deg(const int* __restrict__ dst,
                                            float* __restrict__ deg, int E) {
    int e = blockIdx.x * NT + threadIdx.x;
    if (e < E) atomicAdd(&deg[dst[e]], 1.0f);
}

__global__ __launch_bounds__(NT) void k_dis(float* __restrict__ dis, int N) {
    int n = blockIdx.x * NT + threadIdx.x;
    if (n < N) dis[n] = rsqrtf(dis[n] + 1.0f);
}

__global__ __launch_bounds__(NT) void k_node0(const float* __restrict__ x,
                                              const float* __restrict__ W,
                                              const float* __restrict__ dis,
                                              float* __restrict__ tmp,
                                              float* __restrict__ acc, int N) {
    int n = blockIdx.x * NT + threadIdx.x;
    if (n >= N) return;
    float x0 = x[2 * n], x1 = x[2 * n + 1];
    float di = dis[n], w2 = di * di;
#pragma unroll
    for (int f = 0; f < 8; ++f) {
        float t = x0 * W[f] + x1 * W[8 + f];
        tmp[8 * n + f] = t;
        acc[8 * n + f] = t * w2;
    }
}

__global__ __launch_bounds__(NT) void k_scatter8(const int* __restrict__ src,
                                                 const int* __restrict__ dst,
                                                 const float* __restrict__ dis,
                                                 const float* __restrict__ tmp,
                                                 float* __restrict__ acc, int E) {
    int e = blockIdx.x * NT + threadIdx.x;
    if (e >= E) return;
    int s = src[e], d = dst[e];
    float w = dis[s] * dis[d];
    const float4* tp = reinterpret_cast<const float4*>(tmp + 8 * s);
    float4 t0 = tp[0], t1 = tp[1];
    float* o = acc + 8 * d;
    atomicAdd(o + 0, t0.x * w); atomicAdd(o + 1, t0.y * w);
    atomicAdd(o + 2, t0.z * w); atomicAdd(o + 3, t0.w * w);
    atomicAdd(o + 4, t1.x * w); atomicAdd(o + 5, t1.y * w);
    atomicAdd(o + 6, t1.z * w); atomicAdd(o + 7, t1.w * w);
}

__global__ __launch_bounds__(NT) void k_nodemid(const float* __restrict__ b_prev,
                                                const float* __restrict__ W,
                                                const float* __restrict__ dis,
                                                float* __restrict__ tmp,
                                                float* __restrict__ acc, int N) {
    int n = blockIdx.x * NT + threadIdx.x;
    if (n >= N) return;
    float h[8];
#pragma unroll
    for (int f = 0; f < 8; ++f) {
        float v = acc[8 * n + f] + b_prev[f];
        h[f] = v > 0.0f ? v : expm1f(v);
    }
    float di = dis[n], w2 = di * di;
#pragma unroll
    for (int fo = 0; fo < 8; ++fo) {
        float t = 0.0f;
#pragma unroll
        for (int fi = 0; fi < 8; ++fi) t += h[fi] * W[8 * fi + fo];
        tmp[8 * n + fo] = t;
        acc[8 * n + fo] = t * w2;
    }
}

__global__ __launch_bounds__(NT) void k_nodeH(const float* __restrict__ b3,
                                              const float* __restrict__ Wv,
                                              const float* __restrict__ Wp,
                                              const float* __restrict__ dis,
                                              const float* __restrict__ acc,
                                              float* __restrict__ tmpH,
                                              float* __restrict__ accH, int N) {
    int n = blockIdx.x * NT + threadIdx.x;
    if (n >= N) return;
    float tv = 0.0f, tp = 0.0f;
#pragma unroll
    for (int f = 0; f < 8; ++f) {
        float v = acc[8 * n + f] + b3[f];
        float h = v > 0.0f ? v : expm1f(v);
        tv += h * Wv[f];
        tp += h * Wp[f];
    }
    float di = dis[n], w2 = di * di;
    tmpH[2 * n + 0] = tv; tmpH[2 * n + 1] = tp;
    accH[2 * n + 0] = tv * w2; accH[2 * n + 1] = tp * w2;
}

__global__ __launch_bounds__(NT) void k_scatter2(const int* __restrict__ src,
                                                 const int* __restrict__ dst,
                                                 const float* __restrict__ dis,
                                                 const float* __restrict__ tmpH,
                                                 float* __restrict__ accH, int E) {
    int e = blockIdx.x * NT + threadIdx.x;
    if (e >= E) return;
    int s = src[e], d = dst[e];
    float w = dis[s] * dis[d];
    float2 t = *reinterpret_cast<const float2*>(tmpH + 2 * s);
    atomicAdd(accH + 2 * d + 0, t.x * w);
    atomicAdd(accH + 2 * d + 1, t.y * w);
}

__global__ __launch_bounds__(NT) void k_head(const float* __restrict__ accH,
                                             const float* __restrict__ bp,
                                             float* __restrict__ out,
                                             float* __restrict__ vsum, int N) {
    int n = blockIdx.x * NT + threadIdx.x;
    float v = 0.0f;
    if (n < N) {
        out[n] = accH[2 * n + 1] + bp[0];
        v = accH[2 * n + 0];
    }
#pragma unroll
    for (int o = 32; o > 0; o >>= 1) v += __shfl_down(v, o, 64);
    __shared__ float s[NT / 64];
    if ((threadIdx.x & 63) == 0) s[threadIdx.x >> 6] = v;
    __syncthreads();
    if (threadIdx.x == 0) {
        float b = 0.0f;
#pragma unroll
        for (int k = 0; k < NT / 64; ++k) b += s[k];
        atomicAdd(vsum, b);
    }
}

// ================================ launch ================================

extern "C" void kernel_launch(void* const* d_in, const int* in_sizes, int n_in,
                              void* d_out, int out_size, void* d_ws, size_t ws_size,
                              hipStream_t stream) {
    const float* x  = (const float*)d_in[0];
    const int* ei   = (const int*)d_in[1];
    const float* W0 = (const float*)d_in[2];
    const float* b0 = (const float*)d_in[3];
    const float* W1 = (const float*)d_in[4];
    const float* b1 = (const float*)d_in[5];
    const float* W2 = (const float*)d_in[6];
    const float* b2 = (const float*)d_in[7];
    const float* W3 = (const float*)d_in[8];
    const float* b3 = (const float*)d_in[9];
    const float* Wv = (const float*)d_in[10];
    const float* bv = (const float*)d_in[11];
    const float* Wp = (const float*)d_in[12];
    const float* bp = (const float*)d_in[13];
    float* out = (float*)d_out;

    int N = in_sizes[0] / 2;
    int E = in_sizes[1] / 2;
    const int* src = ei;
    const int* dst = ei + E;
    int nblk = (N + CHUNK - 1) / CHUNK;

    size_t needA = ((size_t)19 * N + (size_t)E + 2 * (size_t)nblk + 32) * 4;

    if (ws_size >= needA) {
        int* deg      = (int*)d_ws;                 // N
        int* rowst    = deg + N;                    // N+1
        int* chunkoff = rowst + N + 1;              // nblk
        int* partial  = chunkoff + nblk;            // nblk
        float* dis    = (float*)(partial + nblk);   // N
        float* vsum   = dis + N;                    // 8 (1 used)
        float* uA     = vsum + 8;                   // 8N
        float* uB     = uA + (size_t)8 * N;         // 8N
        int* csr      = (int*)(uB + (size_t)8 * N); // E

        hipMemsetAsync(deg, 0, (size_t)N * 4, stream);
        hipMemsetAsync(vsum, 0, 4, stream);

        k_count<<<nbi(E), NT, 0, stream>>>(dst, deg, E);
        k_scanA<<<nblk, NT, 0, stream>>>(deg, partial, N);
        k_scanB<<<1, 64, 0, stream>>>(partial, chunkoff, rowst, nblk, N);
        k_scanC<<<nblk, NT, 0, stream>>>(deg, chunkoff, rowst, dis, N);
        k_fill<<<nbi(E), NT, 0, stream>>>(src, dst, rowst, deg, csr, E);

        k_node0n<<<nbi(N), NT, 0, stream>>>(x, W0, dis, uA, N);
        k_gather_layer<<<nbi(4LL * N), NT, 0, stream>>>(rowst, csr, dis, uA, b0, W1, uB, N);
        k_gather_layer<<<nbi(4LL * N), NT, 0, stream>>>(rowst, csr, dis, uB, b1, W2, uA, N);
        k_gather_layer<<<nbi(4LL * N), NT, 0, stream>>>(rowst, csr, dis, uA, b2, W3, uB, N);
        k_gather_head<<<nbi(4LL * N), NT, 0, stream>>>(rowst, csr, dis, uB, b3, Wv, Wp, uA, N);
        k_gather2n<<<nbi(4LL * N), NT, 0, stream>>>(rowst, csr, dis, uA, bp, out, vsum, N);
        k_final<<<1, 1, 0, stream>>>(vsum, bv, out + N, N);
    } else {
        // fallback: round-1 atomic-scatter path (needs (21N+8)*4 bytes)
        float* ws   = (float*)d_ws;
        float* dis  = ws;
        float* vsum = ws + N;
        float* tmp  = ws + N + 8;
        float* acc  = tmp + (size_t)8 * N;
        float* tmpH = acc + (size_t)8 * N;
        float* accH = tmpH + (size_t)2 * N;

        hipMemsetAsync(ws, 0, (size_t)(N + 8) * sizeof(float), stream);

        k_deg<<<nbi(E), NT, 0, stream>>>(dst, dis, E);
        k_dis<<<nbi(N), NT, 0, stream>>>(dis, N);
        k_node0<<<nbi(N), NT, 0, stream>>>(x, W0, dis, tmp, acc, N);
        k_scatter8<<<nbi(E), NT, 0, stream>>>(src, dst, dis, tmp, acc, E);
        k_nodemid<<<nbi(N), NT, 0, stream>>>(b0, W1, dis, tmp, acc, N);
        k_scatter8<<<nbi(E), NT, 0, stream>>>(src, dst, dis, tmp, acc, E);
        k_nodemid<<<nbi(N), NT, 0, stream>>>(b1, W2, dis, tmp, acc, N);
        k_scatter8<<<nbi(E), NT, 0, stream>>>(src, dst, dis, tmp, acc, E);
        k_nodemid<<<nbi(N), NT, 0, stream>>>(b2, W3, dis, tmp, acc, N);
        k_scatter8<<<nbi(E), NT, 0, stream>>>(src, dst, dis, tmp, acc, E);
        k_nodeH<<<nbi(N), NT, 0, stream>>>(b3, Wv, Wp, dis, acc, tmpH, accH, N);
        k_scatter2<<<nbi(E), NT, 0, stream>>>(src, dst, dis, tmpH, accH, E);
        k_head<<<nbi(N), NT, 0, stream>>>(accH, bp, out, vsum, N);
        k_final<<<1, 1, 0, stream>>>(vsum, bv, out + N, N);
    }
}

// Round 3
// 823.161 us; speedup vs baseline: 13.6404x; 1.2047x over previous
//
#include <hip/hip_runtime.h>

#define NT 256
#define STRIDE 128
#define CHUNK 1024

static inline int nbi(long long n) { return (int)((n + NT - 1) / NT); }

// ======================= stride-CSR path (primary) =======================

// one-pass CSR build: slot = atomicAdd(cnt[d]), csr[d*STRIDE+slot] = src
__global__ __launch_bounds__(NT) void k_fillS(const int* __restrict__ src,
                                              const int* __restrict__ dst,
                                              int* __restrict__ cnt,
                                              int* __restrict__ csr, int E) {
    int e = blockIdx.x * NT + threadIdx.x;
    if (e >= E) return;
    int s = src[e], d = dst[e];
    int slot = atomicAdd(&cnt[d], 1);
    if (slot < STRIDE) csr[(size_t)d * STRIDE + slot] = s;
}

// per-node: dis = rsqrt(cnt+1); u0 = dis * (x @ W0)
__global__ __launch_bounds__(NT) void k_prep(const int* __restrict__ cnt,
                                             const float* __restrict__ x,
                                             const float* __restrict__ W,
                                             float* __restrict__ dis,
                                             float* __restrict__ u, int N) {
    int n = blockIdx.x * NT + threadIdx.x;
    if (n >= N) return;
    float dn = rsqrtf((float)cnt[n] + 1.0f);
    dis[n] = dn;
    float x0 = x[2 * n], x1 = x[2 * n + 1];
    float o[8];
#pragma unroll
    for (int f = 0; f < 8; ++f) o[f] = dn * (x0 * W[f] + x1 * W[8 + f]);
    float4* up = reinterpret_cast<float4*>(u + 8 * n);
    up[0] = make_float4(o[0], o[1], o[2], o[3]);
    up[1] = make_float4(o[4], o[5], o[6], o[7]);
}

// gather (4 lanes/node) + fused layer, stride-CSR version
__global__ __launch_bounds__(NT) void k_gatherS_layer(const int* __restrict__ cnt,
                                                      const int* __restrict__ csr,
                                                      const float* __restrict__ dis,
                                                      const float* __restrict__ u,
                                                      const float* __restrict__ b,
                                                      const float* __restrict__ W,
                                                      float* __restrict__ un, int N) {
    int g = blockIdx.x * NT + threadIdx.x;
    int n = g >> 2, sub = g & 3;
    if (n >= N) return;
    int base = n * STRIDE;
    int i = base + sub, end = base + min(cnt[n], STRIDE);
    float a[8];
#pragma unroll
    for (int k = 0; k < 8; ++k) a[k] = 0.0f;
    for (; i + 4 < end; i += 8) {
        int s0 = csr[i], s1 = csr[i + 4];
        float4 p0 = *reinterpret_cast<const float4*>(u + 8 * s0);
        float4 p1 = *reinterpret_cast<const float4*>(u + 8 * s0 + 4);
        float4 q0 = *reinterpret_cast<const float4*>(u + 8 * s1);
        float4 q1 = *reinterpret_cast<const float4*>(u + 8 * s1 + 4);
        a[0] += p0.x + q0.x; a[1] += p0.y + q0.y;
        a[2] += p0.z + q0.z; a[3] += p0.w + q0.w;
        a[4] += p1.x + q1.x; a[5] += p1.y + q1.y;
        a[6] += p1.z + q1.z; a[7] += p1.w + q1.w;
    }
    if (i < end) {
        int s0 = csr[i];
        float4 p0 = *reinterpret_cast<const float4*>(u + 8 * s0);
        float4 p1 = *reinterpret_cast<const float4*>(u + 8 * s0 + 4);
        a[0] += p0.x; a[1] += p0.y; a[2] += p0.z; a[3] += p0.w;
        a[4] += p1.x; a[5] += p1.y; a[6] += p1.z; a[7] += p1.w;
    }
#pragma unroll
    for (int k = 0; k < 8; ++k) {
        a[k] += __shfl_xor(a[k], 1, 64);
        a[k] += __shfl_xor(a[k], 2, 64);
    }
    if (sub == 0) {
        float4 s0v = *reinterpret_cast<const float4*>(u + 8 * n);
        float4 s1v = *reinterpret_cast<const float4*>(u + 8 * n + 4);
        a[0] += s0v.x; a[1] += s0v.y; a[2] += s0v.z; a[3] += s0v.w;
        a[4] += s1v.x; a[5] += s1v.y; a[6] += s1v.z; a[7] += s1v.w;
        float dn = dis[n];
        float h[8];
#pragma unroll
        for (int f = 0; f < 8; ++f) {
            float gg = a[f] * dn + b[f];
            h[f] = gg > 0.0f ? gg : expm1f(gg);
        }
        float o[8];
#pragma unroll
        for (int fo = 0; fo < 8; ++fo) {
            float t = 0.0f;
#pragma unroll
            for (int fi = 0; fi < 8; ++fi) t += h[fi] * W[fi * 8 + fo];
            o[fo] = dn * t;
        }
        float4* up = reinterpret_cast<float4*>(un + 8 * n);
        up[0] = make_float4(o[0], o[1], o[2], o[3]);
        up[1] = make_float4(o[4], o[5], o[6], o[7]);
    }
}

// gather + fused head projections, stride-CSR version
__global__ __launch_bounds__(NT) void k_gatherS_head(const int* __restrict__ cnt,
                                                     const int* __restrict__ csr,
                                                     const float* __restrict__ dis,
                                                     const float* __restrict__ u,
                                                     const float* __restrict__ b,
                                                     const float* __restrict__ Wv,
                                                     const float* __restrict__ Wp,
                                                     float* __restrict__ uH, int N) {
    int g = blockIdx.x * NT + threadIdx.x;
    int n = g >> 2, sub = g & 3;
    if (n >= N) return;
    int base = n * STRIDE;
    int i = base + sub, end = base + min(cnt[n], STRIDE);
    float a[8];
#pragma unroll
    for (int k = 0; k < 8; ++k) a[k] = 0.0f;
    for (; i + 4 < end; i += 8) {
        int s0 = csr[i], s1 = csr[i + 4];
        float4 p0 = *reinterpret_cast<const float4*>(u + 8 * s0);
        float4 p1 = *reinterpret_cast<const float4*>(u + 8 * s0 + 4);
        float4 q0 = *reinterpret_cast<const float4*>(u + 8 * s1);
        float4 q1 = *reinterpret_cast<const float4*>(u + 8 * s1 + 4);
        a[0] += p0.x + q0.x; a[1] += p0.y + q0.y;
        a[2] += p0.z + q0.z; a[3] += p0.w + q0.w;
        a[4] += p1.x + q1.x; a[5] += p1.y + q1.y;
        a[6] += p1.z + q1.z; a[7] += p1.w + q1.w;
    }
    if (i < end) {
        int s0 = csr[i];
        float4 p0 = *reinterpret_cast<const float4*>(u + 8 * s0);
        float4 p1 = *reinterpret_cast<const float4*>(u + 8 * s0 + 4);
        a[0] += p0.x; a[1] += p0.y; a[2] += p0.z; a[3] += p0.w;
        a[4] += p1.x; a[5] += p1.y; a[6] += p1.z; a[7] += p1.w;
    }
#pragma unroll
    for (int k = 0; k < 8; ++k) {
        a[k] += __shfl_xor(a[k], 1, 64);
        a[k] += __shfl_xor(a[k], 2, 64);
    }
    if (sub == 0) {
        float4 s0v = *reinterpret_cast<const float4*>(u + 8 * n);
        float4 s1v = *reinterpret_cast<const float4*>(u + 8 * n + 4);
        a[0] += s0v.x; a[1] += s0v.y; a[2] += s0v.z; a[3] += s0v.w;
        a[4] += s1v.x; a[5] += s1v.y; a[6] += s1v.z; a[7] += s1v.w;
        float dn = dis[n];
        float tv = 0.0f, tp = 0.0f;
#pragma unroll
        for (int f = 0; f < 8; ++f) {
            float gg = a[f] * dn + b[f];
            float h = gg > 0.0f ? gg : expm1f(gg);
            tv += h * Wv[f];
            tp += h * Wp[f];
        }
        *reinterpret_cast<float2*>(uH + 2 * n) = make_float2(dn * tv, dn * tp);
    }
}

// final 2-wide gather, stride-CSR version: proba out + value reduce
__global__ __launch_bounds__(NT) void k_gatherS_2n(const int* __restrict__ cnt,
                                                   const int* __restrict__ csr,
                                                   const float* __restrict__ dis,
                                                   const float* __restrict__ uH,
                                                   const float* __restrict__ bp,
                                                   float* __restrict__ out,
                                                   float* __restrict__ vsum, int N) {
    int g = blockIdx.x * NT + threadIdx.x;
    int n = g >> 2, sub = g & 3;
    bool valid = n < N;
    int i = 0, end = 0;
    if (valid) { int base = n * STRIDE; i = base + sub; end = base + min(cnt[n], STRIDE); }
    float av = 0.0f, ap = 0.0f;
    for (; i + 4 < end; i += 8) {
        int s0 = csr[i], s1 = csr[i + 4];
        float2 p = *reinterpret_cast<const float2*>(uH + 2 * s0);
        float2 q = *reinterpret_cast<const float2*>(uH + 2 * s1);
        av += p.x + q.x; ap += p.y + q.y;
    }
    if (i < end) {
        int s0 = csr[i];
        float2 p = *reinterpret_cast<const float2*>(uH + 2 * s0);
        av += p.x; ap += p.y;
    }
    av += __shfl_xor(av, 1, 64); av += __shfl_xor(av, 2, 64);
    ap += __shfl_xor(ap, 1, 64); ap += __shfl_xor(ap, 2, 64);
    float contrib = 0.0f;
    if (valid && sub == 0) {
        float2 selfv = *reinterpret_cast<const float2*>(uH + 2 * n);
        av += selfv.x; ap += selfv.y;
        float dn = dis[n];
        out[n] = ap * dn + bp[0];
        contrib = av * dn;
    }
#pragma unroll
    for (int o = 32; o > 0; o >>= 1) contrib += __shfl_down(contrib, o, 64);
    __shared__ float sred[NT / 64];
    if ((threadIdx.x & 63) == 0) sred[threadIdx.x >> 6] = contrib;
    __syncthreads();
    if (threadIdx.x == 0) {
        float bsum = 0.0f;
#pragma unroll
        for (int k = 0; k < NT / 64; ++k) bsum += sred[k];
        atomicAdd(vsum, bsum);
    }
}

__global__ void k_final(const float* __restrict__ vsum,
                        const float* __restrict__ bv,
                        float* __restrict__ out, int N) {
    out[0] = vsum[0] * (1.0f / (float)N) + bv[0];
}

// ==================== exact-CSR path (fallback, round-2) ====================

__global__ __launch_bounds__(NT) void k_count(const int* __restrict__ dst,
                                              int* __restrict__ deg, int E) {
    int e = blockIdx.x * NT + threadIdx.x;
    if (e < E) atomicAdd(&deg[dst[e]], 1);
}

__global__ __launch_bounds__(NT) void k_scanA(const int* __restrict__ deg,
                                              int* __restrict__ partial, int N) {
    int t = threadIdx.x;
    int base = blockIdx.x * CHUNK + t * 4;
    int s = 0;
#pragma unroll
    for (int j = 0; j < 4; ++j) { int i = base + j; if (i < N) s += deg[i]; }
    __shared__ int red[NT];
    red[t] = s; __syncthreads();
    for (int o = NT / 2; o > 0; o >>= 1) {
        if (t < o) red[t] += red[t + o];
        __syncthreads();
    }
    if (t == 0) partial[blockIdx.x] = red[0];
}

__global__ void k_scanB(const int* __restrict__ partial, int* __restrict__ chunkoff,
                        int* __restrict__ rowst, int nblk, int N) {
    if (threadIdx.x == 0) {
        int off = 0;
        for (int b = 0; b < nblk; ++b) { chunkoff[b] = off; off += partial[b]; }
        rowst[N] = off;
    }
}

__global__ __launch_bounds__(NT) void k_scanC(const int* __restrict__ deg,
                                              const int* __restrict__ chunkoff,
                                              int* __restrict__ rowst,
                                              float* __restrict__ dis, int N) {
    int t = threadIdx.x;
    int base = blockIdx.x * CHUNK + t * 4;
    int v[4]; int tsum = 0;
#pragma unroll
    for (int j = 0; j < 4; ++j) { int i = base + j; v[j] = (i < N) ? deg[i] : 0; tsum += v[j]; }
    __shared__ int ss[NT];
    ss[t] = tsum; __syncthreads();
    for (int o = 1; o < NT; o <<= 1) {
        int x = (t >= o) ? ss[t - o] : 0;
        __syncthreads();
        ss[t] += x;
        __syncthreads();
    }
    int run = ss[t] - tsum + chunkoff[blockIdx.x];
#pragma unroll
    for (int j = 0; j < 4; ++j) {
        int i = base + j;
        if (i < N) { rowst[i] = run; dis[i] = rsqrtf((float)v[j] + 1.0f); run += v[j]; }
    }
}

__global__ __launch_bounds__(NT) void k_fill(const int* __restrict__ src,
                                             const int* __restrict__ dst,
                                             const int* __restrict__ rowst,
                                             int* __restrict__ deg,
                                             int* __restrict__ csr, int E) {
    int e = blockIdx.x * NT + threadIdx.x;
    if (e >= E) return;
    int s = src[e], d = dst[e];
    int old = atomicSub(&deg[d], 1);
    csr[rowst[d] + old - 1] = s;
}

__global__ __launch_bounds__(NT) void k_node0n(const float* __restrict__ x,
                                               const float* __restrict__ W,
                                               const float* __restrict__ dis,
                                               float* __restrict__ u, int N) {
    int n = blockIdx.x * NT + threadIdx.x;
    if (n >= N) return;
    float x0 = x[2 * n], x1 = x[2 * n + 1];
    float dn = dis[n];
    float o[8];
#pragma unroll
    for (int f = 0; f < 8; ++f) o[f] = dn * (x0 * W[f] + x1 * W[8 + f]);
    float4* up = reinterpret_cast<float4*>(u + 8 * n);
    up[0] = make_float4(o[0], o[1], o[2], o[3]);
    up[1] = make_float4(o[4], o[5], o[6], o[7]);
}

__global__ __launch_bounds__(NT) void k_gather_layer(const int* __restrict__ rowst,
                                                     const int* __restrict__ csr,
                                                     const float* __restrict__ dis,
                                                     const float* __restrict__ u,
                                                     const float* __restrict__ b,
                                                     const float* __restrict__ W,
                                                     float* __restrict__ un, int N) {
    int g = blockIdx.x * NT + threadIdx.x;
    int n = g >> 2, sub = g & 3;
    if (n >= N) return;
    int i = rowst[n] + sub, end = rowst[n + 1];
    float a[8];
#pragma unroll
    for (int k = 0; k < 8; ++k) a[k] = 0.0f;
    for (; i + 4 < end; i += 8) {
        int s0 = csr[i], s1 = csr[i + 4];
        float4 p0 = *reinterpret_cast<const float4*>(u + 8 * s0);
        float4 p1 = *reinterpret_cast<const float4*>(u + 8 * s0 + 4);
        float4 q0 = *reinterpret_cast<const float4*>(u + 8 * s1);
        float4 q1 = *reinterpret_cast<const float4*>(u + 8 * s1 + 4);
        a[0] += p0.x + q0.x; a[1] += p0.y + q0.y;
        a[2] += p0.z + q0.z; a[3] += p0.w + q0.w;
        a[4] += p1.x + q1.x; a[5] += p1.y + q1.y;
        a[6] += p1.z + q1.z; a[7] += p1.w + q1.w;
    }
    if (i < end) {
        int s0 = csr[i];
        float4 p0 = *reinterpret_cast<const float4*>(u + 8 * s0);
        float4 p1 = *reinterpret_cast<const float4*>(u + 8 * s0 + 4);
        a[0] += p0.x; a[1] += p0.y; a[2] += p0.z; a[3] += p0.w;
        a[4] += p1.x; a[5] += p1.y; a[6] += p1.z; a[7] += p1.w;
    }
#pragma unroll
    for (int k = 0; k < 8; ++k) {
        a[k] += __shfl_xor(a[k], 1, 64);
        a[k] += __shfl_xor(a[k], 2, 64);
    }
    if (sub == 0) {
        float4 s0v = *reinterpret_cast<const float4*>(u + 8 * n);
        float4 s1v = *reinterpret_cast<const float4*>(u + 8 * n + 4);
        a[0] += s0v.x; a[1] += s0v.y; a[2] += s0v.z; a[3] += s0v.w;
        a[4] += s1v.x; a[5] += s1v.y; a[6] += s1v.z; a[7] += s1v.w;
        float dn = dis[n];
        float h[8];
#pragma unroll
        for (int f = 0; f < 8; ++f) {
            float gg = a[f] * dn + b[f];
            h[f] = gg > 0.0f ? gg : expm1f(gg);
        }
        float o[8];
#pragma unroll
        for (int fo = 0; fo < 8; ++fo) {
            float t = 0.0f;
#pragma unroll
            for (int fi = 0; fi < 8; ++fi) t += h[fi] * W[fi * 8 + fo];
            o[fo] = dn * t;
        }
        float4* up = reinterpret_cast<float4*>(un + 8 * n);
        up[0] = make_float4(o[0], o[1], o[2], o[3]);
        up[1] = make_float4(o[4], o[5], o[6], o[7]);
    }
}

__global__ __launch_bounds__(NT) void k_gather_head(const int* __restrict__ rowst,
                                                    const int* __restrict__ csr,
                                                    const float* __restrict__ dis,
                                                    const float* __restrict__ u,
                                                    const float* __restrict__ b,
                                                    const float* __restrict__ Wv,
                                                    const float* __restrict__ Wp,
                                                    float* __restrict__ uH, int N) {
    int g = blockIdx.x * NT + threadIdx.x;
    int n = g >> 2, sub = g & 3;
    if (n >= N) return;
    int i = rowst[n] + sub, end = rowst[n + 1];
    float a[8];
#pragma unroll
    for (int k = 0; k < 8; ++k) a[k] = 0.0f;
    for (; i + 4 < end; i += 8) {
        int s0 = csr[i], s1 = csr[i + 4];
        float4 p0 = *reinterpret_cast<const float4*>(u + 8 * s0);
        float4 p1 = *reinterpret_cast<const float4*>(u + 8 * s0 + 4);
        float4 q0 = *reinterpret_cast<const float4*>(u + 8 * s1);
        float4 q1 = *reinterpret_cast<const float4*>(u + 8 * s1 + 4);
        a[0] += p0.x + q0.x; a[1] += p0.y + q0.y;
        a[2] += p0.z + q0.z; a[3] += p0.w + q0.w;
        a[4] += p1.x + q1.x; a[5] += p1.y + q1.y;
        a[6] += p1.z + q1.z; a[7] += p1.w + q1.w;
    }
    if (i < end) {
        int s0 = csr[i];
        float4 p0 = *reinterpret_cast<const float4*>(u + 8 * s0);
        float4 p1 = *reinterpret_cast<const float4*>(u + 8 * s0 + 4);
        a[0] += p0.x; a[1] += p0.y; a[2] += p0.z; a[3] += p0.w;
        a[4] += p1.x; a[5] += p1.y; a[6] += p1.z; a[7] += p1.w;
    }
#pragma unroll
    for (int k = 0; k < 8; ++k) {
        a[k] += __shfl_xor(a[k], 1, 64);
        a[k] += __shfl_xor(a[k], 2, 64);
    }
    if (sub == 0) {
        float4 s0v = *reinterpret_cast<const float4*>(u + 8 * n);
        float4 s1v = *reinterpret_cast<const float4*>(u + 8 * n + 4);
        a[0] += s0v.x; a[1] += s0v.y; a[2] += s0v.z; a[3] += s0v.w;
        a[4] += s1v.x; a[5] += s1v.y; a[6] += s1v.z; a[7] += s1v.w;
        float dn = dis[n];
        float tv = 0.0f, tp = 0.0f;
#pragma unroll
        for (int f = 0; f < 8; ++f) {
            float gg = a[f] * dn + b[f];
            float h = gg > 0.0f ? gg : expm1f(gg);
            tv += h * Wv[f];
            tp += h * Wp[f];
        }
        *reinterpret_cast<float2*>(uH + 2 * n) = make_float2(dn * tv, dn * tp);
    }
}

__global__ __launch_bounds__(NT) void k_gather2n(const int* __restrict__ rowst,
                                                 const int* __restrict__ csr,
                                                 const float* __restrict__ dis,
                                                 const float* __restrict__ uH,
                                                 const float* __restrict__ bp,
                                                 float* __restrict__ out,
                                                 float* __restrict__ vsum, int N) {
    int g = blockIdx.x * NT + threadIdx.x;
    int n = g >> 2, sub = g & 3;
    bool valid = n < N;
    int i = 0, end = 0;
    if (valid) { i = rowst[n] + sub; end = rowst[n + 1]; }
    float av = 0.0f, ap = 0.0f;
    for (; i + 4 < end; i += 8) {
        int s0 = csr[i], s1 = csr[i + 4];
        float2 p = *reinterpret_cast<const float2*>(uH + 2 * s0);
        float2 q = *reinterpret_cast<const float2*>(uH + 2 * s1);
        av += p.x + q.x; ap += p.y + q.y;
    }
    if (i < end) {
        int s0 = csr[i];
        float2 p = *reinterpret_cast<const float2*>(uH + 2 * s0);
        av += p.x; ap += p.y;
    }
    av += __shfl_xor(av, 1, 64); av += __shfl_xor(av, 2, 64);
    ap += __shfl_xor(ap, 1, 64); ap += __shfl_xor(ap, 2, 64);
    float contrib = 0.0f;
    if (valid && sub == 0) {
        float2 selfv = *reinterpret_cast<const float2*>(uH + 2 * n);
        av += selfv.x; ap += selfv.y;
        float dn = dis[n];
        out[n] = ap * dn + bp[0];
        contrib = av * dn;
    }
#pragma unroll
    for (int o = 32; o > 0; o >>= 1) contrib += __shfl_down(contrib, o, 64);
    __shared__ float sred[NT / 64];
    if ((threadIdx.x & 63) == 0) sred[threadIdx.x >> 6] = contrib;
    __syncthreads();
    if (threadIdx.x == 0) {
        float bsum = 0.0f;
#pragma unroll
        for (int k = 0; k < NT / 64; ++k) bsum += sred[k];
        atomicAdd(vsum, bsum);
    }
}

// ================================ launch ================================

extern "C" void kernel_launch(void* const* d_in, const int* in_sizes, int n_in,
                              void* d_out, int out_size, void* d_ws, size_t ws_size,
                              hipStream_t stream) {
    const float* x  = (const float*)d_in[0];
    const int* ei   = (const int*)d_in[1];
    const float* W0 = (const float*)d_in[2];
    const float* b0 = (const float*)d_in[3];
    const float* W1 = (const float*)d_in[4];
    const float* b1 = (const float*)d_in[5];
    const float* W2 = (const float*)d_in[6];
    const float* b2 = (const float*)d_in[7];
    const float* W3 = (const float*)d_in[8];
    const float* b3 = (const float*)d_in[9];
    const float* Wv = (const float*)d_in[10];
    const float* bv = (const float*)d_in[11];
    const float* Wp = (const float*)d_in[12];
    const float* bp = (const float*)d_in[13];
    float* out = (float*)d_out;

    int N = in_sizes[0] / 2;
    int E = in_sizes[1] / 2;
    const int* src = ei;
    const int* dst = ei + E;

    size_t needS = ((size_t)18 * N + 8 + (size_t)STRIDE * N) * 4;

    if (ws_size >= needS) {
        // -------- stride-CSR path: one atomic pass, no count/scan --------
        int* cnt    = (int*)d_ws;                   // N
        float* vsum = (float*)(cnt + N);            // 8 (1 used)
        float* dis  = vsum + 8;                     // N
        float* uA   = dis + N;                      // 8N
        float* uB   = uA + (size_t)8 * N;           // 8N
        int* csr    = (int*)(uB + (size_t)8 * N);   // STRIDE*N

        hipMemsetAsync(cnt, 0, ((size_t)N + 8) * 4, stream);

        k_fillS<<<nbi(E), NT, 0, stream>>>(src, dst, cnt, csr, E);
        k_prep<<<nbi(N), NT, 0, stream>>>(cnt, x, W0, dis, uA, N);
        k_gatherS_layer<<<nbi(4LL * N), NT, 0, stream>>>(cnt, csr, dis, uA, b0, W1, uB, N);
        k_gatherS_layer<<<nbi(4LL * N), NT, 0, stream>>>(cnt, csr, dis, uB, b1, W2, uA, N);
        k_gatherS_layer<<<nbi(4LL * N), NT, 0, stream>>>(cnt, csr, dis, uA, b2, W3, uB, N);
        k_gatherS_head<<<nbi(4LL * N), NT, 0, stream>>>(cnt, csr, dis, uB, b3, Wv, Wp, uA, N);
        k_gatherS_2n<<<nbi(4LL * N), NT, 0, stream>>>(cnt, csr, dis, uA, bp, out, vsum, N);
        k_final<<<1, 1, 0, stream>>>(vsum, bv, out + N, N);
    } else {
        // -------- exact-CSR fallback (round-2 path) --------
        int nblk = (N + CHUNK - 1) / CHUNK;
        int* deg      = (int*)d_ws;
        int* rowst    = deg + N;
        int* chunkoff = rowst + N + 1;
        int* partial  = chunkoff + nblk;
        float* dis    = (float*)(partial + nblk);
        float* vsum   = dis + N;
        float* uA     = vsum + 8;
        float* uB     = uA + (size_t)8 * N;
        int* csr      = (int*)(uB + (size_t)8 * N);

        hipMemsetAsync(deg, 0, (size_t)N * 4, stream);
        hipMemsetAsync(vsum, 0, 4, stream);

        k_count<<<nbi(E), NT, 0, stream>>>(dst, deg, E);
        k_scanA<<<nblk, NT, 0, stream>>>(deg, partial, N);
        k_scanB<<<1, 64, 0, stream>>>(partial, chunkoff, rowst, nblk, N);
        k_scanC<<<nblk, NT, 0, stream>>>(deg, chunkoff, rowst, dis, N);
        k_fill<<<nbi(E), NT, 0, stream>>>(src, dst, rowst, deg, csr, E);

        k_node0n<<<nbi(N), NT, 0, stream>>>(x, W0, dis, uA, N);
        k_gather_layer<<<nbi(4LL * N), NT, 0, stream>>>(rowst, csr, dis, uA, b0, W1, uB, N);
        k_gather_layer<<<nbi(4LL * N), NT, 0, stream>>>(rowst, csr, dis, uB, b1, W2, uA, N);
        k_gather_layer<<<nbi(4LL * N), NT, 0, stream>>>(rowst, csr, dis, uA, b2, W3, uB, N);
        k_gather_head<<<nbi(4LL * N), NT, 0, stream>>>(rowst, csr, dis, uB, b3, Wv, Wp, uA, N);
        k_gather2n<<<nbi(4LL * N), NT, 0, stream>>>(rowst, csr, dis, uA, bp, out, vsum, N);
        k_final<<<1, 1, 0, stream>>>(vsum, bv, out + N, N);
    }
}

// Round 4
// 457.040 us; speedup vs baseline: 24.5674x; 1.8011x over previous
//
#include <hip/hip_runtime.h>

#define NT 256
#define CHUNK 1024
#define PBLK 512   // blocks for hist/partition passes

static inline int nbi(long long n) { return (int)((n + NT - 1) / NT); }

// ===================== bucket-partition CSR build =====================
// buckets of 256 nodes: bucket = dst >> 8, d_local = dst & 255
// packed entry = (d_local << 17) | src   (requires N <= 131072)

__global__ __launch_bounds__(256) void k_hist(const int* __restrict__ dst,
                                              int* __restrict__ hist_g,
                                              int E, int NB) {
    __shared__ int lh[512];
    for (int i = threadIdx.x; i < 512; i += 256) lh[i] = 0;
    __syncthreads();
    int chunk = (E + gridDim.x - 1) / gridDim.x;
    int lo = blockIdx.x * chunk, hi = min(E, lo + chunk);
    for (int i = lo + threadIdx.x; i < hi; i += 256)
        atomicAdd(&lh[dst[i] >> 8], 1);
    __syncthreads();
    for (int b = threadIdx.x; b < NB; b += 256)
        if (lh[b]) atomicAdd(&hist_g[b], lh[b]);
}

__global__ __launch_bounds__(512) void k_bscan(const int* __restrict__ hist_g,
                                               int* __restrict__ bbase,
                                               int* __restrict__ cursor,
                                               int* __restrict__ rowst,
                                               int NB, int N, int E) {
    __shared__ int s[512];
    int t = threadIdx.x;
    int own = (t < NB) ? hist_g[t] : 0;
    s[t] = own;
    __syncthreads();
    for (int o = 1; o < 512; o <<= 1) {
        int v = (t >= o) ? s[t - o] : 0;
        __syncthreads();
        s[t] += v;
        __syncthreads();
    }
    if (t < NB) { int ex = s[t] - own; bbase[t] = ex; cursor[t] = ex; }
    if (t == 0) { bbase[NB] = E; rowst[N] = E; }
}

__global__ __launch_bounds__(256) void k_part(const int* __restrict__ src,
                                              const int* __restrict__ dst,
                                              int* __restrict__ cursor,
                                              int* __restrict__ part,
                                              int E, int NB) {
    __shared__ int lh[512], lbase[512];
    for (int i = threadIdx.x; i < 512; i += 256) lh[i] = 0;
    __syncthreads();
    int chunk = (E + gridDim.x - 1) / gridDim.x;
    int lo = blockIdx.x * chunk, hi = min(E, lo + chunk);
    for (int i = lo + threadIdx.x; i < hi; i += 256)
        atomicAdd(&lh[dst[i] >> 8], 1);
    __syncthreads();
    for (int b = threadIdx.x; b < NB; b += 256) {
        int c = lh[b];
        lbase[b] = c ? atomicAdd(&cursor[b], c) : 0;
    }
    __syncthreads();
    for (int i = threadIdx.x; i < 512; i += 256) lh[i] = 0;
    __syncthreads();
    for (int i = lo + threadIdx.x; i < hi; i += 256) {
        int d = dst[i], s = src[i];
        int b = d >> 8;
        int pos = lbase[b] + atomicAdd(&lh[b], 1);
        part[pos] = ((d & 255) << 17) | s;
    }
}

// one block per bucket: LDS count -> scan -> rowst/dis -> place csr
__global__ __launch_bounds__(256) void k_build(const int* __restrict__ bbase,
                                               const int* __restrict__ part,
                                               int* __restrict__ rowst,
                                               float* __restrict__ dis,
                                               int* __restrict__ csr,
                                               int N) {
    __shared__ int dcnt[256], doff[256];
    int b = blockIdx.x, t = threadIdx.x;
    int lo = bbase[b], hi = bbase[b + 1];
    dcnt[t] = 0;
    __syncthreads();
    for (int i = lo + t; i < hi; i += 256)
        atomicAdd(&dcnt[part[i] >> 17], 1);
    __syncthreads();
    int own = dcnt[t];
    doff[t] = own;
    __syncthreads();
    for (int o = 1; o < 256; o <<= 1) {
        int v = (t >= o) ? doff[t - o] : 0;
        __syncthreads();
        doff[t] += v;
        __syncthreads();
    }
    int excl = doff[t] - own;
    int node = (b << 8) + t;
    if (node < N) {
        rowst[node] = lo + excl;
        dis[node] = rsqrtf((float)own + 1.0f);
    }
    dcnt[t] = excl;
    __syncthreads();
    for (int i = lo + t; i < hi; i += 256) {
        int pv = part[i];
        int slot = atomicAdd(&dcnt[pv >> 17], 1);
        csr[lo + slot] = pv & 0x1FFFF;
    }
}

// ===================== per-node + gather kernels =====================

// u0 = dis * (x @ W0)
__global__ __launch_bounds__(NT) void k_node0n(const float* __restrict__ x,
                                               const float* __restrict__ W,
                                               const float* __restrict__ dis,
                                               float* __restrict__ u, int N) {
    int n = blockIdx.x * NT + threadIdx.x;
    if (n >= N) return;
    float x0 = x[2 * n], x1 = x[2 * n + 1];
    float dn = dis[n];
    float o[8];
#pragma unroll
    for (int f = 0; f < 8; ++f) o[f] = dn * (x0 * W[f] + x1 * W[8 + f]);
    float4* up = reinterpret_cast<float4*>(u + 8 * n);
    up[0] = make_float4(o[0], o[1], o[2], o[3]);
    up[1] = make_float4(o[4], o[5], o[6], o[7]);
}

__global__ __launch_bounds__(NT) void k_gather_layer(const int* __restrict__ rowst,
                                                     const int* __restrict__ csr,
                                                     const float* __restrict__ dis,
                                                     const float* __restrict__ u,
                                                     const float* __restrict__ b,
                                                     const float* __restrict__ W,
                                                     float* __restrict__ un, int N) {
    int g = blockIdx.x * NT + threadIdx.x;
    int n = g >> 2, sub = g & 3;
    if (n >= N) return;
    int i = rowst[n] + sub, end = rowst[n + 1];
    float a[8];
#pragma unroll
    for (int k = 0; k < 8; ++k) a[k] = 0.0f;
    for (; i + 4 < end; i += 8) {
        int s0 = csr[i], s1 = csr[i + 4];
        float4 p0 = *reinterpret_cast<const float4*>(u + 8 * s0);
        float4 p1 = *reinterpret_cast<const float4*>(u + 8 * s0 + 4);
        float4 q0 = *reinterpret_cast<const float4*>(u + 8 * s1);
        float4 q1 = *reinterpret_cast<const float4*>(u + 8 * s1 + 4);
        a[0] += p0.x + q0.x; a[1] += p0.y + q0.y;
        a[2] += p0.z + q0.z; a[3] += p0.w + q0.w;
        a[4] += p1.x + q1.x; a[5] += p1.y + q1.y;
        a[6] += p1.z + q1.z; a[7] += p1.w + q1.w;
    }
    if (i < end) {
        int s0 = csr[i];
        float4 p0 = *reinterpret_cast<const float4*>(u + 8 * s0);
        float4 p1 = *reinterpret_cast<const float4*>(u + 8 * s0 + 4);
        a[0] += p0.x; a[1] += p0.y; a[2] += p0.z; a[3] += p0.w;
        a[4] += p1.x; a[5] += p1.y; a[6] += p1.z; a[7] += p1.w;
    }
#pragma unroll
    for (int k = 0; k < 8; ++k) {
        a[k] += __shfl_xor(a[k], 1, 64);
        a[k] += __shfl_xor(a[k], 2, 64);
    }
    if (sub == 0) {
        float4 s0v = *reinterpret_cast<const float4*>(u + 8 * n);
        float4 s1v = *reinterpret_cast<const float4*>(u + 8 * n + 4);
        a[0] += s0v.x; a[1] += s0v.y; a[2] += s0v.z; a[3] += s0v.w;
        a[4] += s1v.x; a[5] += s1v.y; a[6] += s1v.z; a[7] += s1v.w;
        float dn = dis[n];
        float h[8];
#pragma unroll
        for (int f = 0; f < 8; ++f) {
            float gg = a[f] * dn + b[f];
            h[f] = gg > 0.0f ? gg : expm1f(gg);
        }
        float o[8];
#pragma unroll
        for (int fo = 0; fo < 8; ++fo) {
            float t = 0.0f;
#pragma unroll
            for (int fi = 0; fi < 8; ++fi) t += h[fi] * W[fi * 8 + fo];
            o[fo] = dn * t;
        }
        float4* up = reinterpret_cast<float4*>(un + 8 * n);
        up[0] = make_float4(o[0], o[1], o[2], o[3]);
        up[1] = make_float4(o[4], o[5], o[6], o[7]);
    }
}

__global__ __launch_bounds__(NT) void k_gather_head(const int* __restrict__ rowst,
                                                    const int* __restrict__ csr,
                                                    const float* __restrict__ dis,
                                                    const float* __restrict__ u,
                                                    const float* __restrict__ b,
                                                    const float* __restrict__ Wv,
                                                    const float* __restrict__ Wp,
                                                    float* __restrict__ uH, int N) {
    int g = blockIdx.x * NT + threadIdx.x;
    int n = g >> 2, sub = g & 3;
    if (n >= N) return;
    int i = rowst[n] + sub, end = rowst[n + 1];
    float a[8];
#pragma unroll
    for (int k = 0; k < 8; ++k) a[k] = 0.0f;
    for (; i + 4 < end; i += 8) {
        int s0 = csr[i], s1 = csr[i + 4];
        float4 p0 = *reinterpret_cast<const float4*>(u + 8 * s0);
        float4 p1 = *reinterpret_cast<const float4*>(u + 8 * s0 + 4);
        float4 q0 = *reinterpret_cast<const float4*>(u + 8 * s1);
        float4 q1 = *reinterpret_cast<const float4*>(u + 8 * s1 + 4);
        a[0] += p0.x + q0.x; a[1] += p0.y + q0.y;
        a[2] += p0.z + q0.z; a[3] += p0.w + q0.w;
        a[4] += p1.x + q1.x; a[5] += p1.y + q1.y;
        a[6] += p1.z + q1.z; a[7] += p1.w + q1.w;
    }
    if (i < end) {
        int s0 = csr[i];
        float4 p0 = *reinterpret_cast<const float4*>(u + 8 * s0);
        float4 p1 = *reinterpret_cast<const float4*>(u + 8 * s0 + 4);
        a[0] += p0.x; a[1] += p0.y; a[2] += p0.z; a[3] += p0.w;
        a[4] += p1.x; a[5] += p1.y; a[6] += p1.z; a[7] += p1.w;
    }
#pragma unroll
    for (int k = 0; k < 8; ++k) {
        a[k] += __shfl_xor(a[k], 1, 64);
        a[k] += __shfl_xor(a[k], 2, 64);
    }
    if (sub == 0) {
        float4 s0v = *reinterpret_cast<const float4*>(u + 8 * n);
        float4 s1v = *reinterpret_cast<const float4*>(u + 8 * n + 4);
        a[0] += s0v.x; a[1] += s0v.y; a[2] += s0v.z; a[3] += s0v.w;
        a[4] += s1v.x; a[5] += s1v.y; a[6] += s1v.z; a[7] += s1v.w;
        float dn = dis[n];
        float tv = 0.0f, tp = 0.0f;
#pragma unroll
        for (int f = 0; f < 8; ++f) {
            float gg = a[f] * dn + b[f];
            float h = gg > 0.0f ? gg : expm1f(gg);
            tv += h * Wv[f];
            tp += h * Wp[f];
        }
        *reinterpret_cast<float2*>(uH + 2 * n) = make_float2(dn * tv, dn * tp);
    }
}

__global__ __launch_bounds__(NT) void k_gather2n(const int* __restrict__ rowst,
                                                 const int* __restrict__ csr,
                                                 const float* __restrict__ dis,
                                                 const float* __restrict__ uH,
                                                 const float* __restrict__ bp,
                                                 float* __restrict__ out,
                                                 float* __restrict__ vsum, int N) {
    int g = blockIdx.x * NT + threadIdx.x;
    int n = g >> 2, sub = g & 3;
    bool valid = n < N;
    int i = 0, end = 0;
    if (valid) { i = rowst[n] + sub; end = rowst[n + 1]; }
    float av = 0.0f, ap = 0.0f;
    for (; i + 4 < end; i += 8) {
        int s0 = csr[i], s1 = csr[i + 4];
        float2 p = *reinterpret_cast<const float2*>(uH + 2 * s0);
        float2 q = *reinterpret_cast<const float2*>(uH + 2 * s1);
        av += p.x + q.x; ap += p.y + q.y;
    }
    if (i < end) {
        int s0 = csr[i];
        float2 p = *reinterpret_cast<const float2*>(uH + 2 * s0);
        av += p.x; ap += p.y;
    }
    av += __shfl_xor(av, 1, 64); av += __shfl_xor(av, 2, 64);
    ap += __shfl_xor(ap, 1, 64); ap += __shfl_xor(ap, 2, 64);
    float contrib = 0.0f;
    if (valid && sub == 0) {
        float2 selfv = *reinterpret_cast<const float2*>(uH + 2 * n);
        av += selfv.x; ap += selfv.y;
        float dn = dis[n];
        out[n] = ap * dn + bp[0];
        contrib = av * dn;
    }
#pragma unroll
    for (int o = 32; o > 0; o >>= 1) contrib += __shfl_down(contrib, o, 64);
    __shared__ float sred[NT / 64];
    if ((threadIdx.x & 63) == 0) sred[threadIdx.x >> 6] = contrib;
    __syncthreads();
    if (threadIdx.x == 0) {
        float bsum = 0.0f;
#pragma unroll
        for (int k = 0; k < NT / 64; ++k) bsum += sred[k];
        atomicAdd(vsum, bsum);
    }
}

__global__ void k_final(const float* __restrict__ vsum,
                        const float* __restrict__ bv,
                        float* __restrict__ out, int N) {
    out[0] = vsum[0] * (1.0f / (float)N) + bv[0];
}

// ============== fallback: round-2 two-pass exact-CSR build ==============

__global__ __launch_bounds__(NT) void k_count(const int* __restrict__ dst,
                                              int* __restrict__ deg, int E) {
    int e = blockIdx.x * NT + threadIdx.x;
    if (e < E) atomicAdd(&deg[dst[e]], 1);
}

__global__ __launch_bounds__(NT) void k_scanA(const int* __restrict__ deg,
                                              int* __restrict__ partial, int N) {
    int t = threadIdx.x;
    int base = blockIdx.x * CHUNK + t * 4;
    int s = 0;
#pragma unroll
    for (int j = 0; j < 4; ++j) { int i = base + j; if (i < N) s += deg[i]; }
    __shared__ int red[NT];
    red[t] = s; __syncthreads();
    for (int o = NT / 2; o > 0; o >>= 1) {
        if (t < o) red[t] += red[t + o];
        __syncthreads();
    }
    if (t == 0) partial[blockIdx.x] = red[0];
}

__global__ void k_scanB(const int* __restrict__ partial, int* __restrict__ chunkoff,
                        int* __restrict__ rowst, int nblk, int N) {
    if (threadIdx.x == 0) {
        int off = 0;
        for (int b = 0; b < nblk; ++b) { chunkoff[b] = off; off += partial[b]; }
        rowst[N] = off;
    }
}

__global__ __launch_bounds__(NT) void k_scanC(const int* __restrict__ deg,
                                              const int* __restrict__ chunkoff,
                                              int* __restrict__ rowst,
                                              float* __restrict__ dis, int N) {
    int t = threadIdx.x;
    int base = blockIdx.x * CHUNK + t * 4;
    int v[4]; int tsum = 0;
#pragma unroll
    for (int j = 0; j < 4; ++j) { int i = base + j; v[j] = (i < N) ? deg[i] : 0; tsum += v[j]; }
    __shared__ int ss[NT];
    ss[t] = tsum; __syncthreads();
    for (int o = 1; o < NT; o <<= 1) {
        int x = (t >= o) ? ss[t - o] : 0;
        __syncthreads();
        ss[t] += x;
        __syncthreads();
    }
    int run = ss[t] - tsum + chunkoff[blockIdx.x];
#pragma unroll
    for (int j = 0; j < 4; ++j) {
        int i = base + j;
        if (i < N) { rowst[i] = run; dis[i] = rsqrtf((float)v[j] + 1.0f); run += v[j]; }
    }
}

__global__ __launch_bounds__(NT) void k_fill(const int* __restrict__ src,
                                             const int* __restrict__ dst,
                                             const int* __restrict__ rowst,
                                             int* __restrict__ deg,
                                             int* __restrict__ csr, int E) {
    int e = blockIdx.x * NT + threadIdx.x;
    if (e >= E) return;
    int s = src[e], d = dst[e];
    int old = atomicSub(&deg[d], 1);
    csr[rowst[d] + old - 1] = s;
}

// ================================ launch ================================

extern "C" void kernel_launch(void* const* d_in, const int* in_sizes, int n_in,
                              void* d_out, int out_size, void* d_ws, size_t ws_size,
                              hipStream_t stream) {
    const float* x  = (const float*)d_in[0];
    const int* ei   = (const int*)d_in[1];
    const float* W0 = (const float*)d_in[2];
    const float* b0 = (const float*)d_in[3];
    const float* W1 = (const float*)d_in[4];
    const float* b1 = (const float*)d_in[5];
    const float* W2 = (const float*)d_in[6];
    const float* b2 = (const float*)d_in[7];
    const float* W3 = (const float*)d_in[8];
    const float* b3 = (const float*)d_in[9];
    const float* Wv = (const float*)d_in[10];
    const float* bv = (const float*)d_in[11];
    const float* Wp = (const float*)d_in[12];
    const float* bp = (const float*)d_in[13];
    float* out = (float*)d_out;

    int N = in_sizes[0] / 2;
    int E = in_sizes[1] / 2;
    const int* src = ei;
    const int* dst = ei + E;
    int NB = (N + 255) >> 8;

    size_t needP = ((size_t)18 * N + 2 * (size_t)E + 1600) * 4;

    if (N <= 131072 && ws_size >= needP) {
        // ---- bucket-partition build (LDS atomics) + exact-CSR gathers ----
        int* hist_g = (int*)d_ws;                   // 512
        float* vsum = (float*)(hist_g + 512);       // 8
        int* bbase  = (int*)(vsum + 8);             // 513
        int* cursor = bbase + 513;                  // 512
        int* rowst  = cursor + 512;                 // N+1
        float* dis  = (float*)(rowst + N + 1);      // N
        float* uA   = dis + N;                      // 8N
        float* uB   = uA + (size_t)8 * N;           // 8N
        int* part   = (int*)(uB + (size_t)8 * N);   // E
        int* csr    = part + (size_t)E;             // E

        hipMemsetAsync(hist_g, 0, 520 * 4, stream);

        k_hist<<<PBLK, 256, 0, stream>>>(dst, hist_g, E, NB);
        k_bscan<<<1, 512, 0, stream>>>(hist_g, bbase, cursor, rowst, NB, N, E);
        k_part<<<PBLK, 256, 0, stream>>>(src, dst, cursor, part, E, NB);
        k_build<<<NB, 256, 0, stream>>>(bbase, part, rowst, dis, csr, N);

        k_node0n<<<nbi(N), NT, 0, stream>>>(x, W0, dis, uA, N);
        k_gather_layer<<<nbi(4LL * N), NT, 0, stream>>>(rowst, csr, dis, uA, b0, W1, uB, N);
        k_gather_layer<<<nbi(4LL * N), NT, 0, stream>>>(rowst, csr, dis, uB, b1, W2, uA, N);
        k_gather_layer<<<nbi(4LL * N), NT, 0, stream>>>(rowst, csr, dis, uA, b2, W3, uB, N);
        k_gather_head<<<nbi(4LL * N), NT, 0, stream>>>(rowst, csr, dis, uB, b3, Wv, Wp, uA, N);
        k_gather2n<<<nbi(4LL * N), NT, 0, stream>>>(rowst, csr, dis, uA, bp, out, vsum, N);
        k_final<<<1, 1, 0, stream>>>(vsum, bv, out + N, N);
    } else {
        // ---- fallback: two-pass exact CSR (round-2 path) ----
        int nblk = (N + CHUNK - 1) / CHUNK;
        int* deg      = (int*)d_ws;
        int* rowst    = deg + N;
        int* chunkoff = rowst + N + 1;
        int* partial  = chunkoff + nblk;
        float* dis    = (float*)(partial + nblk);
        float* vsum   = dis + N;
        float* uA     = vsum + 8;
        float* uB     = uA + (size_t)8 * N;
        int* csr      = (int*)(uB + (size_t)8 * N);

        hipMemsetAsync(deg, 0, (size_t)N * 4, stream);
        hipMemsetAsync(vsum, 0, 4, stream);

        k_count<<<nbi(E), NT, 0, stream>>>(dst, deg, E);
        k_scanA<<<nblk, NT, 0, stream>>>(deg, partial, N);
        k_scanB<<<1, 64, 0, stream>>>(partial, chunkoff, rowst, nblk, N);
        k_scanC<<<nblk, NT, 0, stream>>>(deg, chunkoff, rowst, dis, N);
        k_fill<<<nbi(E), NT, 0, stream>>>(src, dst, rowst, deg, csr, E);

        k_node0n<<<nbi(N), NT, 0, stream>>>(x, W0, dis, uA, N);
        k_gather_layer<<<nbi(4LL * N), NT, 0, stream>>>(rowst, csr, dis, uA, b0, W1, uB, N);
        k_gather_layer<<<nbi(4LL * N), NT, 0, stream>>>(rowst, csr, dis, uB, b1, W2, uA, N);
        k_gather_layer<<<nbi(4LL * N), NT, 0, stream>>>(rowst, csr, dis, uA, b2, W3, uB, N);
        k_gather_head<<<nbi(4LL * N), NT, 0, stream>>>(rowst, csr, dis, uB, b3, Wv, Wp, uA, N);
        k_gather2n<<<nbi(4LL * N), NT, 0, stream>>>(rowst, csr, dis, uA, bp, out, vsum, N);
        k_final<<<1, 1, 0, stream>>>(vsum, bv, out + N, N);
    }
}

// Round 5
// 446.615 us; speedup vs baseline: 25.1408x; 1.0233x over previous
//
#include <hip/hip_runtime.h>

#define NT 256
#define CHUNK 1024
#define PBLK 512   // blocks for hist/partition passes
#define PTILE 8192 // staged partition tile (edges)

static inline int nbi(long long n) { return (int)((n + NT - 1) / NT); }

// ===================== bucket-partition CSR build =====================
// buckets of 256 nodes: bucket = dst >> 8, d_local = dst & 255
// packed entry = (d_local << 17) | src   (requires N <= 131072)

__global__ __launch_bounds__(256) void k_hist(const int* __restrict__ dst,
                                              int* __restrict__ hist_g,
                                              int E, int NB) {
    __shared__ int lh[512];
    for (int i = threadIdx.x; i < 512; i += 256) lh[i] = 0;
    __syncthreads();
    int chunk = (E + gridDim.x - 1) / gridDim.x;
    int lo = blockIdx.x * chunk, hi = min(E, lo + chunk);
    for (int i = lo + threadIdx.x; i < hi; i += 256)
        atomicAdd(&lh[dst[i] >> 8], 1);
    __syncthreads();
    for (int b = threadIdx.x; b < NB; b += 256)
        if (lh[b]) atomicAdd(&hist_g[b], lh[b]);
}

__global__ __launch_bounds__(512) void k_bscan(const int* __restrict__ hist_g,
                                               int* __restrict__ bbase,
                                               int* __restrict__ cursor,
                                               int* __restrict__ rowst,
                                               int NB, int N, int E) {
    __shared__ int s[512];
    int t = threadIdx.x;
    int own = (t < NB) ? hist_g[t] : 0;
    s[t] = own;
    __syncthreads();
    for (int o = 1; o < 512; o <<= 1) {
        int v = (t >= o) ? s[t - o] : 0;
        __syncthreads();
        s[t] += v;
        __syncthreads();
    }
    if (t < NB) { int ex = s[t] - own; bbase[t] = ex; cursor[t] = ex; }
    if (t == 0) { bbase[NB] = E; rowst[N] = E; }
}

// staged partition: per-block reservation + LDS tile staging -> coalesced writes
__global__ __launch_bounds__(256) void k_part(const int* __restrict__ src,
                                              const int* __restrict__ dst,
                                              int* __restrict__ cursor,
                                              int* __restrict__ part,
                                              int E, int NB) {
    __shared__ int lh[512];
    __shared__ int wcur[512];
    __shared__ int th[512], tloff[512], tcnt[512];
    __shared__ int ps[256];
    __shared__ int stage[PTILE];
    __shared__ unsigned short sbkt[PTILE];
    int t = threadIdx.x;
    int chunk = (E + gridDim.x - 1) / gridDim.x;
    int lo = blockIdx.x * chunk, hi = min(E, lo + chunk);

    for (int i = t; i < 512; i += 256) lh[i] = 0;
    __syncthreads();
    for (int i = lo + t; i < hi; i += 256) atomicAdd(&lh[dst[i] >> 8], 1);
    __syncthreads();
    for (int b = t; b < NB; b += 256) {
        int c = lh[b];
        wcur[b] = c ? atomicAdd(&cursor[b], c) : 0;
    }
    __syncthreads();

    for (int tlo = lo; tlo < hi; tlo += PTILE) {
        int thi = min(hi, tlo + PTILE);
        int cnt = thi - tlo;
        for (int i = t; i < 512; i += 256) { th[i] = 0; tcnt[i] = 0; }
        __syncthreads();
        for (int i = tlo + t; i < thi; i += 256) atomicAdd(&th[dst[i] >> 8], 1);
        __syncthreads();
        // exclusive scan of th[0..512) with 256 threads (2 per thread)
        int a0 = th[2 * t], a1 = th[2 * t + 1];
        int psum = a0 + a1;
        ps[t] = psum;
        __syncthreads();
        for (int o = 1; o < 256; o <<= 1) {
            int v = (t >= o) ? ps[t - o] : 0;
            __syncthreads();
            ps[t] += v;
            __syncthreads();
        }
        int excl = ps[t] - psum;
        tloff[2 * t] = excl;
        tloff[2 * t + 1] = excl + a0;
        __syncthreads();
        // scatter into LDS staging, bucket-major
        for (int i = tlo + t; i < thi; i += 256) {
            int d = dst[i], s = src[i];
            int b = d >> 8;
            int pos = tloff[b] + atomicAdd(&tcnt[b], 1);
            stage[pos] = ((d & 255) << 17) | s;
            sbkt[pos] = (unsigned short)b;
        }
        __syncthreads();
        // coalesced copy-out
        for (int i = t; i < cnt; i += 256) {
            int b = sbkt[i];
            part[wcur[b] + (i - tloff[b])] = stage[i];
        }
        __syncthreads();
        for (int b = t; b < NB; b += 256) wcur[b] += th[b];
        __syncthreads();
    }
}

// one block per bucket (512 thr): LDS count -> scan -> rowst/dis -> place csr
__global__ __launch_bounds__(512) void k_build(const int* __restrict__ bbase,
                                               const int* __restrict__ part,
                                               int* __restrict__ rowst,
                                               float* __restrict__ dis,
                                               int* __restrict__ csr,
                                               int N) {
    __shared__ int dcnt[256], doff[256];
    int b = blockIdx.x, t = threadIdx.x;
    int lo = bbase[b], hi = bbase[b + 1];
    if (t < 256) dcnt[t] = 0;
    __syncthreads();
    for (int i = lo + t; i < hi; i += 512)
        atomicAdd(&dcnt[part[i] >> 17], 1);
    __syncthreads();
    int own = 0;
    if (t < 256) { own = dcnt[t]; doff[t] = own; }
    __syncthreads();
    for (int o = 1; o < 256; o <<= 1) {
        int v = 0;
        if (t < 256 && t >= o) v = doff[t - o];
        __syncthreads();
        if (t < 256) doff[t] += v;
        __syncthreads();
    }
    if (t < 256) {
        int excl = doff[t] - own;
        int node = (b << 8) + t;
        if (node < N) {
            rowst[node] = lo + excl;
            dis[node] = rsqrtf((float)own + 1.0f);
        }
        dcnt[t] = excl;
    }
    __syncthreads();
    for (int i = lo + t; i < hi; i += 512) {
        int pv = part[i];
        int slot = atomicAdd(&dcnt[pv >> 17], 1);
        csr[lo + slot] = pv & 0x1FFFF;
    }
}

// ===================== per-node + gather kernels =====================

// u0 = dis * (x @ W0)
__global__ __launch_bounds__(NT) void k_node0n(const float* __restrict__ x,
                                               const float* __restrict__ W,
                                               const float* __restrict__ dis,
                                               float* __restrict__ u, int N) {
    int n = blockIdx.x * NT + threadIdx.x;
    if (n >= N) return;
    float x0 = x[2 * n], x1 = x[2 * n + 1];
    float dn = dis[n];
    float o[8];
#pragma unroll
    for (int f = 0; f < 8; ++f) o[f] = dn * (x0 * W[f] + x1 * W[8 + f]);
    float4* up = reinterpret_cast<float4*>(u + 8 * n);
    up[0] = make_float4(o[0], o[1], o[2], o[3]);
    up[1] = make_float4(o[4], o[5], o[6], o[7]);
}

// gather (4 lanes/node, csr prefetch) + fused layer (epilogue spread on 4 lanes)
__global__ __launch_bounds__(NT) void k_gather_layer(const int* __restrict__ rowst,
                                                     const int* __restrict__ csr,
                                                     const float* __restrict__ dis,
                                                     const float* __restrict__ u,
                                                     const float* __restrict__ b,
                                                     const float* __restrict__ W,
                                                     float* __restrict__ un, int N) {
    int g = blockIdx.x * NT + threadIdx.x;
    int n = g >> 2, sub = g & 3;
    if (n >= N) return;
    int i = rowst[n] + sub, end = rowst[n + 1];
    float a[8];
#pragma unroll
    for (int k = 0; k < 8; ++k) a[k] = 0.0f;
    int s0 = 0, s1 = 0;
    bool run = (i + 4 < end);
    if (run) { s0 = csr[i]; s1 = csr[i + 4]; }
    while (run) {
        int ni = i + 8;
        bool nrun = (ni + 4 < end);
        int ns0 = 0, ns1 = 0;
        if (nrun) { ns0 = csr[ni]; ns1 = csr[ni + 4]; }
        float4 p0 = *reinterpret_cast<const float4*>(u + 8 * s0);
        float4 p1 = *reinterpret_cast<const float4*>(u + 8 * s0 + 4);
        float4 q0 = *reinterpret_cast<const float4*>(u + 8 * s1);
        float4 q1 = *reinterpret_cast<const float4*>(u + 8 * s1 + 4);
        a[0] += p0.x + q0.x; a[1] += p0.y + q0.y;
        a[2] += p0.z + q0.z; a[3] += p0.w + q0.w;
        a[4] += p1.x + q1.x; a[5] += p1.y + q1.y;
        a[6] += p1.z + q1.z; a[7] += p1.w + q1.w;
        i = ni; run = nrun; s0 = ns0; s1 = ns1;
    }
    if (i < end) {
        int sl = csr[i];
        float4 p0 = *reinterpret_cast<const float4*>(u + 8 * sl);
        float4 p1 = *reinterpret_cast<const float4*>(u + 8 * sl + 4);
        a[0] += p0.x; a[1] += p0.y; a[2] += p0.z; a[3] += p0.w;
        a[4] += p1.x; a[5] += p1.y; a[6] += p1.z; a[7] += p1.w;
    }
#pragma unroll
    for (int k = 0; k < 8; ++k) {
        a[k] += __shfl_xor(a[k], 1, 64);
        a[k] += __shfl_xor(a[k], 2, 64);
    }
    // lane owns output features {2*sub, 2*sub+1}
    float va = sub == 0 ? a[0] : (sub == 1 ? a[2] : (sub == 2 ? a[4] : a[6]));
    float vb = sub == 0 ? a[1] : (sub == 1 ? a[3] : (sub == 2 ? a[5] : a[7]));
    float2 selfv = *reinterpret_cast<const float2*>(u + 8 * n + 2 * sub);
    va += selfv.x; vb += selfv.y;
    float dn = dis[n];
    float2 bb = *reinterpret_cast<const float2*>(b + 2 * sub);
    float g0 = va * dn + bb.x, g1 = vb * dn + bb.y;
    float h0 = g0 > 0.0f ? g0 : expm1f(g0);
    float h1 = g1 > 0.0f ? g1 : expm1f(g1);
    int base = (threadIdx.x & 63) & ~3;
    float hh0 = __shfl(h0, base + 0, 64), hh1 = __shfl(h1, base + 0, 64);
    float hh2 = __shfl(h0, base + 1, 64), hh3 = __shfl(h1, base + 1, 64);
    float hh4 = __shfl(h0, base + 2, 64), hh5 = __shfl(h1, base + 2, 64);
    float hh6 = __shfl(h0, base + 3, 64), hh7 = __shfl(h1, base + 3, 64);
    int fo = 2 * sub;
    float o0 = hh0 * W[0 * 8 + fo] + hh1 * W[1 * 8 + fo] + hh2 * W[2 * 8 + fo] +
               hh3 * W[3 * 8 + fo] + hh4 * W[4 * 8 + fo] + hh5 * W[5 * 8 + fo] +
               hh6 * W[6 * 8 + fo] + hh7 * W[7 * 8 + fo];
    float o1 = hh0 * W[0 * 8 + fo + 1] + hh1 * W[1 * 8 + fo + 1] + hh2 * W[2 * 8 + fo + 1] +
               hh3 * W[3 * 8 + fo + 1] + hh4 * W[4 * 8 + fo + 1] + hh5 * W[5 * 8 + fo + 1] +
               hh6 * W[6 * 8 + fo + 1] + hh7 * W[7 * 8 + fo + 1];
    *reinterpret_cast<float2*>(un + 8 * n + fo) = make_float2(dn * o0, dn * o1);
}

// gather + fused head projections (partial dot on each lane)
__global__ __launch_bounds__(NT) void k_gather_head(const int* __restrict__ rowst,
                                                    const int* __restrict__ csr,
                                                    const float* __restrict__ dis,
                                                    const float* __restrict__ u,
                                                    const float* __restrict__ b,
                                                    const float* __restrict__ Wv,
                                                    const float* __restrict__ Wp,
                                                    float* __restrict__ uH, int N) {
    int g = blockIdx.x * NT + threadIdx.x;
    int n = g >> 2, sub = g & 3;
    if (n >= N) return;
    int i = rowst[n] + sub, end = rowst[n + 1];
    float a[8];
#pragma unroll
    for (int k = 0; k < 8; ++k) a[k] = 0.0f;
    int s0 = 0, s1 = 0;
    bool run = (i + 4 < end);
    if (run) { s0 = csr[i]; s1 = csr[i + 4]; }
    while (run) {
        int ni = i + 8;
        bool nrun = (ni + 4 < end);
        int ns0 = 0, ns1 = 0;
        if (nrun) { ns0 = csr[ni]; ns1 = csr[ni + 4]; }
        float4 p0 = *reinterpret_cast<const float4*>(u + 8 * s0);
        float4 p1 = *reinterpret_cast<const float4*>(u + 8 * s0 + 4);
        float4 q0 = *reinterpret_cast<const float4*>(u + 8 * s1);
        float4 q1 = *reinterpret_cast<const float4*>(u + 8 * s1 + 4);
        a[0] += p0.x + q0.x; a[1] += p0.y + q0.y;
        a[2] += p0.z + q0.z; a[3] += p0.w + q0.w;
        a[4] += p1.x + q1.x; a[5] += p1.y + q1.y;
        a[6] += p1.z + q1.z; a[7] += p1.w + q1.w;
        i = ni; run = nrun; s0 = ns0; s1 = ns1;
    }
    if (i < end) {
        int sl = csr[i];
        float4 p0 = *reinterpret_cast<const float4*>(u + 8 * sl);
        float4 p1 = *reinterpret_cast<const float4*>(u + 8 * sl + 4);
        a[0] += p0.x; a[1] += p0.y; a[2] += p0.z; a[3] += p0.w;
        a[4] += p1.x; a[5] += p1.y; a[6] += p1.z; a[7] += p1.w;
    }
#pragma unroll
    for (int k = 0; k < 8; ++k) {
        a[k] += __shfl_xor(a[k], 1, 64);
        a[k] += __shfl_xor(a[k], 2, 64);
    }
    float va = sub == 0 ? a[0] : (sub == 1 ? a[2] : (sub == 2 ? a[4] : a[6]));
    float vb = sub == 0 ? a[1] : (sub == 1 ? a[3] : (sub == 2 ? a[5] : a[7]));
    float2 selfv = *reinterpret_cast<const float2*>(u + 8 * n + 2 * sub);
    va += selfv.x; vb += selfv.y;
    float dn = dis[n];
    float2 bb = *reinterpret_cast<const float2*>(b + 2 * sub);
    float g0 = va * dn + bb.x, g1 = vb * dn + bb.y;
    float h0 = g0 > 0.0f ? g0 : expm1f(g0);
    float h1 = g1 > 0.0f ? g1 : expm1f(g1);
    float tvp = h0 * Wv[2 * sub] + h1 * Wv[2 * sub + 1];
    float tpp = h0 * Wp[2 * sub] + h1 * Wp[2 * sub + 1];
    tvp += __shfl_xor(tvp, 1, 64); tvp += __shfl_xor(tvp, 2, 64);
    tpp += __shfl_xor(tpp, 1, 64); tpp += __shfl_xor(tpp, 2, 64);
    if (sub == 0)
        *reinterpret_cast<float2*>(uH + 2 * n) = make_float2(dn * tvp, dn * tpp);
}

// final 2-wide gather: proba out + value block-reduce
__global__ __launch_bounds__(NT) void k_gather2n(const int* __restrict__ rowst,
                                                 const int* __restrict__ csr,
                                                 const float* __restrict__ dis,
                                                 const float* __restrict__ uH,
                                                 const float* __restrict__ bp,
                                                 float* __restrict__ out,
                                                 float* __restrict__ vsum, int N) {
    int g = blockIdx.x * NT + threadIdx.x;
    int n = g >> 2, sub = g & 3;
    bool valid = n < N;
    int i = 0, end = 0;
    if (valid) { i = rowst[n] + sub; end = rowst[n + 1]; }
    float av = 0.0f, ap = 0.0f;
    int s0 = 0, s1 = 0;
    bool run = (i + 4 < end);
    if (run) { s0 = csr[i]; s1 = csr[i + 4]; }
    while (run) {
        int ni = i + 8;
        bool nrun = (ni + 4 < end);
        int ns0 = 0, ns1 = 0;
        if (nrun) { ns0 = csr[ni]; ns1 = csr[ni + 4]; }
        float2 p = *reinterpret_cast<const float2*>(uH + 2 * s0);
        float2 q = *reinterpret_cast<const float2*>(uH + 2 * s1);
        av += p.x + q.x; ap += p.y + q.y;
        i = ni; run = nrun; s0 = ns0; s1 = ns1;
    }
    if (i < end) {
        int sl = csr[i];
        float2 p = *reinterpret_cast<const float2*>(uH + 2 * sl);
        av += p.x; ap += p.y;
    }
    av += __shfl_xor(av, 1, 64); av += __shfl_xor(av, 2, 64);
    ap += __shfl_xor(ap, 1, 64); ap += __shfl_xor(ap, 2, 64);
    float contrib = 0.0f;
    if (valid && sub == 0) {
        float2 selfv = *reinterpret_cast<const float2*>(uH + 2 * n);
        av += selfv.x; ap += selfv.y;
        float dn = dis[n];
        out[n] = ap * dn + bp[0];
        contrib = av * dn;
    }
#pragma unroll
    for (int o = 32; o > 0; o >>= 1) contrib += __shfl_down(contrib, o, 64);
    __shared__ float sred[NT / 64];
    if ((threadIdx.x & 63) == 0) sred[threadIdx.x >> 6] = contrib;
    __syncthreads();
    if (threadIdx.x == 0) {
        float bsum = 0.0f;
#pragma unroll
        for (int k = 0; k < NT / 64; ++k) bsum += sred[k];
        atomicAdd(vsum, bsum);
    }
}

__global__ void k_final(const float* __restrict__ vsum,
                        const float* __restrict__ bv,
                        float* __restrict__ out, int N) {
    out[0] = vsum[0] * (1.0f / (float)N) + bv[0];
}

// ============== fallback: round-2 two-pass exact-CSR build ==============

__global__ __launch_bounds__(NT) void k_count(const int* __restrict__ dst,
                                              int* __restrict__ deg, int E) {
    int e = blockIdx.x * NT + threadIdx.x;
    if (e < E) atomicAdd(&deg[dst[e]], 1);
}

__global__ __launch_bounds__(NT) void k_scanA(const int* __restrict__ deg,
                                              int* __restrict__ partial, int N) {
    int t = threadIdx.x;
    int base = blockIdx.x * CHUNK + t * 4;
    int s = 0;
#pragma unroll
    for (int j = 0; j < 4; ++j) { int i = base + j; if (i < N) s += deg[i]; }
    __shared__ int red[NT];
    red[t] = s; __syncthreads();
    for (int o = NT / 2; o > 0; o >>= 1) {
        if (t < o) red[t] += red[t + o];
        __syncthreads();
    }
    if (t == 0) partial[blockIdx.x] = red[0];
}

__global__ void k_scanB(const int* __restrict__ partial, int* __restrict__ chunkoff,
                        int* __restrict__ rowst, int nblk, int N) {
    if (threadIdx.x == 0) {
        int off = 0;
        for (int b = 0; b < nblk; ++b) { chunkoff[b] = off; off += partial[b]; }
        rowst[N] = off;
    }
}

__global__ __launch_bounds__(NT) void k_scanC(const int* __restrict__ deg,
                                              const int* __restrict__ chunkoff,
                                              int* __restrict__ rowst,
                                              float* __restrict__ dis, int N) {
    int t = threadIdx.x;
    int base = blockIdx.x * CHUNK + t * 4;
    int v[4]; int tsum = 0;
#pragma unroll
    for (int j = 0; j < 4; ++j) { int i = base + j; v[j] = (i < N) ? deg[i] : 0; tsum += v[j]; }
    __shared__ int ss[NT];
    ss[t] = tsum; __syncthreads();
    for (int o = 1; o < NT; o <<= 1) {
        int x = (t >= o) ? ss[t - o] : 0;
        __syncthreads();
        ss[t] += x;
        __syncthreads();
    }
    int run = ss[t] - tsum + chunkoff[blockIdx.x];
#pragma unroll
    for (int j = 0; j < 4; ++j) {
        int i = base + j;
        if (i < N) { rowst[i] = run; dis[i] = rsqrtf((float)v[j] + 1.0f); run += v[j]; }
    }
}

__global__ __launch_bounds__(NT) void k_fill(const int* __restrict__ src,
                                             const int* __restrict__ dst,
                                             const int* __restrict__ rowst,
                                             int* __restrict__ deg,
                                             int* __restrict__ csr, int E) {
    int e = blockIdx.x * NT + threadIdx.x;
    if (e >= E) return;
    int s = src[e], d = dst[e];
    int old = atomicSub(&deg[d], 1);
    csr[rowst[d] + old - 1] = s;
}

// ================================ launch ================================

extern "C" void kernel_launch(void* const* d_in, const int* in_sizes, int n_in,
                              void* d_out, int out_size, void* d_ws, size_t ws_size,
                              hipStream_t stream) {
    const float* x  = (const float*)d_in[0];
    const int* ei   = (const int*)d_in[1];
    const float* W0 = (const float*)d_in[2];
    const float* b0 = (const float*)d_in[3];
    const float* W1 = (const float*)d_in[4];
    const float* b1 = (const float*)d_in[5];
    const float* W2 = (const float*)d_in[6];
    const float* b2 = (const float*)d_in[7];
    const float* W3 = (const float*)d_in[8];
    const float* b3 = (const float*)d_in[9];
    const float* Wv = (const float*)d_in[10];
    const float* bv = (const float*)d_in[11];
    const float* Wp = (const float*)d_in[12];
    const float* bp = (const float*)d_in[13];
    float* out = (float*)d_out;

    int N = in_sizes[0] / 2;
    int E = in_sizes[1] / 2;
    const int* src = ei;
    const int* dst = ei + E;
    int NB = (N + 255) >> 8;

    size_t needP = ((size_t)18 * N + 2 * (size_t)E + 1600) * 4;

    if (N <= 131072 && ws_size >= needP) {
        // ---- bucket-partition build (LDS atomics) + exact-CSR gathers ----
        int* hist_g = (int*)d_ws;                   // 512
        float* vsum = (float*)(hist_g + 512);       // 8
        int* bbase  = (int*)(vsum + 8);             // 513
        int* cursor = bbase + 513;                  // 512
        int* rowst  = cursor + 512;                 // N+1
        float* dis  = (float*)(rowst + N + 1);      // N
        float* uA   = dis + N;                      // 8N
        float* uB   = uA + (size_t)8 * N;           // 8N
        int* part   = (int*)(uB + (size_t)8 * N);   // E
        int* csr    = part + (size_t)E;             // E

        hipMemsetAsync(hist_g, 0, 520 * 4, stream);

        k_hist<<<PBLK, 256, 0, stream>>>(dst, hist_g, E, NB);
        k_bscan<<<1, 512, 0, stream>>>(hist_g, bbase, cursor, rowst, NB, N, E);
        k_part<<<PBLK, 256, 0, stream>>>(src, dst, cursor, part, E, NB);
        k_build<<<NB, 512, 0, stream>>>(bbase, part, rowst, dis, csr, N);

        k_node0n<<<nbi(N), NT, 0, stream>>>(x, W0, dis, uA, N);
        k_gather_layer<<<nbi(4LL * N), NT, 0, stream>>>(rowst, csr, dis, uA, b0, W1, uB, N);
        k_gather_layer<<<nbi(4LL * N), NT, 0, stream>>>(rowst, csr, dis, uB, b1, W2, uA, N);
        k_gather_layer<<<nbi(4LL * N), NT, 0, stream>>>(rowst, csr, dis, uA, b2, W3, uB, N);
        k_gather_head<<<nbi(4LL * N), NT, 0, stream>>>(rowst, csr, dis, uB, b3, Wv, Wp, uA, N);
        k_gather2n<<<nbi(4LL * N), NT, 0, stream>>>(rowst, csr, dis, uA, bp, out, vsum, N);
        k_final<<<1, 1, 0, stream>>>(vsum, bv, out + N, N);
    } else {
        // ---- fallback: two-pass exact CSR (round-2 path) ----
        int nblk = (N + CHUNK - 1) / CHUNK;
        int* deg      = (int*)d_ws;
        int* rowst    = deg + N;
        int* chunkoff = rowst + N + 1;
        int* partial  = chunkoff + nblk;
        float* dis    = (float*)(partial + nblk);
        float* vsum   = dis + N;
        float* uA     = vsum + 8;
        float* uB     = uA + (size_t)8 * N;
        int* csr      = (int*)(uB + (size_t)8 * N);

        hipMemsetAsync(deg, 0, (size_t)N * 4, stream);
        hipMemsetAsync(vsum, 0, 4, stream);

        k_count<<<nbi(E), NT, 0, stream>>>(dst, deg, E);
        k_scanA<<<nblk, NT, 0, stream>>>(deg, partial, N);
        k_scanB<<<1, 64, 0, stream>>>(partial, chunkoff, rowst, nblk, N);
        k_scanC<<<nblk, NT, 0, stream>>>(deg, chunkoff, rowst, dis, N);
        k_fill<<<nbi(E), NT, 0, stream>>>(src, dst, rowst, deg, csr, E);

        k_node0n<<<nbi(N), NT, 0, stream>>>(x, W0, dis, uA, N);
        k_gather_layer<<<nbi(4LL * N), NT, 0, stream>>>(rowst, csr, dis, uA, b0, W1, uB, N);
        k_gather_layer<<<nbi(4LL * N), NT, 0, stream>>>(rowst, csr, dis, uB, b1, W2, uA, N);
        k_gather_layer<<<nbi(4LL * N), NT, 0, stream>>>(rowst, csr, dis, uA, b2, W3, uB, N);
        k_gather_head<<<nbi(4LL * N), NT, 0, stream>>>(rowst, csr, dis, uB, b3, Wv, Wp, uA, N);
        k_gather2n<<<nbi(4LL * N), NT, 0, stream>>>(rowst, csr, dis, uA, bp, out, vsum, N);
        k_final<<<1, 1, 0, stream>>>(vsum, bv, out + N, N);
    }
}

// Round 6
// 376.255 us; speedup vs baseline: 29.8422x; 1.1870x over previous
//
#include <hip/hip_runtime.h>

#define NT 256
#define CHUNK 1024
#define PBLK2 2048  // blocks for hist/partition passes
#define PTILE 4096  // staged partition tile (edges)

static inline int nbi(long long n) { return (int)((n + NT - 1) / NT); }

// ===================== bucket-partition CSR build =====================
// buckets of 256 nodes: bucket = dst >> 8, d_local = dst & 255
// packed entry = (d_local << 17) | src   (requires N <= 131072)

// per-block histogram, no global atomics: histB[blk*NB + b]
__global__ __launch_bounds__(256) void k_histB(const int* __restrict__ dst,
                                               int* __restrict__ histB,
                                               int E, int NB) {
    __shared__ int lh[512];
    int t = threadIdx.x;
    for (int i = t; i < 512; i += 256) lh[i] = 0;
    __syncthreads();
    int chunk = (E + gridDim.x - 1) / gridDim.x;
    int lo = blockIdx.x * chunk, hi = min(E, lo + chunk);
    for (int i = lo + t; i < hi; i += 256)
        atomicAdd(&lh[dst[i] >> 8], 1);
    __syncthreads();
    for (int b = t; b < NB; b += 256)
        histB[(size_t)blockIdx.x * NB + b] = lh[b];
}

// block per bucket: exclusive scan over blocks -> cursorT[b*PBLK2+blk], tot[b]
__global__ __launch_bounds__(256) void k_scanB2(const int* __restrict__ histB,
                                                int* __restrict__ cursorT,
                                                int* __restrict__ tot,
                                                int NB, int nblk) {
    __shared__ int ch[256];
    __shared__ int carry;
    int b = blockIdx.x, t = threadIdx.x;
    if (t == 0) carry = 0;
    __syncthreads();
    for (int c = 0; c < nblk; c += 256) {
        int blk = c + t;
        int v = (blk < nblk) ? histB[(size_t)blk * NB + b] : 0;
        ch[t] = v;
        __syncthreads();
        for (int o = 1; o < 256; o <<= 1) {
            int x = (t >= o) ? ch[t - o] : 0;
            __syncthreads();
            ch[t] += x;
            __syncthreads();
        }
        int excl = ch[t] - v + carry;
        if (blk < nblk) cursorT[(size_t)b * PBLK2 + blk] = excl;
        __syncthreads();
        if (t == 0) carry += ch[255];
        __syncthreads();
    }
    if (t == 0) tot[b] = carry;
}

// scan bucket totals -> bbase (cursor arg is scratch, may alias tot)
__global__ __launch_bounds__(512) void k_bscan(const int* __restrict__ hist_g,
                                               int* __restrict__ bbase,
                                               int* __restrict__ cursor,
                                               int* __restrict__ rowst,
                                               int NB, int N, int E) {
    __shared__ int s[512];
    int t = threadIdx.x;
    int own = (t < NB) ? hist_g[t] : 0;
    s[t] = own;
    __syncthreads();
    for (int o = 1; o < 512; o <<= 1) {
        int v = (t >= o) ? s[t - o] : 0;
        __syncthreads();
        s[t] += v;
        __syncthreads();
    }
    if (t < NB) { int ex = s[t] - own; bbase[t] = ex; cursor[t] = ex; }
    if (t == 0) { bbase[NB] = E; rowst[N] = E; }
}

// staged partition with precomputed cursors (no phase-1 histogram)
__global__ __launch_bounds__(256) void k_partF(const int* __restrict__ src,
                                               const int* __restrict__ dst,
                                               const int* __restrict__ bbase,
                                               const int* __restrict__ cursorT,
                                               int* __restrict__ part,
                                               int E, int NB) {
    __shared__ int wcur[512];
    __shared__ int th[512], tloff[512], tcnt[512];
    __shared__ int ps[256];
    __shared__ int stage[PTILE];
    __shared__ unsigned short sbkt[PTILE];
    int t = threadIdx.x;
    int chunk = (E + gridDim.x - 1) / gridDim.x;
    int lo = blockIdx.x * chunk, hi = min(E, lo + chunk);
    if (lo >= hi) return;

    for (int b = t; b < NB; b += 256)
        wcur[b] = bbase[b] + cursorT[(size_t)b * PBLK2 + blockIdx.x];
    __syncthreads();

    for (int tlo = lo; tlo < hi; tlo += PTILE) {
        int thi = min(hi, tlo + PTILE);
        int cnt = thi - tlo;
        for (int i = t; i < 512; i += 256) { th[i] = 0; tcnt[i] = 0; }
        __syncthreads();
        for (int i = tlo + t; i < thi; i += 256) atomicAdd(&th[dst[i] >> 8], 1);
        __syncthreads();
        int a0 = th[2 * t], a1 = th[2 * t + 1];
        int psum = a0 + a1;
        ps[t] = psum;
        __syncthreads();
        for (int o = 1; o < 256; o <<= 1) {
            int v = (t >= o) ? ps[t - o] : 0;
            __syncthreads();
            ps[t] += v;
            __syncthreads();
        }
        int excl = ps[t] - psum;
        tloff[2 * t] = excl;
        tloff[2 * t + 1] = excl + a0;
        __syncthreads();
        for (int i = tlo + t; i < thi; i += 256) {
            int d = dst[i], s = src[i];
            int b = d >> 8;
            int pos = tloff[b] + atomicAdd(&tcnt[b], 1);
            stage[pos] = ((d & 255) << 17) | s;
            sbkt[pos] = (unsigned short)b;
        }
        __syncthreads();
        for (int i = t; i < cnt; i += 256) {
            int b = sbkt[i];
            part[wcur[b] + (i - tloff[b])] = stage[i];
        }
        __syncthreads();
        for (int b = t; b < NB; b += 256) wcur[b] += th[b];
        __syncthreads();
    }
}

// one block per bucket (512 thr): LDS count -> scan -> rowst/dis -> place csr
__global__ __launch_bounds__(512) void k_build(const int* __restrict__ bbase,
                                               const int* __restrict__ part,
                                               int* __restrict__ rowst,
                                               float* __restrict__ dis,
                                               int* __restrict__ csr,
                                               int N) {
    __shared__ int dcnt[256], doff[256];
    int b = blockIdx.x, t = threadIdx.x;
    int lo = bbase[b], hi = bbase[b + 1];
    if (t < 256) dcnt[t] = 0;
    __syncthreads();
    for (int i = lo + t; i < hi; i += 512)
        atomicAdd(&dcnt[part[i] >> 17], 1);
    __syncthreads();
    int own = 0;
    if (t < 256) { own = dcnt[t]; doff[t] = own; }
    __syncthreads();
    for (int o = 1; o < 256; o <<= 1) {
        int v = 0;
        if (t < 256 && t >= o) v = doff[t - o];
        __syncthreads();
        if (t < 256) doff[t] += v;
        __syncthreads();
    }
    if (t < 256) {
        int excl = doff[t] - own;
        int node = (b << 8) + t;
        if (node < N) {
            rowst[node] = lo + excl;
            dis[node] = rsqrtf((float)own + 1.0f);
        }
        dcnt[t] = excl;
    }
    __syncthreads();
    for (int i = lo + t; i < hi; i += 512) {
        int pv = part[i];
        int slot = atomicAdd(&dcnt[pv >> 17], 1);
        csr[lo + slot] = pv & 0x1FFFF;
    }
}

// ===================== per-node + gather kernels =====================

__global__ __launch_bounds__(NT) void k_node0n(const float* __restrict__ x,
                                               const float* __restrict__ W,
                                               const float* __restrict__ dis,
                                               float* __restrict__ u, int N) {
    int n = blockIdx.x * NT + threadIdx.x;
    if (n >= N) return;
    float2 xv = *reinterpret_cast<const float2*>(x + 2 * n);
    float dn = dis[n];
    float o[8];
#pragma unroll
    for (int f = 0; f < 8; ++f) o[f] = dn * (xv.x * W[f] + xv.y * W[8 + f]);
    float4* up = reinterpret_cast<float4*>(u + 8 * n);
    up[0] = make_float4(o[0], o[1], o[2], o[3]);
    up[1] = make_float4(o[4], o[5], o[6], o[7]);
}

#define GATHER8_BODY(IDX)                                                     \
    {                                                                         \
        float4 p0 = *reinterpret_cast<const float4*>(u + 8 * (IDX));          \
        float4 p1 = *reinterpret_cast<const float4*>(u + 8 * (IDX) + 4);      \
        a[0] += p0.x; a[1] += p0.y; a[2] += p0.z; a[3] += p0.w;               \
        a[4] += p1.x; a[5] += p1.y; a[6] += p1.z; a[7] += p1.w;               \
    }

// gather (4 lanes/node, 4-deep idx prefetch) + fused layer epilogue
__global__ __launch_bounds__(NT) void k_gather_layer(const int* __restrict__ rowst,
                                                     const int* __restrict__ csr,
                                                     const float* __restrict__ dis,
                                                     const float* __restrict__ u,
                                                     const float* __restrict__ b,
                                                     const float* __restrict__ W,
                                                     float* __restrict__ un, int N) {
    int g = blockIdx.x * NT + threadIdx.x;
    int n = g >> 2, sub = g & 3;
    if (n >= N) return;
    int i = rowst[n] + sub, end = rowst[n + 1];
    float a[8];
#pragma unroll
    for (int k = 0; k < 8; ++k) a[k] = 0.0f;
    int s0 = 0, s1 = 0, s2 = 0, s3 = 0;
    bool run4 = (i + 12 < end);
    if (run4) { s0 = csr[i]; s1 = csr[i + 4]; s2 = csr[i + 8]; s3 = csr[i + 12]; }
    while (run4) {
        int ni = i + 16;
        bool nrun = (ni + 12 < end);
        int t0 = 0, t1 = 0, t2 = 0, t3 = 0;
        if (nrun) { t0 = csr[ni]; t1 = csr[ni + 4]; t2 = csr[ni + 8]; t3 = csr[ni + 12]; }
        GATHER8_BODY(s0); GATHER8_BODY(s1); GATHER8_BODY(s2); GATHER8_BODY(s3);
        i = ni; run4 = nrun; s0 = t0; s1 = t1; s2 = t2; s3 = t3;
    }
    for (; i + 4 < end; i += 8) {
        int q0 = csr[i], q1 = csr[i + 4];
        GATHER8_BODY(q0); GATHER8_BODY(q1);
    }
    if (i < end) { int q0 = csr[i]; GATHER8_BODY(q0); }
#pragma unroll
    for (int k = 0; k < 8; ++k) {
        a[k] += __shfl_xor(a[k], 1, 64);
        a[k] += __shfl_xor(a[k], 2, 64);
    }
    float va = sub == 0 ? a[0] : (sub == 1 ? a[2] : (sub == 2 ? a[4] : a[6]));
    float vb = sub == 0 ? a[1] : (sub == 1 ? a[3] : (sub == 2 ? a[5] : a[7]));
    float2 selfv = *reinterpret_cast<const float2*>(u + 8 * n + 2 * sub);
    va += selfv.x; vb += selfv.y;
    float dn = dis[n];
    float2 bb = *reinterpret_cast<const float2*>(b + 2 * sub);
    float g0 = va * dn + bb.x, g1 = vb * dn + bb.y;
    float h0 = g0 > 0.0f ? g0 : expm1f(g0);
    float h1 = g1 > 0.0f ? g1 : expm1f(g1);
    int base = (threadIdx.x & 63) & ~3;
    float hh0 = __shfl(h0, base + 0, 64), hh1 = __shfl(h1, base + 0, 64);
    float hh2 = __shfl(h0, base + 1, 64), hh3 = __shfl(h1, base + 1, 64);
    float hh4 = __shfl(h0, base + 2, 64), hh5 = __shfl(h1, base + 2, 64);
    float hh6 = __shfl(h0, base + 3, 64), hh7 = __shfl(h1, base + 3, 64);
    int fo = 2 * sub;
    float o0 = hh0 * W[0 * 8 + fo] + hh1 * W[1 * 8 + fo] + hh2 * W[2 * 8 + fo] +
               hh3 * W[3 * 8 + fo] + hh4 * W[4 * 8 + fo] + hh5 * W[5 * 8 + fo] +
               hh6 * W[6 * 8 + fo] + hh7 * W[7 * 8 + fo];
    float o1 = hh0 * W[0 * 8 + fo + 1] + hh1 * W[1 * 8 + fo + 1] + hh2 * W[2 * 8 + fo + 1] +
               hh3 * W[3 * 8 + fo + 1] + hh4 * W[4 * 8 + fo + 1] + hh5 * W[5 * 8 + fo + 1] +
               hh6 * W[6 * 8 + fo + 1] + hh7 * W[7 * 8 + fo + 1];
    *reinterpret_cast<float2*>(un + 8 * n + fo) = make_float2(dn * o0, dn * o1);
}

// gather + fused head projections
__global__ __launch_bounds__(NT) void k_gather_head(const int* __restrict__ rowst,
                                                    const int* __restrict__ csr,
                                                    const float* __restrict__ dis,
                                                    const float* __restrict__ u,
                                                    const float* __restrict__ b,
                                                    const float* __restrict__ Wv,
                                                    const float* __restrict__ Wp,
                                                    float* __restrict__ uH, int N) {
    int g = blockIdx.x * NT + threadIdx.x;
    int n = g >> 2, sub = g & 3;
    if (n >= N) return;
    int i = rowst[n] + sub, end = rowst[n + 1];
    float a[8];
#pragma unroll
    for (int k = 0; k < 8; ++k) a[k] = 0.0f;
    int s0 = 0, s1 = 0, s2 = 0, s3 = 0;
    bool run4 = (i + 12 < end);
    if (run4) { s0 = csr[i]; s1 = csr[i + 4]; s2 = csr[i + 8]; s3 = csr[i + 12]; }
    while (run4) {
        int ni = i + 16;
        bool nrun = (ni + 12 < end);
        int t0 = 0, t1 = 0, t2 = 0, t3 = 0;
        if (nrun) { t0 = csr[ni]; t1 = csr[ni + 4]; t2 = csr[ni + 8]; t3 = csr[ni + 12]; }
        GATHER8_BODY(s0); GATHER8_BODY(s1); GATHER8_BODY(s2); GATHER8_BODY(s3);
        i = ni; run4 = nrun; s0 = t0; s1 = t1; s2 = t2; s3 = t3;
    }
    for (; i + 4 < end; i += 8) {
        int q0 = csr[i], q1 = csr[i + 4];
        GATHER8_BODY(q0); GATHER8_BODY(q1);
    }
    if (i < end) { int q0 = csr[i]; GATHER8_BODY(q0); }
#pragma unroll
    for (int k = 0; k < 8; ++k) {
        a[k] += __shfl_xor(a[k], 1, 64);
        a[k] += __shfl_xor(a[k], 2, 64);
    }
    float va = sub == 0 ? a[0] : (sub == 1 ? a[2] : (sub == 2 ? a[4] : a[6]));
    float vb = sub == 0 ? a[1] : (sub == 1 ? a[3] : (sub == 2 ? a[5] : a[7]));
    float2 selfv = *reinterpret_cast<const float2*>(u + 8 * n + 2 * sub);
    va += selfv.x; vb += selfv.y;
    float dn = dis[n];
    float2 bb = *reinterpret_cast<const float2*>(b + 2 * sub);
    float g0 = va * dn + bb.x, g1 = vb * dn + bb.y;
    float h0 = g0 > 0.0f ? g0 : expm1f(g0);
    float h1 = g1 > 0.0f ? g1 : expm1f(g1);
    float tvp = h0 * Wv[2 * sub] + h1 * Wv[2 * sub + 1];
    float tpp = h0 * Wp[2 * sub] + h1 * Wp[2 * sub + 1];
    tvp += __shfl_xor(tvp, 1, 64); tvp += __shfl_xor(tvp, 2, 64);
    tpp += __shfl_xor(tpp, 1, 64); tpp += __shfl_xor(tpp, 2, 64);
    if (sub == 0)
        *reinterpret_cast<float2*>(uH + 2 * n) = make_float2(dn * tvp, dn * tpp);
}

// final 2-wide gather: proba out + value block-reduce
__global__ __launch_bounds__(NT) void k_gather2n(const int* __restrict__ rowst,
                                                 const int* __restrict__ csr,
                                                 const float* __restrict__ dis,
                                                 const float* __restrict__ uH,
                                                 const float* __restrict__ bp,
                                                 float* __restrict__ out,
                                                 float* __restrict__ vsum, int N) {
    int g = blockIdx.x * NT + threadIdx.x;
    int n = g >> 2, sub = g & 3;
    bool valid = n < N;
    int i = 0, end = 0;
    if (valid) { i = rowst[n] + sub; end = rowst[n + 1]; }
    float av = 0.0f, ap = 0.0f;
    int s0 = 0, s1 = 0, s2 = 0, s3 = 0;
    bool run4 = (i + 12 < end);
    if (run4) { s0 = csr[i]; s1 = csr[i + 4]; s2 = csr[i + 8]; s3 = csr[i + 12]; }
    while (run4) {
        int ni = i + 16;
        bool nrun = (ni + 12 < end);
        int t0 = 0, t1 = 0, t2 = 0, t3 = 0;
        if (nrun) { t0 = csr[ni]; t1 = csr[ni + 4]; t2 = csr[ni + 8]; t3 = csr[ni + 12]; }
        float2 p0 = *reinterpret_cast<const float2*>(uH + 2 * s0);
        float2 p1 = *reinterpret_cast<const float2*>(uH + 2 * s1);
        float2 p2 = *reinterpret_cast<const float2*>(uH + 2 * s2);
        float2 p3 = *reinterpret_cast<const float2*>(uH + 2 * s3);
        av += p0.x + p1.x + p2.x + p3.x;
        ap += p0.y + p1.y + p2.y + p3.y;
        i = ni; run4 = nrun; s0 = t0; s1 = t1; s2 = t2; s3 = t3;
    }
    for (; i + 4 < end; i += 8) {
        int q0 = csr[i], q1 = csr[i + 4];
        float2 p = *reinterpret_cast<const float2*>(uH + 2 * q0);
        float2 q = *reinterpret_cast<const float2*>(uH + 2 * q1);
        av += p.x + q.x; ap += p.y + q.y;
    }
    if (i < end) {
        int q0 = csr[i];
        float2 p = *reinterpret_cast<const float2*>(uH + 2 * q0);
        av += p.x; ap += p.y;
    }
    av += __shfl_xor(av, 1, 64); av += __shfl_xor(av, 2, 64);
    ap += __shfl_xor(ap, 1, 64); ap += __shfl_xor(ap, 2, 64);
    float contrib = 0.0f;
    if (valid && sub == 0) {
        float2 selfv = *reinterpret_cast<const float2*>(uH + 2 * n);
        av += selfv.x; ap += selfv.y;
        float dn = dis[n];
        out[n] = ap * dn + bp[0];
        contrib = av * dn;
    }
#pragma unroll
    for (int o = 32; o > 0; o >>= 1) contrib += __shfl_down(contrib, o, 64);
    __shared__ float sred[NT / 64];
    if ((threadIdx.x & 63) == 0) sred[threadIdx.x >> 6] = contrib;
    __syncthreads();
    if (threadIdx.x == 0) {
        float bsum = 0.0f;
#pragma unroll
        for (int k = 0; k < NT / 64; ++k) bsum += sred[k];
        atomicAdd(vsum, bsum);
    }
}

__global__ void k_final(const float* __restrict__ vsum,
                        const float* __restrict__ bv,
                        float* __restrict__ out, int N) {
    out[0] = vsum[0] * (1.0f / (float)N) + bv[0];
}

// ============== fallback: round-2 two-pass exact-CSR build ==============

__global__ __launch_bounds__(NT) void k_count(const int* __restrict__ dst,
                                              int* __restrict__ deg, int E) {
    int e = blockIdx.x * NT + threadIdx.x;
    if (e < E) atomicAdd(&deg[dst[e]], 1);
}

__global__ __launch_bounds__(NT) void k_scanA(const int* __restrict__ deg,
                                              int* __restrict__ partial, int N) {
    int t = threadIdx.x;
    int base = blockIdx.x * CHUNK + t * 4;
    int s = 0;
#pragma unroll
    for (int j = 0; j < 4; ++j) { int i = base + j; if (i < N) s += deg[i]; }
    __shared__ int red[NT];
    red[t] = s; __syncthreads();
    for (int o = NT / 2; o > 0; o >>= 1) {
        if (t < o) red[t] += red[t + o];
        __syncthreads();
    }
    if (t == 0) partial[blockIdx.x] = red[0];
}

__global__ void k_scanB(const int* __restrict__ partial, int* __restrict__ chunkoff,
                        int* __restrict__ rowst, int nblk, int N) {
    if (threadIdx.x == 0) {
        int off = 0;
        for (int b = 0; b < nblk; ++b) { chunkoff[b] = off; off += partial[b]; }
        rowst[N] = off;
    }
}

__global__ __launch_bounds__(NT) void k_scanC(const int* __restrict__ deg,
                                              const int* __restrict__ chunkoff,
                                              int* __restrict__ rowst,
                                              float* __restrict__ dis, int N) {
    int t = threadIdx.x;
    int base = blockIdx.x * CHUNK + t * 4;
    int v[4]; int tsum = 0;
#pragma unroll
    for (int j = 0; j < 4; ++j) { int i = base + j; v[j] = (i < N) ? deg[i] : 0; tsum += v[j]; }
    __shared__ int ss[NT];
    ss[t] = tsum; __syncthreads();
    for (int o = 1; o < NT; o <<= 1) {
        int x = (t >= o) ? ss[t - o] : 0;
        __syncthreads();
        ss[t] += x;
        __syncthreads();
    }
    int run = ss[t] - tsum + chunkoff[blockIdx.x];
#pragma unroll
    for (int j = 0; j < 4; ++j) {
        int i = base + j;
        if (i < N) { rowst[i] = run; dis[i] = rsqrtf((float)v[j] + 1.0f); run += v[j]; }
    }
}

__global__ __launch_bounds__(NT) void k_fill(const int* __restrict__ src,
                                             const int* __restrict__ dst,
                                             const int* __restrict__ rowst,
                                             int* __restrict__ deg,
                                             int* __restrict__ csr, int E) {
    int e = blockIdx.x * NT + threadIdx.x;
    if (e >= E) return;
    int s = src[e], d = dst[e];
    int old = atomicSub(&deg[d], 1);
    csr[rowst[d] + old - 1] = s;
}

// ================================ launch ================================

extern "C" void kernel_launch(void* const* d_in, const int* in_sizes, int n_in,
                              void* d_out, int out_size, void* d_ws, size_t ws_size,
                              hipStream_t stream) {
    const float* x  = (const float*)d_in[0];
    const int* ei   = (const int*)d_in[1];
    const float* W0 = (const float*)d_in[2];
    const float* b0 = (const float*)d_in[3];
    const float* W1 = (const float*)d_in[4];
    const float* b1 = (const float*)d_in[5];
    const float* W2 = (const float*)d_in[6];
    const float* b2 = (const float*)d_in[7];
    const float* W3 = (const float*)d_in[8];
    const float* b3 = (const float*)d_in[9];
    const float* Wv = (const float*)d_in[10];
    const float* bv = (const float*)d_in[11];
    const float* Wp = (const float*)d_in[12];
    const float* bp = (const float*)d_in[13];
    float* out = (float*)d_out;

    int N = in_sizes[0] / 2;
    int E = in_sizes[1] / 2;
    const int* src = ei;
    const int* dst = ei + E;
    int NB = (N + 255) >> 8;

    size_t needP = ((size_t)18 * N + 2 * (size_t)E + 2048) * 4;
    bool histFits = (size_t)2 * PBLK2 * NB <= (size_t)E;  // histB+cursorT inside csr

    if (N <= 131072 && NB <= 512 && ws_size >= needP && histFits) {
        int* tot    = (int*)d_ws;                   // 512
        int* bbase  = tot + 512;                    // 513
        float* vsum = (float*)(bbase + 513);        // 8
        int* rowst  = (int*)(vsum + 8);             // N+1
        float* dis  = (float*)(rowst + N + 1);      // N
        float* uA   = dis + N;                      // 8N
        float* uB   = uA + (size_t)8 * N;           // 8N
        int* part   = (int*)(uB + (size_t)8 * N);   // E
        int* csr    = part + (size_t)E;             // E
        int* histB   = csr;                         // PBLK2*NB (scratch inside csr)
        int* cursorT = csr + (size_t)PBLK2 * NB;    // PBLK2*NB

        hipMemsetAsync(vsum, 0, 4, stream);

        k_histB<<<PBLK2, 256, 0, stream>>>(dst, histB, E, NB);
        k_scanB2<<<NB, 256, 0, stream>>>(histB, cursorT, tot, NB, PBLK2);
        k_bscan<<<1, 512, 0, stream>>>(tot, bbase, tot, rowst, NB, N, E);
        k_partF<<<PBLK2, 256, 0, stream>>>(src, dst, bbase, cursorT, part, E, NB);
        k_build<<<NB, 512, 0, stream>>>(bbase, part, rowst, dis, csr, N);

        k_node0n<<<nbi(N), NT, 0, stream>>>(x, W0, dis, uA, N);
        k_gather_layer<<<nbi(4LL * N), NT, 0, stream>>>(rowst, csr, dis, uA, b0, W1, uB, N);
        k_gather_layer<<<nbi(4LL * N), NT, 0, stream>>>(rowst, csr, dis, uB, b1, W2, uA, N);
        k_gather_layer<<<nbi(4LL * N), NT, 0, stream>>>(rowst, csr, dis, uA, b2, W3, uB, N);
        k_gather_head<<<nbi(4LL * N), NT, 0, stream>>>(rowst, csr, dis, uB, b3, Wv, Wp, uA, N);
        k_gather2n<<<nbi(4LL * N), NT, 0, stream>>>(rowst, csr, dis, uA, bp, out, vsum, N);
        k_final<<<1, 1, 0, stream>>>(vsum, bv, out + N, N);
    } else {
        // ---- fallback: two-pass exact CSR (round-2 path) ----
        int nblk = (N + CHUNK - 1) / CHUNK;
        int* deg      = (int*)d_ws;
        int* rowst    = deg + N;
        int* chunkoff = rowst + N + 1;
        int* partial  = chunkoff + nblk;
        float* dis    = (float*)(partial + nblk);
        float* vsum   = dis + N;
        float* uA     = vsum + 8;
        float* uB     = uA + (size_t)8 * N;
        int* csr      = (int*)(uB + (size_t)8 * N);

        hipMemsetAsync(deg, 0, (size_t)N * 4, stream);
        hipMemsetAsync(vsum, 0, 4, stream);

        k_count<<<nbi(E), NT, 0, stream>>>(dst, deg, E);
        k_scanA<<<nblk, NT, 0, stream>>>(deg, partial, N);
        k_scanB<<<1, 64, 0, stream>>>(partial, chunkoff, rowst, nblk, N);
        k_scanC<<<nblk, NT, 0, stream>>>(deg, chunkoff, rowst, dis, N);
        k_fill<<<nbi(E), NT, 0, stream>>>(src, dst, rowst, deg, csr, E);

        k_node0n<<<nbi(N), NT, 0, stream>>>(x, W0, dis, uA, N);
        k_gather_layer<<<nbi(4LL * N), NT, 0, stream>>>(rowst, csr, dis, uA, b0, W1, uB, N);
        k_gather_layer<<<nbi(4LL * N), NT, 0, stream>>>(rowst, csr, dis, uB, b1, W2, uA, N);
        k_gather_layer<<<nbi(4LL * N), NT, 0, stream>>>(rowst, csr, dis, uA, b2, W3, uB, N);
        k_gather_head<<<nbi(4LL * N), NT, 0, stream>>>(rowst, csr, dis, uB, b3, Wv, Wp, uA, N);
        k_gather2n<<<nbi(4LL * N), NT, 0, stream>>>(rowst, csr, dis, uA, bp, out, vsum, N);
        k_final<<<1, 1, 0, stream>>>(vsum, bv, out + N, N);
    }
}

// Round 7
// 355.765 us; speedup vs baseline: 31.5609x; 1.0576x over previous
//
#include <hip/hip_runtime.h>

#define NT 256
#define CHUNK 1024
#define PBLK2 2048  // blocks for hist/partition passes
#define PTILE 4096  // staged partition tile (edges)

static inline int nbi(long long n) { return (int)((n + NT - 1) / NT); }

// ===================== bucket-partition CSR build =====================
// buckets of 256 nodes: bucket = dst >> 8, d_local = dst & 255
// packed entry = (d_local << 17) | src   (requires N <= 131072)

__global__ __launch_bounds__(256) void k_histB(const int* __restrict__ dst,
                                               int* __restrict__ histB,
                                               int E, int NB) {
    __shared__ int lh[512];
    int t = threadIdx.x;
    for (int i = t; i < 512; i += 256) lh[i] = 0;
    __syncthreads();
    int chunk = (E + gridDim.x - 1) / gridDim.x;
    int lo = blockIdx.x * chunk, hi = min(E, lo + chunk);
    for (int i = lo + t; i < hi; i += 256)
        atomicAdd(&lh[dst[i] >> 8], 1);
    __syncthreads();
    for (int b = t; b < NB; b += 256)
        histB[(size_t)blockIdx.x * NB + b] = lh[b];
}

__global__ __launch_bounds__(256) void k_scanB2(const int* __restrict__ histB,
                                                int* __restrict__ cursorT,
                                                int* __restrict__ tot,
                                                int NB, int nblk) {
    __shared__ int ch[256];
    __shared__ int carry;
    int b = blockIdx.x, t = threadIdx.x;
    if (t == 0) carry = 0;
    __syncthreads();
    for (int c = 0; c < nblk; c += 256) {
        int blk = c + t;
        int v = (blk < nblk) ? histB[(size_t)blk * NB + b] : 0;
        ch[t] = v;
        __syncthreads();
        for (int o = 1; o < 256; o <<= 1) {
            int x = (t >= o) ? ch[t - o] : 0;
            __syncthreads();
            ch[t] += x;
            __syncthreads();
        }
        int excl = ch[t] - v + carry;
        if (blk < nblk) cursorT[(size_t)b * PBLK2 + blk] = excl;
        __syncthreads();
        if (t == 0) carry += ch[255];
        __syncthreads();
    }
    if (t == 0) tot[b] = carry;
}

__global__ __launch_bounds__(512) void k_bscan(const int* __restrict__ hist_g,
                                               int* __restrict__ bbase,
                                               int* __restrict__ rowst,
                                               int NB, int N, int E) {
    __shared__ int s[512];
    int t = threadIdx.x;
    int own = (t < NB) ? hist_g[t] : 0;
    s[t] = own;
    __syncthreads();
    for (int o = 1; o < 512; o <<= 1) {
        int v = (t >= o) ? s[t - o] : 0;
        __syncthreads();
        s[t] += v;
        __syncthreads();
    }
    if (t < NB) bbase[t] = s[t] - own;
    if (t == 0) { bbase[NB] = E; rowst[N] = E; }
}

__global__ __launch_bounds__(256) void k_partF(const int* __restrict__ src,
                                               const int* __restrict__ dst,
                                               const int* __restrict__ bbase,
                                               const int* __restrict__ cursorT,
                                               int* __restrict__ part,
                                               int E, int NB) {
    __shared__ int wcur[512];
    __shared__ int th[512], tloff[512], tcnt[512];
    __shared__ int ps[256];
    __shared__ int stage[PTILE];
    __shared__ unsigned short sbkt[PTILE];
    int t = threadIdx.x;
    int chunk = (E + gridDim.x - 1) / gridDim.x;
    int lo = blockIdx.x * chunk, hi = min(E, lo + chunk);
    if (lo >= hi) return;

    for (int b = t; b < NB; b += 256)
        wcur[b] = bbase[b] + cursorT[(size_t)b * PBLK2 + blockIdx.x];
    __syncthreads();

    for (int tlo = lo; tlo < hi; tlo += PTILE) {
        int thi = min(hi, tlo + PTILE);
        int cnt = thi - tlo;
        for (int i = t; i < 512; i += 256) { th[i] = 0; tcnt[i] = 0; }
        __syncthreads();
        for (int i = tlo + t; i < thi; i += 256) atomicAdd(&th[dst[i] >> 8], 1);
        __syncthreads();
        int a0 = th[2 * t], a1 = th[2 * t + 1];
        int psum = a0 + a1;
        ps[t] = psum;
        __syncthreads();
        for (int o = 1; o < 256; o <<= 1) {
            int v = (t >= o) ? ps[t - o] : 0;
            __syncthreads();
            ps[t] += v;
            __syncthreads();
        }
        int excl = ps[t] - psum;
        tloff[2 * t] = excl;
        tloff[2 * t + 1] = excl + a0;
        __syncthreads();
        for (int i = tlo + t; i < thi; i += 256) {
            int d = dst[i], s = src[i];
            int b = d >> 8;
            int pos = tloff[b] + atomicAdd(&tcnt[b], 1);
            stage[pos] = ((d & 255) << 17) | s;
            sbkt[pos] = (unsigned short)b;
        }
        __syncthreads();
        for (int i = t; i < cnt; i += 256) {
            int b = sbkt[i];
            part[wcur[b] + (i - tloff[b])] = stage[i];
        }
        __syncthreads();
        for (int b = t; b < NB; b += 256) wcur[b] += th[b];
        __syncthreads();
    }
}

// one block/bucket: LDS count -> scan -> rowst/dis/v0 -> place csr
__global__ __launch_bounds__(512) void k_build(const int* __restrict__ bbase,
                                               const int* __restrict__ part,
                                               const float* __restrict__ x,
                                               int* __restrict__ rowst,
                                               float* __restrict__ dis,
                                               float* __restrict__ v0,
                                               int* __restrict__ csr,
                                               int N) {
    __shared__ int dcnt[256], doff[256];
    int b = blockIdx.x, t = threadIdx.x;
    int lo = bbase[b], hi = bbase[b + 1];
    if (t < 256) dcnt[t] = 0;
    __syncthreads();
    for (int i = lo + t; i < hi; i += 512)
        atomicAdd(&dcnt[part[i] >> 17], 1);
    __syncthreads();
    int own = 0;
    if (t < 256) { own = dcnt[t]; doff[t] = own; }
    __syncthreads();
    for (int o = 1; o < 256; o <<= 1) {
        int v = 0;
        if (t < 256 && t >= o) v = doff[t - o];
        __syncthreads();
        if (t < 256) doff[t] += v;
        __syncthreads();
    }
    if (t < 256) {
        int excl = doff[t] - own;
        int node = (b << 8) + t;
        if (node < N) {
            rowst[node] = lo + excl;
            float dn = rsqrtf((float)own + 1.0f);
            dis[node] = dn;
            float2 xv = *reinterpret_cast<const float2*>(x + 2 * node);
            *reinterpret_cast<float2*>(v0 + 2 * node) = make_float2(dn * xv.x, dn * xv.y);
        }
        dcnt[t] = excl;
    }
    __syncthreads();
    for (int i = lo + t; i < hi; i += 512) {
        int pv = part[i];
        int slot = atomicAdd(&dcnt[pv >> 17], 1);
        csr[lo + slot] = pv & 0x1FFFF;
    }
}

// ===================== gather kernels (8 lanes/node) =====================

// pass 1: gather 2-wide v0; epilogue applies W0,b0 then W1 -> u1 (8-wide)
__global__ __launch_bounds__(NT) void k_gL1(const int* __restrict__ rowst,
                                            const int* __restrict__ csr,
                                            const float* __restrict__ dis,
                                            const float* __restrict__ v0,
                                            const float* __restrict__ W0,
                                            const float* __restrict__ b0,
                                            const float* __restrict__ W1,
                                            float* __restrict__ un, int N) {
    int g = blockIdx.x * NT + threadIdx.x;
    int n = g >> 3, sub = g & 7;
    if (n >= N) return;
    int i = rowst[n] + sub, end = rowst[n + 1];
    float ax = 0.0f, ay = 0.0f;
    int s0 = 0, s1 = 0;
    bool r0 = i < end, r1 = i + 8 < end;
    if (r0) s0 = csr[i];
    if (r1) s1 = csr[i + 8];
    while (r0) {
        float2 p = *reinterpret_cast<const float2*>(v0 + 2 * s0);
        int i2 = i + 16;
        bool r2 = i2 < end;
        int s2 = 0; if (r2) s2 = csr[i2];
        ax += p.x; ay += p.y;
        i += 8; r0 = r1; s0 = s1; r1 = r2; s1 = s2;
    }
    ax += __shfl_xor(ax, 1, 64); ax += __shfl_xor(ax, 2, 64); ax += __shfl_xor(ax, 4, 64);
    ay += __shfl_xor(ay, 1, 64); ay += __shfl_xor(ay, 2, 64); ay += __shfl_xor(ay, 4, 64);
    float2 sv = *reinterpret_cast<const float2*>(v0 + 2 * n);
    ax += sv.x; ay += sv.y;
    float dn = dis[n];
    float gg = dn * (ax * W0[sub] + ay * W0[8 + sub]) + b0[sub];
    float h = gg > 0.0f ? gg : expm1f(gg);
    int base = (threadIdx.x & 63) & ~7;
    float o = 0.0f;
#pragma unroll
    for (int k = 0; k < 8; ++k) o += __shfl(h, base + k, 64) * W1[k * 8 + sub];
    un[8 * n + sub] = dn * o;
}

// mid pass: gather 8-wide u; reduce-scatter; epilogue bias+elu+W -> un
__global__ __launch_bounds__(NT) void k_gL8(const int* __restrict__ rowst,
                                            const int* __restrict__ csr,
                                            const float* __restrict__ dis,
                                            const float* __restrict__ u,
                                            const float* __restrict__ b,
                                            const float* __restrict__ W,
                                            float* __restrict__ un, int N) {
    int g = blockIdx.x * NT + threadIdx.x;
    int n = g >> 3, sub = g & 7;
    if (n >= N) return;
    int i = rowst[n] + sub, end = rowst[n + 1];
    float a[8];
#pragma unroll
    for (int k = 0; k < 8; ++k) a[k] = 0.0f;
    int s0 = 0, s1 = 0;
    bool r0 = i < end, r1 = i + 8 < end;
    if (r0) s0 = csr[i];
    if (r1) s1 = csr[i + 8];
    while (r0) {
        float4 p0 = *reinterpret_cast<const float4*>(u + 8 * s0);
        float4 p1 = *reinterpret_cast<const float4*>(u + 8 * s0 + 4);
        int i2 = i + 16;
        bool r2 = i2 < end;
        int s2 = 0; if (r2) s2 = csr[i2];
        a[0] += p0.x; a[1] += p0.y; a[2] += p0.z; a[3] += p0.w;
        a[4] += p1.x; a[5] += p1.y; a[6] += p1.z; a[7] += p1.w;
        i += 8; r0 = r1; s0 = s1; r1 = r2; s1 = s2;
    }
    // reduce-scatter butterfly: lane sub ends owning feature sub in a[0]
    int c4 = sub & 4, c2 = sub & 2, c1 = sub & 1;
#pragma unroll
    for (int j = 0; j < 4; ++j) {
        float send = c4 ? a[j] : a[j + 4];
        float recv = __shfl_xor(send, 4, 64);
        a[j] = (c4 ? a[j + 4] : a[j]) + recv;
    }
#pragma unroll
    for (int j = 0; j < 2; ++j) {
        float send = c2 ? a[j] : a[j + 2];
        float recv = __shfl_xor(send, 2, 64);
        a[j] = (c2 ? a[j + 2] : a[j]) + recv;
    }
    {
        float send = c1 ? a[0] : a[1];
        float recv = __shfl_xor(send, 1, 64);
        a[0] = (c1 ? a[1] : a[0]) + recv;
    }
    float dn = dis[n];
    float va = a[0] + u[8 * n + sub];
    float gg = va * dn + b[sub];
    float h = gg > 0.0f ? gg : expm1f(gg);
    int base = (threadIdx.x & 63) & ~7;
    float o = 0.0f;
#pragma unroll
    for (int k = 0; k < 8; ++k) o += __shfl(h, base + k, 64) * W[k * 8 + sub];
    un[8 * n + sub] = dn * o;
}

// head pass: gather 8-wide u3; epilogue b3+elu then Wv/Wp -> uH (2-wide)
__global__ __launch_bounds__(NT) void k_gHead(const int* __restrict__ rowst,
                                              const int* __restrict__ csr,
                                              const float* __restrict__ dis,
                                              const float* __restrict__ u,
                                              const float* __restrict__ b,
                                              const float* __restrict__ Wv,
                                              const float* __restrict__ Wp,
                                              float* __restrict__ uH, int N) {
    int g = blockIdx.x * NT + threadIdx.x;
    int n = g >> 3, sub = g & 7;
    if (n >= N) return;
    int i = rowst[n] + sub, end = rowst[n + 1];
    float a[8];
#pragma unroll
    for (int k = 0; k < 8; ++k) a[k] = 0.0f;
    int s0 = 0, s1 = 0;
    bool r0 = i < end, r1 = i + 8 < end;
    if (r0) s0 = csr[i];
    if (r1) s1 = csr[i + 8];
    while (r0) {
        float4 p0 = *reinterpret_cast<const float4*>(u + 8 * s0);
        float4 p1 = *reinterpret_cast<const float4*>(u + 8 * s0 + 4);
        int i2 = i + 16;
        bool r2 = i2 < end;
        int s2 = 0; if (r2) s2 = csr[i2];
        a[0] += p0.x; a[1] += p0.y; a[2] += p0.z; a[3] += p0.w;
        a[4] += p1.x; a[5] += p1.y; a[6] += p1.z; a[7] += p1.w;
        i += 8; r0 = r1; s0 = s1; r1 = r2; s1 = s2;
    }
    int c4 = sub & 4, c2 = sub & 2, c1 = sub & 1;
#pragma unroll
    for (int j = 0; j < 4; ++j) {
        float send = c4 ? a[j] : a[j + 4];
        float recv = __shfl_xor(send, 4, 64);
        a[j] = (c4 ? a[j + 4] : a[j]) + recv;
    }
#pragma unroll
    for (int j = 0; j < 2; ++j) {
        float send = c2 ? a[j] : a[j + 2];
        float recv = __shfl_xor(send, 2, 64);
        a[j] = (c2 ? a[j + 2] : a[j]) + recv;
    }
    {
        float send = c1 ? a[0] : a[1];
        float recv = __shfl_xor(send, 1, 64);
        a[0] = (c1 ? a[1] : a[0]) + recv;
    }
    float dn = dis[n];
    float va = a[0] + u[8 * n + sub];
    float gg = va * dn + b[sub];
    float h = gg > 0.0f ? gg : expm1f(gg);
    float tv = h * Wv[sub];
    float tp = h * Wp[sub];
    tv += __shfl_xor(tv, 1, 64); tv += __shfl_xor(tv, 2, 64); tv += __shfl_xor(tv, 4, 64);
    tp += __shfl_xor(tp, 1, 64); tp += __shfl_xor(tp, 2, 64); tp += __shfl_xor(tp, 4, 64);
    if (sub == 0)
        *reinterpret_cast<float2*>(uH + 2 * n) = make_float2(dn * tv, dn * tp);
}

// final: gather 2-wide uH -> proba out + value reduce
__global__ __launch_bounds__(NT) void k_g2F(const int* __restrict__ rowst,
                                            const int* __restrict__ csr,
                                            const float* __restrict__ dis,
                                            const float* __restrict__ uH,
                                            const float* __restrict__ bp,
                                            float* __restrict__ out,
                                            float* __restrict__ vsum, int N) {
    int g = blockIdx.x * NT + threadIdx.x;
    int n = g >> 3, sub = g & 7;
    bool valid = n < N;
    int i = 0, end = 0;
    if (valid) { i = rowst[n] + sub; end = rowst[n + 1]; }
    float av = 0.0f, ap = 0.0f;
    int s0 = 0, s1 = 0;
    bool r0 = i < end, r1 = i + 8 < end;
    if (r0) s0 = csr[i];
    if (r1) s1 = csr[i + 8];
    while (r0) {
        float2 p = *reinterpret_cast<const float2*>(uH + 2 * s0);
        int i2 = i + 16;
        bool r2 = i2 < end;
        int s2 = 0; if (r2) s2 = csr[i2];
        av += p.x; ap += p.y;
        i = i + 8; r0 = r1; s0 = s1; r1 = r2; s1 = s2;
    }
    av += __shfl_xor(av, 1, 64); av += __shfl_xor(av, 2, 64); av += __shfl_xor(av, 4, 64);
    ap += __shfl_xor(ap, 1, 64); ap += __shfl_xor(ap, 2, 64); ap += __shfl_xor(ap, 4, 64);
    float contrib = 0.0f;
    if (valid && sub == 0) {
        float2 selfv = *reinterpret_cast<const float2*>(uH + 2 * n);
        av += selfv.x; ap += selfv.y;
        float dn = dis[n];
        out[n] = ap * dn + bp[0];
        contrib = av * dn;
    }
#pragma unroll
    for (int o = 32; o > 0; o >>= 1) contrib += __shfl_down(contrib, o, 64);
    __shared__ float sred[NT / 64];
    if ((threadIdx.x & 63) == 0) sred[threadIdx.x >> 6] = contrib;
    __syncthreads();
    if (threadIdx.x == 0) {
        float bsum = 0.0f;
#pragma unroll
        for (int k = 0; k < NT / 64; ++k) bsum += sred[k];
        atomicAdd(vsum, bsum);
    }
}

__global__ void k_final(const float* __restrict__ vsum,
                        const float* __restrict__ bv,
                        float* __restrict__ out, int N) {
    out[0] = vsum[0] * (1.0f / (float)N) + bv[0];
}

// ============== fallback: two-pass exact-CSR build ==============

__global__ __launch_bounds__(NT) void k_count(const int* __restrict__ dst,
                                              int* __restrict__ deg, int E) {
    int e = blockIdx.x * NT + threadIdx.x;
    if (e < E) atomicAdd(&deg[dst[e]], 1);
}

__global__ __launch_bounds__(NT) void k_scanA(const int* __restrict__ deg,
                                              int* __restrict__ partial, int N) {
    int t = threadIdx.x;
    int base = blockIdx.x * CHUNK + t * 4;
    int s = 0;
#pragma unroll
    for (int j = 0; j < 4; ++j) { int i = base + j; if (i < N) s += deg[i]; }
    __shared__ int red[NT];
    red[t] = s; __syncthreads();
    for (int o = NT / 2; o > 0; o >>= 1) {
        if (t < o) red[t] += red[t + o];
        __syncthreads();
    }
    if (t == 0) partial[blockIdx.x] = red[0];
}

__global__ void k_scanB(const int* __restrict__ partial, int* __restrict__ chunkoff,
                        int* __restrict__ rowst, int nblk, int N) {
    if (threadIdx.x == 0) {
        int off = 0;
        for (int b = 0; b < nblk; ++b) { chunkoff[b] = off; off += partial[b]; }
        rowst[N] = off;
    }
}

__global__ __launch_bounds__(NT) void k_scanC(const int* __restrict__ deg,
                                              const int* __restrict__ chunkoff,
                                              int* __restrict__ rowst,
                                              float* __restrict__ dis, int N) {
    int t = threadIdx.x;
    int base = blockIdx.x * CHUNK + t * 4;
    int v[4]; int tsum = 0;
#pragma unroll
    for (int j = 0; j < 4; ++j) { int i = base + j; v[j] = (i < N) ? deg[i] : 0; tsum += v[j]; }
    __shared__ int ss[NT];
    ss[t] = tsum; __syncthreads();
    for (int o = 1; o < NT; o <<= 1) {
        int x = (t >= o) ? ss[t - o] : 0;
        __syncthreads();
        ss[t] += x;
        __syncthreads();
    }
    int run = ss[t] - tsum + chunkoff[blockIdx.x];
#pragma unroll
    for (int j = 0; j < 4; ++j) {
        int i = base + j;
        if (i < N) { rowst[i] = run; dis[i] = rsqrtf((float)v[j] + 1.0f); run += v[j]; }
    }
}

__global__ __launch_bounds__(NT) void k_fill(const int* __restrict__ src,
                                             const int* __restrict__ dst,
                                             const int* __restrict__ rowst,
                                             int* __restrict__ deg,
                                             int* __restrict__ csr, int E) {
    int e = blockIdx.x * NT + threadIdx.x;
    if (e >= E) return;
    int s = src[e], d = dst[e];
    int old = atomicSub(&deg[d], 1);
    csr[rowst[d] + old - 1] = s;
}

__global__ __launch_bounds__(NT) void k_v0(const float* __restrict__ x,
                                           const float* __restrict__ dis,
                                           float* __restrict__ v0, int N) {
    int n = blockIdx.x * NT + threadIdx.x;
    if (n >= N) return;
    float dn = dis[n];
    float2 xv = *reinterpret_cast<const float2*>(x + 2 * n);
    *reinterpret_cast<float2*>(v0 + 2 * n) = make_float2(dn * xv.x, dn * xv.y);
}

// ================================ launch ================================

extern "C" void kernel_launch(void* const* d_in, const int* in_sizes, int n_in,
                              void* d_out, int out_size, void* d_ws, size_t ws_size,
                              hipStream_t stream) {
    const float* x  = (const float*)d_in[0];
    const int* ei   = (const int*)d_in[1];
    const float* W0 = (const float*)d_in[2];
    const float* b0 = (const float*)d_in[3];
    const float* W1 = (const float*)d_in[4];
    const float* b1 = (const float*)d_in[5];
    const float* W2 = (const float*)d_in[6];
    const float* b2 = (const float*)d_in[7];
    const float* W3 = (const float*)d_in[8];
    const float* b3 = (const float*)d_in[9];
    const float* Wv = (const float*)d_in[10];
    const float* bv = (const float*)d_in[11];
    const float* Wp = (const float*)d_in[12];
    const float* bp = (const float*)d_in[13];
    float* out = (float*)d_out;

    int N = in_sizes[0] / 2;
    int E = in_sizes[1] / 2;
    const int* src = ei;
    const int* dst = ei + E;
    int NB = (N + 255) >> 8;

    size_t needP = ((size_t)22 * N + 2 * (size_t)E + 2048) * 4;
    bool histFits = (size_t)2 * PBLK2 * NB <= (size_t)E;

    if (N <= 131072 && NB <= 512 && ws_size >= needP && histFits) {
        int* tot    = (int*)d_ws;                   // 512
        int* bbase  = tot + 512;                    // 513
        float* vsum = (float*)(bbase + 513);        // 8
        int* rowst  = (int*)(vsum + 8);             // N+1
        float* dis  = (float*)(rowst + N + 1);      // N
        float* v0   = dis + N;                      // 2N
        float* uA   = v0 + (size_t)2 * N;           // 8N
        float* uB   = uA + (size_t)8 * N;           // 8N
        float* uH   = uB + (size_t)8 * N;           // 2N
        int* part   = (int*)(uH + (size_t)2 * N);   // E
        int* csr    = part + (size_t)E;             // E
        int* histB   = csr;                         // scratch inside csr
        int* cursorT = csr + (size_t)PBLK2 * NB;

        hipMemsetAsync(vsum, 0, 4, stream);

        k_histB<<<PBLK2, 256, 0, stream>>>(dst, histB, E, NB);
        k_scanB2<<<NB, 256, 0, stream>>>(histB, cursorT, tot, NB, PBLK2);
        k_bscan<<<1, 512, 0, stream>>>(tot, bbase, rowst, NB, N, E);
        k_partF<<<PBLK2, 256, 0, stream>>>(src, dst, bbase, cursorT, part, E, NB);
        k_build<<<NB, 512, 0, stream>>>(bbase, part, x, rowst, dis, v0, csr, N);

        k_gL1<<<nbi(8LL * N), NT, 0, stream>>>(rowst, csr, dis, v0, W0, b0, W1, uA, N);
        k_gL8<<<nbi(8LL * N), NT, 0, stream>>>(rowst, csr, dis, uA, b1, W2, uB, N);
        k_gL8<<<nbi(8LL * N), NT, 0, stream>>>(rowst, csr, dis, uB, b2, W3, uA, N);
        k_gHead<<<nbi(8LL * N), NT, 0, stream>>>(rowst, csr, dis, uA, b3, Wv, Wp, uH, N);
        k_g2F<<<nbi(8LL * N), NT, 0, stream>>>(rowst, csr, dis, uH, bp, out, vsum, N);
        k_final<<<1, 1, 0, stream>>>(vsum, bv, out + N, N);
    } else {
        // ---- fallback: two-pass exact CSR, same gather kernels ----
        int nblk = (N + CHUNK - 1) / CHUNK;
        int* deg      = (int*)d_ws;                 // N
        int* rowst    = deg + N;                    // N+1
        int* chunkoff = rowst + N + 1;              // nblk
        int* partial  = chunkoff + nblk;            // nblk
        float* dis    = (float*)(partial + nblk);   // N
        float* vsum   = dis + N;                    // 8
        float* v0     = vsum + 8;                   // 2N
        float* uA     = v0 + (size_t)2 * N;         // 8N
        float* uB     = uA + (size_t)8 * N;         // 8N
        float* uH     = uB + (size_t)8 * N;         // 2N
        int* csr      = (int*)(uH + (size_t)2 * N); // E

        hipMemsetAsync(deg, 0, (size_t)N * 4, stream);
        hipMemsetAsync(vsum, 0, 4, stream);

        k_count<<<nbi(E), NT, 0, stream>>>(dst, deg, E);
        k_scanA<<<nblk, NT, 0, stream>>>(deg, partial, N);
        k_scanB<<<1, 64, 0, stream>>>(partial, chunkoff, rowst, nblk, N);
        k_scanC<<<nblk, NT, 0, stream>>>(deg, chunkoff, rowst, dis, N);
        k_fill<<<nbi(E), NT, 0, stream>>>(src, dst, rowst, deg, csr, E);
        k_v0<<<nbi(N), NT, 0, stream>>>(x, dis, v0, N);

        k_gL1<<<nbi(8LL * N), NT, 0, stream>>>(rowst, csr, dis, v0, W0, b0, W1, uA, N);
        k_gL8<<<nbi(8LL * N), NT, 0, stream>>>(rowst, csr, dis, uA, b1, W2, uB, N);
        k_gL8<<<nbi(8LL * N), NT, 0, stream>>>(rowst, csr, dis, uB, b2, W3, uA, N);
        k_gHead<<<nbi(8LL * N), NT, 0, stream>>>(rowst, csr, dis, uA, b3, Wv, Wp, uH, N);
        k_g2F<<<nbi(8LL * N), NT, 0, stream>>>(rowst, csr, dis, uH, bp, out, vsum, N);
        k_final<<<1, 1, 0, stream>>>(vsum, bv, out + N, N);
    }
}

// Round 8
// 335.323 us; speedup vs baseline: 33.4850x; 1.0610x over previous
//
#include <hip/hip_runtime.h>

#define NT 256
#define CHUNK 1024
#define PBLK2 2048  // blocks for hist/partition passes
#define PTILE 4096  // staged partition tile (edges)

static inline int nbi(long long n) { return (int)((n + NT - 1) / NT); }

// ===================== bucket-partition CSR build =====================
// buckets of 256 nodes: bucket = dst >> 8, d_local = dst & 255
// packed entry = (d_local << 17) | src   (requires N <= 131072)

__global__ __launch_bounds__(256) void k_histB(const int* __restrict__ dst,
                                               int* __restrict__ histB,
                                               int E, int NB) {
    __shared__ int lh[512];
    int t = threadIdx.x;
    for (int i = t; i < 512; i += 256) lh[i] = 0;
    __syncthreads();
    int chunk = (E + gridDim.x - 1) / gridDim.x;
    int lo = blockIdx.x * chunk, hi = min(E, lo + chunk);
    for (int i = lo + t; i < hi; i += 256)
        atomicAdd(&lh[dst[i] >> 8], 1);
    __syncthreads();
    for (int b = t; b < NB; b += 256)
        histB[(size_t)blockIdx.x * NB + b] = lh[b];
}

__global__ __launch_bounds__(256) void k_scanB2(const int* __restrict__ histB,
                                                int* __restrict__ cursorT,
                                                int* __restrict__ tot,
                                                int NB, int nblk) {
    __shared__ int ch[256];
    __shared__ int carry;
    int b = blockIdx.x, t = threadIdx.x;
    if (t == 0) carry = 0;
    __syncthreads();
    for (int c = 0; c < nblk; c += 256) {
        int blk = c + t;
        int v = (blk < nblk) ? histB[(size_t)blk * NB + b] : 0;
        ch[t] = v;
        __syncthreads();
        for (int o = 1; o < 256; o <<= 1) {
            int x = (t >= o) ? ch[t - o] : 0;
            __syncthreads();
            ch[t] += x;
            __syncthreads();
        }
        int excl = ch[t] - v + carry;
        if (blk < nblk) cursorT[(size_t)b * PBLK2 + blk] = excl;
        __syncthreads();
        if (t == 0) carry += ch[255];
        __syncthreads();
    }
    if (t == 0) tot[b] = carry;
}

__global__ __launch_bounds__(512) void k_bscan(const int* __restrict__ hist_g,
                                               int* __restrict__ bbase,
                                               int* __restrict__ rowst,
                                               int NB, int N, int E) {
    __shared__ int s[512];
    int t = threadIdx.x;
    int own = (t < NB) ? hist_g[t] : 0;
    s[t] = own;
    __syncthreads();
    for (int o = 1; o < 512; o <<= 1) {
        int v = (t >= o) ? s[t - o] : 0;
        __syncthreads();
        s[t] += v;
        __syncthreads();
    }
    if (t < NB) bbase[t] = s[t] - own;
    if (t == 0) { bbase[NB] = E; rowst[N] = E; }
}

// single-tile partition: hist comes from histB (no per-edge recount)
__global__ __launch_bounds__(256) void k_partF(const int* __restrict__ src,
                                               const int* __restrict__ dst,
                                               const int* __restrict__ bbase,
                                               const int* __restrict__ histB,
                                               const int* __restrict__ cursorT,
                                               int* __restrict__ part,
                                               int E, int NB) {
    __shared__ int wadj[512], tloff[512], tcnt[512], ps[256];
    __shared__ int stage[PTILE];
    __shared__ unsigned short sbkt[PTILE];
    int t = threadIdx.x;
    int blk = blockIdx.x;
    int chunk = (E + gridDim.x - 1) / gridDim.x;
    int lo = blk * chunk, hi = min(E, lo + chunk);
    if (lo >= hi) return;
    int cnt = hi - lo;
    int b0 = 2 * t, b1 = 2 * t + 1;
    int v0c = (b0 < NB) ? histB[(size_t)blk * NB + b0] : 0;
    int v1c = (b1 < NB) ? histB[(size_t)blk * NB + b1] : 0;
    ps[t] = v0c + v1c;
    __syncthreads();
    for (int o = 1; o < 256; o <<= 1) {
        int v = (t >= o) ? ps[t - o] : 0;
        __syncthreads();
        ps[t] += v;
        __syncthreads();
    }
    int excl = ps[t] - v0c - v1c;
    tloff[b0] = excl;
    tloff[b1] = excl + v0c;
    tcnt[b0] = 0; tcnt[b1] = 0;
    if (b0 < NB) wadj[b0] = bbase[b0] + cursorT[(size_t)b0 * PBLK2 + blk] - excl;
    if (b1 < NB) wadj[b1] = bbase[b1] + cursorT[(size_t)b1 * PBLK2 + blk] - (excl + v0c);
    __syncthreads();
    for (int i = lo + t; i < hi; i += 256) {
        int d = dst[i], s = src[i];
        int b = d >> 8;
        int pos = tloff[b] + atomicAdd(&tcnt[b], 1);
        stage[pos] = ((d & 255) << 17) | s;
        sbkt[pos] = (unsigned short)b;
    }
    __syncthreads();
    for (int i = t; i < cnt; i += 256) {
        int b = sbkt[i];
        part[wadj[b] + i] = stage[i];
    }
}

// one block/bucket: LDS count -> scan -> rowst/dis/v0 -> place csr
__global__ __launch_bounds__(512) void k_build(const int* __restrict__ bbase,
                                               const int* __restrict__ part,
                                               const float* __restrict__ x,
                                               int* __restrict__ rowst,
                                               float* __restrict__ dis,
                                               float* __restrict__ v0,
                                               int* __restrict__ csr,
                                               int N) {
    __shared__ int dcnt[256], doff[256];
    int b = blockIdx.x, t = threadIdx.x;
    int lo = bbase[b], hi = bbase[b + 1];
    if (t < 256) dcnt[t] = 0;
    __syncthreads();
    for (int i = lo + t; i < hi; i += 512)
        atomicAdd(&dcnt[part[i] >> 17], 1);
    __syncthreads();
    int own = 0;
    if (t < 256) { own = dcnt[t]; doff[t] = own; }
    __syncthreads();
    for (int o = 1; o < 256; o <<= 1) {
        int v = 0;
        if (t < 256 && t >= o) v = doff[t - o];
        __syncthreads();
        if (t < 256) doff[t] += v;
        __syncthreads();
    }
    if (t < 256) {
        int excl = doff[t] - own;
        int node = (b << 8) + t;
        if (node < N) {
            rowst[node] = lo + excl;
            float dn = rsqrtf((float)own + 1.0f);
            dis[node] = dn;
            float2 xv = *reinterpret_cast<const float2*>(x + 2 * node);
            *reinterpret_cast<float2*>(v0 + 2 * node) = make_float2(dn * xv.x, dn * xv.y);
        }
        dcnt[t] = excl;
    }
    __syncthreads();
    for (int i = lo + t; i < hi; i += 512) {
        int pv = part[i];
        int slot = atomicAdd(&dcnt[pv >> 17], 1);
        csr[lo + slot] = pv & 0x1FFFF;
    }
}

// ============ gather kernels (8 lanes/node, batch-4 value loads) ============

// pass 1: gather 2-wide v0; epilogue applies W0,b0 then W1 -> u1 (8-wide)
__global__ __launch_bounds__(NT) void k_gL1(const int* __restrict__ rowst,
                                            const int* __restrict__ csr,
                                            const float* __restrict__ dis,
                                            const float* __restrict__ v0,
                                            const float* __restrict__ W0,
                                            const float* __restrict__ b0,
                                            const float* __restrict__ W1,
                                            float* __restrict__ un, int N) {
    int g = blockIdx.x * NT + threadIdx.x;
    int n = g >> 3, sub = g & 7;
    if (n >= N) return;
    int i = rowst[n] + sub, end = rowst[n + 1];
    float ax = 0.0f, ay = 0.0f;
    while (i + 24 < end) {
        int i0 = csr[i], i1 = csr[i + 8], i2 = csr[i + 16], i3 = csr[i + 24];
        float2 p0 = *reinterpret_cast<const float2*>(v0 + 2 * i0);
        float2 p1 = *reinterpret_cast<const float2*>(v0 + 2 * i1);
        float2 p2 = *reinterpret_cast<const float2*>(v0 + 2 * i2);
        float2 p3 = *reinterpret_cast<const float2*>(v0 + 2 * i3);
        ax += p0.x + p1.x + p2.x + p3.x;
        ay += p0.y + p1.y + p2.y + p3.y;
        i += 32;
    }
    while (i < end) {
        int s = csr[i];
        float2 p = *reinterpret_cast<const float2*>(v0 + 2 * s);
        ax += p.x; ay += p.y;
        i += 8;
    }
    ax += __shfl_xor(ax, 1, 64); ax += __shfl_xor(ax, 2, 64); ax += __shfl_xor(ax, 4, 64);
    ay += __shfl_xor(ay, 1, 64); ay += __shfl_xor(ay, 2, 64); ay += __shfl_xor(ay, 4, 64);
    float2 sv = *reinterpret_cast<const float2*>(v0 + 2 * n);
    ax += sv.x; ay += sv.y;
    float dn = dis[n];
    float gg = dn * (ax * W0[sub] + ay * W0[8 + sub]) + b0[sub];
    float h = gg > 0.0f ? gg : expm1f(gg);
    int base = (threadIdx.x & 63) & ~7;
    float o = 0.0f;
#pragma unroll
    for (int k = 0; k < 8; ++k) o += __shfl(h, base + k, 64) * W1[k * 8 + sub];
    un[8 * n + sub] = dn * o;
}

// mid pass: gather 8-wide u; reduce-scatter; epilogue bias+elu+W -> un
__global__ __launch_bounds__(NT) void k_gL8(const int* __restrict__ rowst,
                                            const int* __restrict__ csr,
                                            const float* __restrict__ dis,
                                            const float* __restrict__ u,
                                            const float* __restrict__ b,
                                            const float* __restrict__ W,
                                            float* __restrict__ un, int N) {
    int g = blockIdx.x * NT + threadIdx.x;
    int n = g >> 3, sub = g & 7;
    if (n >= N) return;
    int i = rowst[n] + sub, end = rowst[n + 1];
    float a[8];
#pragma unroll
    for (int k = 0; k < 8; ++k) a[k] = 0.0f;
    while (i + 24 < end) {
        int i0 = csr[i], i1 = csr[i + 8], i2 = csr[i + 16], i3 = csr[i + 24];
        float4 p00 = *reinterpret_cast<const float4*>(u + 8 * i0);
        float4 p01 = *reinterpret_cast<const float4*>(u + 8 * i0 + 4);
        float4 p10 = *reinterpret_cast<const float4*>(u + 8 * i1);
        float4 p11 = *reinterpret_cast<const float4*>(u + 8 * i1 + 4);
        float4 p20 = *reinterpret_cast<const float4*>(u + 8 * i2);
        float4 p21 = *reinterpret_cast<const float4*>(u + 8 * i2 + 4);
        float4 p30 = *reinterpret_cast<const float4*>(u + 8 * i3);
        float4 p31 = *reinterpret_cast<const float4*>(u + 8 * i3 + 4);
        a[0] += p00.x + p10.x + p20.x + p30.x;
        a[1] += p00.y + p10.y + p20.y + p30.y;
        a[2] += p00.z + p10.z + p20.z + p30.z;
        a[3] += p00.w + p10.w + p20.w + p30.w;
        a[4] += p01.x + p11.x + p21.x + p31.x;
        a[5] += p01.y + p11.y + p21.y + p31.y;
        a[6] += p01.z + p11.z + p21.z + p31.z;
        a[7] += p01.w + p11.w + p21.w + p31.w;
        i += 32;
    }
    while (i < end) {
        int s = csr[i];
        float4 p0 = *reinterpret_cast<const float4*>(u + 8 * s);
        float4 p1 = *reinterpret_cast<const float4*>(u + 8 * s + 4);
        a[0] += p0.x; a[1] += p0.y; a[2] += p0.z; a[3] += p0.w;
        a[4] += p1.x; a[5] += p1.y; a[6] += p1.z; a[7] += p1.w;
        i += 8;
    }
    // reduce-scatter butterfly: lane sub ends owning feature sub in a[0]
    int c4 = sub & 4, c2 = sub & 2, c1 = sub & 1;
#pragma unroll
    for (int j = 0; j < 4; ++j) {
        float send = c4 ? a[j] : a[j + 4];
        float recv = __shfl_xor(send, 4, 64);
        a[j] = (c4 ? a[j + 4] : a[j]) + recv;
    }
#pragma unroll
    for (int j = 0; j < 2; ++j) {
        float send = c2 ? a[j] : a[j + 2];
        float recv = __shfl_xor(send, 2, 64);
        a[j] = (c2 ? a[j + 2] : a[j]) + recv;
    }
    {
        float send = c1 ? a[0] : a[1];
        float recv = __shfl_xor(send, 1, 64);
        a[0] = (c1 ? a[1] : a[0]) + recv;
    }
    float dn = dis[n];
    float va = a[0] + u[8 * n + sub];
    float gg = va * dn + b[sub];
    float h = gg > 0.0f ? gg : expm1f(gg);
    int base = (threadIdx.x & 63) & ~7;
    float o = 0.0f;
#pragma unroll
    for (int k = 0; k < 8; ++k) o += __shfl(h, base + k, 64) * W[k * 8 + sub];
    un[8 * n + sub] = dn * o;
}

// head pass: gather 8-wide u3; epilogue b3+elu then Wv/Wp -> uH (2-wide)
__global__ __launch_bounds__(NT) void k_gHead(const int* __restrict__ rowst,
                                              const int* __restrict__ csr,
                                              const float* __restrict__ dis,
                                              const float* __restrict__ u,
                                              const float* __restrict__ b,
                                              const float* __restrict__ Wv,
                                              const float* __restrict__ Wp,
                                              float* __restrict__ uH, int N) {
    int g = blockIdx.x * NT + threadIdx.x;
    int n = g >> 3, sub = g & 7;
    if (n >= N) return;
    int i = rowst[n] + sub, end = rowst[n + 1];
    float a[8];
#pragma unroll
    for (int k = 0; k < 8; ++k) a[k] = 0.0f;
    while (i + 24 < end) {
        int i0 = csr[i], i1 = csr[i + 8], i2 = csr[i + 16], i3 = csr[i + 24];
        float4 p00 = *reinterpret_cast<const float4*>(u + 8 * i0);
        float4 p01 = *reinterpret_cast<const float4*>(u + 8 * i0 + 4);
        float4 p10 = *reinterpret_cast<const float4*>(u + 8 * i1);
        float4 p11 = *reinterpret_cast<const float4*>(u + 8 * i1 + 4);
        float4 p20 = *reinterpret_cast<const float4*>(u + 8 * i2);
        float4 p21 = *reinterpret_cast<const float4*>(u + 8 * i2 + 4);
        float4 p30 = *reinterpret_cast<const float4*>(u + 8 * i3);
        float4 p31 = *reinterpret_cast<const float4*>(u + 8 * i3 + 4);
        a[0] += p00.x + p10.x + p20.x + p30.x;
        a[1] += p00.y + p10.y + p20.y + p30.y;
        a[2] += p00.z + p10.z + p20.z + p30.z;
        a[3] += p00.w + p10.w + p20.w + p30.w;
        a[4] += p01.x + p11.x + p21.x + p31.x;
        a[5] += p01.y + p11.y + p21.y + p31.y;
        a[6] += p01.z + p11.z + p21.z + p31.z;
        a[7] += p01.w + p11.w + p21.w + p31.w;
        i += 32;
    }
    while (i < end) {
        int s = csr[i];
        float4 p0 = *reinterpret_cast<const float4*>(u + 8 * s);
        float4 p1 = *reinterpret_cast<const float4*>(u + 8 * s + 4);
        a[0] += p0.x; a[1] += p0.y; a[2] += p0.z; a[3] += p0.w;
        a[4] += p1.x; a[5] += p1.y; a[6] += p1.z; a[7] += p1.w;
        i += 8;
    }
    int c4 = sub & 4, c2 = sub & 2, c1 = sub & 1;
#pragma unroll
    for (int j = 0; j < 4; ++j) {
        float send = c4 ? a[j] : a[j + 4];
        float recv = __shfl_xor(send, 4, 64);
        a[j] = (c4 ? a[j + 4] : a[j]) + recv;
    }
#pragma unroll
    for (int j = 0; j < 2; ++j) {
        float send = c2 ? a[j] : a[j + 2];
        float recv = __shfl_xor(send, 2, 64);
        a[j] = (c2 ? a[j + 2] : a[j]) + recv;
    }
    {
        float send = c1 ? a[0] : a[1];
        float recv = __shfl_xor(send, 1, 64);
        a[0] = (c1 ? a[1] : a[0]) + recv;
    }
    float dn = dis[n];
    float va = a[0] + u[8 * n + sub];
    float gg = va * dn + b[sub];
    float h = gg > 0.0f ? gg : expm1f(gg);
    float tv = h * Wv[sub];
    float tp = h * Wp[sub];
    tv += __shfl_xor(tv, 1, 64); tv += __shfl_xor(tv, 2, 64); tv += __shfl_xor(tv, 4, 64);
    tp += __shfl_xor(tp, 1, 64); tp += __shfl_xor(tp, 2, 64); tp += __shfl_xor(tp, 4, 64);
    if (sub == 0)
        *reinterpret_cast<float2*>(uH + 2 * n) = make_float2(dn * tv, dn * tp);
}

// final: gather 2-wide uH -> proba out + value reduce
__global__ __launch_bounds__(NT) void k_g2F(const int* __restrict__ rowst,
                                            const int* __restrict__ csr,
                                            const float* __restrict__ dis,
                                            const float* __restrict__ uH,
                                            const float* __restrict__ bp,
                                            float* __restrict__ out,
                                            float* __restrict__ vsum, int N) {
    int g = blockIdx.x * NT + threadIdx.x;
    int n = g >> 3, sub = g & 7;
    bool valid = n < N;
    int i = 0, end = 0;
    if (valid) { i = rowst[n] + sub; end = rowst[n + 1]; }
    float av = 0.0f, ap = 0.0f;
    while (i + 24 < end) {
        int i0 = csr[i], i1 = csr[i + 8], i2 = csr[i + 16], i3 = csr[i + 24];
        float2 p0 = *reinterpret_cast<const float2*>(uH + 2 * i0);
        float2 p1 = *reinterpret_cast<const float2*>(uH + 2 * i1);
        float2 p2 = *reinterpret_cast<const float2*>(uH + 2 * i2);
        float2 p3 = *reinterpret_cast<const float2*>(uH + 2 * i3);
        av += p0.x + p1.x + p2.x + p3.x;
        ap += p0.y + p1.y + p2.y + p3.y;
        i += 32;
    }
    while (i < end) {
        int s = csr[i];
        float2 p = *reinterpret_cast<const float2*>(uH + 2 * s);
        av += p.x; ap += p.y;
        i += 8;
    }
    av += __shfl_xor(av, 1, 64); av += __shfl_xor(av, 2, 64); av += __shfl_xor(av, 4, 64);
    ap += __shfl_xor(ap, 1, 64); ap += __shfl_xor(ap, 2, 64); ap += __shfl_xor(ap, 4, 64);
    float contrib = 0.0f;
    if (valid && sub == 0) {
        float2 selfv = *reinterpret_cast<const float2*>(uH + 2 * n);
        av += selfv.x; ap += selfv.y;
        float dn = dis[n];
        out[n] = ap * dn + bp[0];
        contrib = av * dn;
    }
#pragma unroll
    for (int o = 32; o > 0; o >>= 1) contrib += __shfl_down(contrib, o, 64);
    __shared__ float sred[NT / 64];
    if ((threadIdx.x & 63) == 0) sred[threadIdx.x >> 6] = contrib;
    __syncthreads();
    if (threadIdx.x == 0) {
        float bsum = 0.0f;
#pragma unroll
        for (int k = 0; k < NT / 64; ++k) bsum += sred[k];
        atomicAdd(vsum, bsum);
    }
}

__global__ void k_final(const float* __restrict__ vsum,
                        const float* __restrict__ bv,
                        float* __restrict__ out, int N) {
    out[0] = vsum[0] * (1.0f / (float)N) + bv[0];
}

// ============== fallback: two-pass exact-CSR build ==============

__global__ __launch_bounds__(NT) void k_count(const int* __restrict__ dst,
                                              int* __restrict__ deg, int E) {
    int e = blockIdx.x * NT + threadIdx.x;
    if (e < E) atomicAdd(&deg[dst[e]], 1);
}

__global__ __launch_bounds__(NT) void k_scanA(const int* __restrict__ deg,
                                              int* __restrict__ partial, int N) {
    int t = threadIdx.x;
    int base = blockIdx.x * CHUNK + t * 4;
    int s = 0;
#pragma unroll
    for (int j = 0; j < 4; ++j) { int i = base + j; if (i < N) s += deg[i]; }
    __shared__ int red[NT];
    red[t] = s; __syncthreads();
    for (int o = NT / 2; o > 0; o >>= 1) {
        if (t < o) red[t] += red[t + o];
        __syncthreads();
    }
    if (t == 0) partial[blockIdx.x] = red[0];
}

__global__ void k_scanB(const int* __restrict__ partial, int* __restrict__ chunkoff,
                        int* __restrict__ rowst, int nblk, int N) {
    if (threadIdx.x == 0) {
        int off = 0;
        for (int b = 0; b < nblk; ++b) { chunkoff[b] = off; off += partial[b]; }
        rowst[N] = off;
    }
}

__global__ __launch_bounds__(NT) void k_scanC(const int* __restrict__ deg,
                                              const int* __restrict__ chunkoff,
                                              int* __restrict__ rowst,
                                              float* __restrict__ dis, int N) {
    int t = threadIdx.x;
    int base = blockIdx.x * CHUNK + t * 4;
    int v[4]; int tsum = 0;
#pragma unroll
    for (int j = 0; j < 4; ++j) { int i = base + j; v[j] = (i < N) ? deg[i] : 0; tsum += v[j]; }
    __shared__ int ss[NT];
    ss[t] = tsum; __syncthreads();
    for (int o = 1; o < NT; o <<= 1) {
        int x = (t >= o) ? ss[t - o] : 0;
        __syncthreads();
        ss[t] += x;
        __syncthreads();
    }
    int run = ss[t] - tsum + chunkoff[blockIdx.x];
#pragma unroll
    for (int j = 0; j < 4; ++j) {
        int i = base + j;
        if (i < N) { rowst[i] = run; dis[i] = rsqrtf((float)v[j] + 1.0f); run += v[j]; }
    }
}

__global__ __launch_bounds__(NT) void k_fill(const int* __restrict__ src,
                                             const int* __restrict__ dst,
                                             const int* __restrict__ rowst,
                                             int* __restrict__ deg,
                                             int* __restrict__ csr, int E) {
    int e = blockIdx.x * NT + threadIdx.x;
    if (e >= E) return;
    int s = src[e], d = dst[e];
    int old = atomicSub(&deg[d], 1);
    csr[rowst[d] + old - 1] = s;
}

__global__ __launch_bounds__(NT) void k_v0(const float* __restrict__ x,
                                           const float* __restrict__ dis,
                                           float* __restrict__ v0, int N) {
    int n = blockIdx.x * NT + threadIdx.x;
    if (n >= N) return;
    float dn = dis[n];
    float2 xv = *reinterpret_cast<const float2*>(x + 2 * n);
    *reinterpret_cast<float2*>(v0 + 2 * n) = make_float2(dn * xv.x, dn * xv.y);
}

// ================================ launch ================================

extern "C" void kernel_launch(void* const* d_in, const int* in_sizes, int n_in,
                              void* d_out, int out_size, void* d_ws, size_t ws_size,
                              hipStream_t stream) {
    const float* x  = (const float*)d_in[0];
    const int* ei   = (const int*)d_in[1];
    const float* W0 = (const float*)d_in[2];
    const float* b0 = (const float*)d_in[3];
    const float* W1 = (const float*)d_in[4];
    const float* b1 = (const float*)d_in[5];
    const float* W2 = (const float*)d_in[6];
    const float* b2 = (const float*)d_in[7];
    const float* W3 = (const float*)d_in[8];
    const float* b3 = (const float*)d_in[9];
    const float* Wv = (const float*)d_in[10];
    const float* bv = (const float*)d_in[11];
    const float* Wp = (const float*)d_in[12];
    const float* bp = (const float*)d_in[13];
    float* out = (float*)d_out;

    int N = in_sizes[0] / 2;
    int E = in_sizes[1] / 2;
    const int* src = ei;
    const int* dst = ei + E;
    int NB = (N + 255) >> 8;
    int NP = (N + 3) & ~3;
    int EP = (E + 3) & ~3;
    int chunkP = (E + PBLK2 - 1) / PBLK2;

    size_t needP = ((size_t)22 * NP + 2 * (size_t)EP + 1044) * 4;
    bool histFits = (size_t)2 * PBLK2 * NB <= (size_t)E;

    if (N <= 131072 && NB <= 512 && ws_size >= needP && histFits && chunkP <= PTILE) {
        int* tot    = (int*)d_ws;                   // 512
        int* bbase  = tot + 512;                    // 520 (NB+1 used)
        float* vsum = (float*)(bbase + 520);        // 8
        int* rowst  = (int*)(vsum + 8);             // NP+4 (N+1 used)
        float* dis  = (float*)(rowst + NP + 4);     // NP
        float* v0   = dis + NP;                     // 2NP
        float* uA   = v0 + (size_t)2 * NP;          // 8NP
        float* uB   = uA + (size_t)8 * NP;          // 8NP
        float* uH   = uB + (size_t)8 * NP;          // 2NP
        int* part   = (int*)(uH + (size_t)2 * NP);  // EP
        int* csr    = part + (size_t)EP;            // EP
        int* histB   = csr;                         // scratch inside csr
        int* cursorT = csr + (size_t)PBLK2 * NB;

        hipMemsetAsync(vsum, 0, 4, stream);

        k_histB<<<PBLK2, 256, 0, stream>>>(dst, histB, E, NB);
        k_scanB2<<<NB, 256, 0, stream>>>(histB, cursorT, tot, NB, PBLK2);
        k_bscan<<<1, 512, 0, stream>>>(tot, bbase, rowst, NB, N, E);
        k_partF<<<PBLK2, 256, 0, stream>>>(src, dst, bbase, histB, cursorT, part, E, NB);
        k_build<<<NB, 512, 0, stream>>>(bbase, part, x, rowst, dis, v0, csr, N);

        k_gL1<<<nbi(8LL * N), NT, 0, stream>>>(rowst, csr, dis, v0, W0, b0, W1, uA, N);
        k_gL8<<<nbi(8LL * N), NT, 0, stream>>>(rowst, csr, dis, uA, b1, W2, uB, N);
        k_gL8<<<nbi(8LL * N), NT, 0, stream>>>(rowst, csr, dis, uB, b2, W3, uA, N);
        k_gHead<<<nbi(8LL * N), NT, 0, stream>>>(rowst, csr, dis, uA, b3, Wv, Wp, uH, N);
        k_g2F<<<nbi(8LL * N), NT, 0, stream>>>(rowst, csr, dis, uH, bp, out, vsum, N);
        k_final<<<1, 1, 0, stream>>>(vsum, bv, out + N, N);
    } else {
        // ---- fallback: two-pass exact CSR, same gather kernels ----
        int nblk = (N + CHUNK - 1) / CHUNK;
        int* deg      = (int*)d_ws;                 // N
        int* rowst    = deg + N;                    // N+1
        int* chunkoff = rowst + N + 1;              // nblk
        int* partial  = chunkoff + nblk;            // nblk
        float* dis    = (float*)(partial + nblk);   // N
        float* vsum   = dis + N;                    // 8
        float* v0     = vsum + 8;                   // 2N
        float* uA     = v0 + (size_t)2 * N;         // 8N
        float* uB     = uA + (size_t)8 * N;         // 8N
        float* uH     = uB + (size_t)8 * N;         // 2N
        int* csr      = (int*)(uH + (size_t)2 * N); // E

        hipMemsetAsync(deg, 0, (size_t)N * 4, stream);
        hipMemsetAsync(vsum, 0, 4, stream);

        k_count<<<nbi(E), NT, 0, stream>>>(dst, deg, E);
        k_scanA<<<nblk, NT, 0, stream>>>(deg, partial, N);
        k_scanB<<<1, 64, 0, stream>>>(partial, chunkoff, rowst, nblk, N);
        k_scanC<<<nblk, NT, 0, stream>>>(deg, chunkoff, rowst, dis, N);
        k_fill<<<nbi(E), NT, 0, stream>>>(src, dst, rowst, deg, csr, E);
        k_v0<<<nbi(N), NT, 0, stream>>>(x, dis, v0, N);

        k_gL1<<<nbi(8LL * N), NT, 0, stream>>>(rowst, csr, dis, v0, W0, b0, W1, uA, N);
        k_gL8<<<nbi(8LL * N), NT, 0, stream>>>(rowst, csr, dis, uA, b1, W2, uB, N);
        k_gL8<<<nbi(8LL * N), NT, 0, stream>>>(rowst, csr, dis, uB, b2, W3, uA, N);
        k_gHead<<<nbi(8LL * N), NT, 0, stream>>>(rowst, csr, dis, uA, b3, Wv, Wp, uH, N);
        k_g2F<<<nbi(8LL * N), NT, 0, stream>>>(rowst, csr, dis, uH, bp, out, vsum, N);
        k_final<<<1, 1, 0, stream>>>(vsum, bv, out + N, N);
    }
}

// Round 9
// 324.304 us; speedup vs baseline: 34.6227x; 1.0340x over previous
//
#include <hip/hip_runtime.h>

#define NT 256
#define CHUNK 1024
#define PBLK2 2048  // blocks for hist/partition passes
#define PTILE 4096  // staged partition tile (edges)

static inline int nbi(long long n) { return (int)((n + NT - 1) / NT); }

// ===================== bucket-partition CSR build =====================
// buckets of 256 nodes: bucket = dst >> 8, d_local = dst & 255
// packed entry = (d_local << 17) | src   (requires N <= 131072)

__global__ __launch_bounds__(256) void k_histB(const int* __restrict__ dst,
                                               int* __restrict__ histB,
                                               int E, int NB) {
    __shared__ int lh[512];
    int t = threadIdx.x;
    for (int i = t; i < 512; i += 256) lh[i] = 0;
    __syncthreads();
    int chunk = (E + gridDim.x - 1) / gridDim.x;
    int lo = blockIdx.x * chunk, hi = min(E, lo + chunk);
    for (int i = lo + t; i < hi; i += 256)
        atomicAdd(&lh[dst[i] >> 8], 1);
    __syncthreads();
    for (int b = t; b < NB; b += 256)
        histB[(size_t)blockIdx.x * NB + b] = lh[b];
}

__global__ __launch_bounds__(256) void k_scanB2(const int* __restrict__ histB,
                                                int* __restrict__ cursorT,
                                                int* __restrict__ tot,
                                                int NB, int nblk) {
    __shared__ int ch[256];
    __shared__ int carry;
    int b = blockIdx.x, t = threadIdx.x;
    if (t == 0) carry = 0;
    __syncthreads();
    for (int c = 0; c < nblk; c += 256) {
        int blk = c + t;
        int v = (blk < nblk) ? histB[(size_t)blk * NB + b] : 0;
        ch[t] = v;
        __syncthreads();
        for (int o = 1; o < 256; o <<= 1) {
            int x = (t >= o) ? ch[t - o] : 0;
            __syncthreads();
            ch[t] += x;
            __syncthreads();
        }
        int excl = ch[t] - v + carry;
        if (blk < nblk) cursorT[(size_t)b * PBLK2 + blk] = excl;
        __syncthreads();
        if (t == 0) carry += ch[255];
        __syncthreads();
    }
    if (t == 0) tot[b] = carry;
}

__global__ __launch_bounds__(512) void k_bscan(const int* __restrict__ hist_g,
                                               int* __restrict__ bbase,
                                               int* __restrict__ rowst,
                                               int NB, int N, int E) {
    __shared__ int s[512];
    int t = threadIdx.x;
    int own = (t < NB) ? hist_g[t] : 0;
    s[t] = own;
    __syncthreads();
    for (int o = 1; o < 512; o <<= 1) {
        int v = (t >= o) ? s[t - o] : 0;
        __syncthreads();
        s[t] += v;
        __syncthreads();
    }
    if (t < NB) bbase[t] = s[t] - own;
    if (t == 0) { bbase[NB] = E; rowst[N] = E; }
}

// single-tile partition: hist comes from histB (no per-edge recount)
__global__ __launch_bounds__(256) void k_partF(const int* __restrict__ src,
                                               const int* __restrict__ dst,
                                               const int* __restrict__ bbase,
                                               const int* __restrict__ histB,
                                               const int* __restrict__ cursorT,
                                               int* __restrict__ part,
                                               int E, int NB) {
    __shared__ int wadj[512], tloff[512], tcnt[512], ps[256];
    __shared__ int stage[PTILE];
    __shared__ unsigned short sbkt[PTILE];
    int t = threadIdx.x;
    int blk = blockIdx.x;
    int chunk = (E + gridDim.x - 1) / gridDim.x;
    int lo = blk * chunk, hi = min(E, lo + chunk);
    if (lo >= hi) return;
    int cnt = hi - lo;
    int b0 = 2 * t, b1 = 2 * t + 1;
    int v0c = (b0 < NB) ? histB[(size_t)blk * NB + b0] : 0;
    int v1c = (b1 < NB) ? histB[(size_t)blk * NB + b1] : 0;
    ps[t] = v0c + v1c;
    __syncthreads();
    for (int o = 1; o < 256; o <<= 1) {
        int v = (t >= o) ? ps[t - o] : 0;
        __syncthreads();
        ps[t] += v;
        __syncthreads();
    }
    int excl = ps[t] - v0c - v1c;
    tloff[b0] = excl;
    tloff[b1] = excl + v0c;
    tcnt[b0] = 0; tcnt[b1] = 0;
    if (b0 < NB) wadj[b0] = bbase[b0] + cursorT[(size_t)b0 * PBLK2 + blk] - excl;
    if (b1 < NB) wadj[b1] = bbase[b1] + cursorT[(size_t)b1 * PBLK2 + blk] - (excl + v0c);
    __syncthreads();
    for (int i = lo + t; i < hi; i += 256) {
        int d = dst[i], s = src[i];
        int b = d >> 8;
        int pos = tloff[b] + atomicAdd(&tcnt[b], 1);
        stage[pos] = ((d & 255) << 17) | s;
        sbkt[pos] = (unsigned short)b;
    }
    __syncthreads();
    for (int i = t; i < cnt; i += 256) {
        int b = sbkt[i];
        part[wadj[b] + i] = stage[i];
    }
}

// one block/bucket: LDS count -> scan -> rowst/dis/v0 -> place csr
__global__ __launch_bounds__(512) void k_build(const int* __restrict__ bbase,
                                               const int* __restrict__ part,
                                               const float* __restrict__ x,
                                               int* __restrict__ rowst,
                                               float* __restrict__ dis,
                                               float* __restrict__ v0,
                                               int* __restrict__ csr,
                                               int N) {
    __shared__ int dcnt[256], doff[256];
    int b = blockIdx.x, t = threadIdx.x;
    int lo = bbase[b], hi = bbase[b + 1];
    if (t < 256) dcnt[t] = 0;
    __syncthreads();
    for (int i = lo + t; i < hi; i += 512)
        atomicAdd(&dcnt[part[i] >> 17], 1);
    __syncthreads();
    int own = 0;
    if (t < 256) { own = dcnt[t]; doff[t] = own; }
    __syncthreads();
    for (int o = 1; o < 256; o <<= 1) {
        int v = 0;
        if (t < 256 && t >= o) v = doff[t - o];
        __syncthreads();
        if (t < 256) doff[t] += v;
        __syncthreads();
    }
    if (t < 256) {
        int excl = doff[t] - own;
        int node = (b << 8) + t;
        if (node < N) {
            rowst[node] = lo + excl;
            float dn = rsqrtf((float)own + 1.0f);
            dis[node] = dn;
            float2 xv = *reinterpret_cast<const float2*>(x + 2 * node);
            *reinterpret_cast<float2*>(v0 + 2 * node) = make_float2(dn * xv.x, dn * xv.y);
        }
        dcnt[t] = excl;
    }
    __syncthreads();
    for (int i = lo + t; i < hi; i += 512) {
        int pv = part[i];
        int slot = atomicAdd(&dcnt[pv >> 17], 1);
        csr[lo + slot] = pv & 0x1FFFF;
    }
}

// ==== gather kernels (8 lanes/node, 8-deep idx prefetch + batched values) ====

// pass 1: gather 2-wide v0; epilogue applies W0,b0 then W1 -> u1 (8-wide)
__global__ __launch_bounds__(NT) void k_gL1(const int* __restrict__ rowst,
                                            const int* __restrict__ csr,
                                            const float* __restrict__ dis,
                                            const float* __restrict__ v0,
                                            const float* __restrict__ W0,
                                            const float* __restrict__ b0,
                                            const float* __restrict__ W1,
                                            float* __restrict__ un, int N) {
    int g = blockIdx.x * NT + threadIdx.x;
    int n = g >> 3, sub = g & 7;
    if (n >= N) return;
    int base = rowst[n], end = rowst[n + 1];
    int i = base + sub;
    float ax = 0.0f, ay = 0.0f;
    int idx[8];
#pragma unroll
    for (int k = 0; k < 8; ++k) {
        int j = i + 8 * k;
        idx[k] = (j < end) ? csr[j] : -1;
    }
    float2 vv[8];
#pragma unroll
    for (int k = 0; k < 8; ++k) {
        int s = idx[k] >= 0 ? idx[k] : n;
        vv[k] = *reinterpret_cast<const float2*>(v0 + 2 * s);
    }
#pragma unroll
    for (int k = 0; k < 8; ++k) {
        if (idx[k] >= 0) { ax += vv[k].x; ay += vv[k].y; }
    }
    for (int j = base + 64 + sub; j < end; j += 8) {
        int s = csr[j];
        float2 p = *reinterpret_cast<const float2*>(v0 + 2 * s);
        ax += p.x; ay += p.y;
    }
    ax += __shfl_xor(ax, 1, 64); ax += __shfl_xor(ax, 2, 64); ax += __shfl_xor(ax, 4, 64);
    ay += __shfl_xor(ay, 1, 64); ay += __shfl_xor(ay, 2, 64); ay += __shfl_xor(ay, 4, 64);
    float2 sv = *reinterpret_cast<const float2*>(v0 + 2 * n);
    ax += sv.x; ay += sv.y;
    float dn = dis[n];
    float gg = dn * (ax * W0[sub] + ay * W0[8 + sub]) + b0[sub];
    float h = gg > 0.0f ? gg : expm1f(gg);
    int lb = (threadIdx.x & 63) & ~7;
    float o = 0.0f;
#pragma unroll
    for (int k = 0; k < 8; ++k) o += __shfl(h, lb + k, 64) * W1[k * 8 + sub];
    un[8 * n + sub] = dn * o;
}

// mid pass: gather 8-wide u; reduce-scatter; epilogue bias+elu+W -> un
__global__ __launch_bounds__(NT) void k_gL8(const int* __restrict__ rowst,
                                            const int* __restrict__ csr,
                                            const float* __restrict__ dis,
                                            const float* __restrict__ u,
                                            const float* __restrict__ b,
                                            const float* __restrict__ W,
                                            float* __restrict__ un, int N) {
    int g = blockIdx.x * NT + threadIdx.x;
    int n = g >> 3, sub = g & 7;
    if (n >= N) return;
    int base = rowst[n], end = rowst[n + 1];
    int i = base + sub;
    float a[8];
#pragma unroll
    for (int k = 0; k < 8; ++k) a[k] = 0.0f;
    int idx[8];
#pragma unroll
    for (int k = 0; k < 8; ++k) {
        int j = i + 8 * k;
        idx[k] = (j < end) ? csr[j] : -1;
    }
    float4 v0r[8], v1r[8];
#pragma unroll
    for (int k = 0; k < 8; ++k) {
        int s = idx[k] >= 0 ? idx[k] : n;
        v0r[k] = *reinterpret_cast<const float4*>(u + 8 * s);
        v1r[k] = *reinterpret_cast<const float4*>(u + 8 * s + 4);
    }
#pragma unroll
    for (int k = 0; k < 8; ++k) {
        if (idx[k] >= 0) {
            a[0] += v0r[k].x; a[1] += v0r[k].y; a[2] += v0r[k].z; a[3] += v0r[k].w;
            a[4] += v1r[k].x; a[5] += v1r[k].y; a[6] += v1r[k].z; a[7] += v1r[k].w;
        }
    }
    for (int j = base + 64 + sub; j < end; j += 8) {
        int s = csr[j];
        float4 p0 = *reinterpret_cast<const float4*>(u + 8 * s);
        float4 p1 = *reinterpret_cast<const float4*>(u + 8 * s + 4);
        a[0] += p0.x; a[1] += p0.y; a[2] += p0.z; a[3] += p0.w;
        a[4] += p1.x; a[5] += p1.y; a[6] += p1.z; a[7] += p1.w;
    }
    // reduce-scatter butterfly: lane sub ends owning feature sub in a[0]
    int c4 = sub & 4, c2 = sub & 2, c1 = sub & 1;
#pragma unroll
    for (int j = 0; j < 4; ++j) {
        float send = c4 ? a[j] : a[j + 4];
        float recv = __shfl_xor(send, 4, 64);
        a[j] = (c4 ? a[j + 4] : a[j]) + recv;
    }
#pragma unroll
    for (int j = 0; j < 2; ++j) {
        float send = c2 ? a[j] : a[j + 2];
        float recv = __shfl_xor(send, 2, 64);
        a[j] = (c2 ? a[j + 2] : a[j]) + recv;
    }
    {
        float send = c1 ? a[0] : a[1];
        float recv = __shfl_xor(send, 1, 64);
        a[0] = (c1 ? a[1] : a[0]) + recv;
    }
    float dn = dis[n];
    float va = a[0] + u[8 * n + sub];
    float gg = va * dn + b[sub];
    float h = gg > 0.0f ? gg : expm1f(gg);
    int lb = (threadIdx.x & 63) & ~7;
    float o = 0.0f;
#pragma unroll
    for (int k = 0; k < 8; ++k) o += __shfl(h, lb + k, 64) * W[k * 8 + sub];
    un[8 * n + sub] = dn * o;
}

// head pass: gather 8-wide u3; epilogue b3+elu then Wv/Wp -> uH (2-wide)
__global__ __launch_bounds__(NT) void k_gHead(const int* __restrict__ rowst,
                                              const int* __restrict__ csr,
                                              const float* __restrict__ dis,
                                              const float* __restrict__ u,
                                              const float* __restrict__ b,
                                              const float* __restrict__ Wv,
                                              const float* __restrict__ Wp,
                                              float* __restrict__ uH, int N) {
    int g = blockIdx.x * NT + threadIdx.x;
    int n = g >> 3, sub = g & 7;
    if (n >= N) return;
    int base = rowst[n], end = rowst[n + 1];
    int i = base + sub;
    float a[8];
#pragma unroll
    for (int k = 0; k < 8; ++k) a[k] = 0.0f;
    int idx[8];
#pragma unroll
    for (int k = 0; k < 8; ++k) {
        int j = i + 8 * k;
        idx[k] = (j < end) ? csr[j] : -1;
    }
    float4 v0r[8], v1r[8];
#pragma unroll
    for (int k = 0; k < 8; ++k) {
        int s = idx[k] >= 0 ? idx[k] : n;
        v0r[k] = *reinterpret_cast<const float4*>(u + 8 * s);
        v1r[k] = *reinterpret_cast<const float4*>(u + 8 * s + 4);
    }
#pragma unroll
    for (int k = 0; k < 8; ++k) {
        if (idx[k] >= 0) {
            a[0] += v0r[k].x; a[1] += v0r[k].y; a[2] += v0r[k].z; a[3] += v0r[k].w;
            a[4] += v1r[k].x; a[5] += v1r[k].y; a[6] += v1r[k].z; a[7] += v1r[k].w;
        }
    }
    for (int j = base + 64 + sub; j < end; j += 8) {
        int s = csr[j];
        float4 p0 = *reinterpret_cast<const float4*>(u + 8 * s);
        float4 p1 = *reinterpret_cast<const float4*>(u + 8 * s + 4);
        a[0] += p0.x; a[1] += p0.y; a[2] += p0.z; a[3] += p0.w;
        a[4] += p1.x; a[5] += p1.y; a[6] += p1.z; a[7] += p1.w;
    }
    int c4 = sub & 4, c2 = sub & 2, c1 = sub & 1;
#pragma unroll
    for (int j = 0; j < 4; ++j) {
        float send = c4 ? a[j] : a[j + 4];
        float recv = __shfl_xor(send, 4, 64);
        a[j] = (c4 ? a[j + 4] : a[j]) + recv;
    }
#pragma unroll
    for (int j = 0; j < 2; ++j) {
        float send = c2 ? a[j] : a[j + 2];
        float recv = __shfl_xor(send, 2, 64);
        a[j] = (c2 ? a[j + 2] : a[j]) + recv;
    }
    {
        float send = c1 ? a[0] : a[1];
        float recv = __shfl_xor(send, 1, 64);
        a[0] = (c1 ? a[1] : a[0]) + recv;
    }
    float dn = dis[n];
    float va = a[0] + u[8 * n + sub];
    float gg = va * dn + b[sub];
    float h = gg > 0.0f ? gg : expm1f(gg);
    float tv = h * Wv[sub];
    float tp = h * Wp[sub];
    tv += __shfl_xor(tv, 1, 64); tv += __shfl_xor(tv, 2, 64); tv += __shfl_xor(tv, 4, 64);
    tp += __shfl_xor(tp, 1, 64); tp += __shfl_xor(tp, 2, 64); tp += __shfl_xor(tp, 4, 64);
    if (sub == 0)
        *reinterpret_cast<float2*>(uH + 2 * n) = make_float2(dn * tv, dn * tp);
}

// final: gather 2-wide uH -> proba out + value reduce
__global__ __launch_bounds__(NT) void k_g2F(const int* __restrict__ rowst,
                                            const int* __restrict__ csr,
                                            const float* __restrict__ dis,
                                            const float* __restrict__ uH,
                                            const float* __restrict__ bp,
                                            float* __restrict__ out,
                                            float* __restrict__ vsum, int N) {
    int g = blockIdx.x * NT + threadIdx.x;
    int n = g >> 3, sub = g & 7;
    bool valid = n < N;
    float av = 0.0f, ap = 0.0f;
    if (valid) {
        int base = rowst[n], end = rowst[n + 1];
        int i = base + sub;
        int idx[8];
#pragma unroll
        for (int k = 0; k < 8; ++k) {
            int j = i + 8 * k;
            idx[k] = (j < end) ? csr[j] : -1;
        }
        float2 vv[8];
#pragma unroll
        for (int k = 0; k < 8; ++k) {
            int s = idx[k] >= 0 ? idx[k] : n;
            vv[k] = *reinterpret_cast<const float2*>(uH + 2 * s);
        }
#pragma unroll
        for (int k = 0; k < 8; ++k) {
            if (idx[k] >= 0) { av += vv[k].x; ap += vv[k].y; }
        }
        for (int j = base + 64 + sub; j < end; j += 8) {
            int s = csr[j];
            float2 p = *reinterpret_cast<const float2*>(uH + 2 * s);
            av += p.x; ap += p.y;
        }
    }
    av += __shfl_xor(av, 1, 64); av += __shfl_xor(av, 2, 64); av += __shfl_xor(av, 4, 64);
    ap += __shfl_xor(ap, 1, 64); ap += __shfl_xor(ap, 2, 64); ap += __shfl_xor(ap, 4, 64);
    float contrib = 0.0f;
    if (valid && sub == 0) {
        float2 selfv = *reinterpret_cast<const float2*>(uH + 2 * n);
        av += selfv.x; ap += selfv.y;
        float dn = dis[n];
        out[n] = ap * dn + bp[0];
        contrib = av * dn;
    }
#pragma unroll
    for (int o = 32; o > 0; o >>= 1) contrib += __shfl_down(contrib, o, 64);
    __shared__ float sred[NT / 64];
    if ((threadIdx.x & 63) == 0) sred[threadIdx.x >> 6] = contrib;
    __syncthreads();
    if (threadIdx.x == 0) {
        float bsum = 0.0f;
#pragma unroll
        for (int k = 0; k < NT / 64; ++k) bsum += sred[k];
        atomicAdd(vsum, bsum);
    }
}

__global__ void k_final(const float* __restrict__ vsum,
                        const float* __restrict__ bv,
                        float* __restrict__ out, int N) {
    out[0] = vsum[0] * (1.0f / (float)N) + bv[0];
}

// ============== fallback: two-pass exact-CSR build ==============

__global__ __launch_bounds__(NT) void k_count(const int* __restrict__ dst,
                                              int* __restrict__ deg, int E) {
    int e = blockIdx.x * NT + threadIdx.x;
    if (e < E) atomicAdd(&deg[dst[e]], 1);
}

__global__ __launch_bounds__(NT) void k_scanA(const int* __restrict__ deg,
                                              int* __restrict__ partial, int N) {
    int t = threadIdx.x;
    int base = blockIdx.x * CHUNK + t * 4;
    int s = 0;
#pragma unroll
    for (int j = 0; j < 4; ++j) { int i = base + j; if (i < N) s += deg[i]; }
    __shared__ int red[NT];
    red[t] = s; __syncthreads();
    for (int o = NT / 2; o > 0; o >>= 1) {
        if (t < o) red[t] += red[t + o];
        __syncthreads();
    }
    if (t == 0) partial[blockIdx.x] = red[0];
}

__global__ void k_scanB(const int* __restrict__ partial, int* __restrict__ chunkoff,
                        int* __restrict__ rowst, int nblk, int N) {
    if (threadIdx.x == 0) {
        int off = 0;
        for (int b = 0; b < nblk; ++b) { chunkoff[b] = off; off += partial[b]; }
        rowst[N] = off;
    }
}

__global__ __launch_bounds__(NT) void k_scanC(const int* __restrict__ deg,
                                              const int* __restrict__ chunkoff,
                                              int* __restrict__ rowst,
                                              float* __restrict__ dis, int N) {
    int t = threadIdx.x;
    int base = blockIdx.x * CHUNK + t * 4;
    int v[4]; int tsum = 0;
#pragma unroll
    for (int j = 0; j < 4; ++j) { int i = base + j; v[j] = (i < N) ? deg[i] : 0; tsum += v[j]; }
    __shared__ int ss[NT];
    ss[t] = tsum; __syncthreads();
    for (int o = 1; o < NT; o <<= 1) {
        int x = (t >= o) ? ss[t - o] : 0;
        __syncthreads();
        ss[t] += x;
        __syncthreads();
    }
    int run = ss[t] - tsum + chunkoff[blockIdx.x];
#pragma unroll
    for (int j = 0; j < 4; ++j) {
        int i = base + j;
        if (i < N) { rowst[i] = run; dis[i] = rsqrtf((float)v[j] + 1.0f); run += v[j]; }
    }
}

__global__ __launch_bounds__(NT) void k_fill(const int* __restrict__ src,
                                             const int* __restrict__ dst,
                                             const int* __restrict__ rowst,
                                             int* __restrict__ deg,
                                             int* __restrict__ csr, int E) {
    int e = blockIdx.x * NT + threadIdx.x;
    if (e >= E) return;
    int s = src[e], d = dst[e];
    int old = atomicSub(&deg[d], 1);
    csr[rowst[d] + old - 1] = s;
}

__global__ __launch_bounds__(NT) void k_v0(const float* __restrict__ x,
                                           const float* __restrict__ dis,
                                           float* __restrict__ v0, int N) {
    int n = blockIdx.x * NT + threadIdx.x;
    if (n >= N) return;
    float dn = dis[n];
    float2 xv = *reinterpret_cast<const float2*>(x + 2 * n);
    *reinterpret_cast<float2*>(v0 + 2 * n) = make_float2(dn * xv.x, dn * xv.y);
}

// ================================ launch ================================

extern "C" void kernel_launch(void* const* d_in, const int* in_sizes, int n_in,
                              void* d_out, int out_size, void* d_ws, size_t ws_size,
                              hipStream_t stream) {
    const float* x  = (const float*)d_in[0];
    const int* ei   = (const int*)d_in[1];
    const float* W0 = (const float*)d_in[2];
    const float* b0 = (const float*)d_in[3];
    const float* W1 = (const float*)d_in[4];
    const float* b1 = (const float*)d_in[5];
    const float* W2 = (const float*)d_in[6];
    const float* b2 = (const float*)d_in[7];
    const float* W3 = (const float*)d_in[8];
    const float* b3 = (const float*)d_in[9];
    const float* Wv = (const float*)d_in[10];
    const float* bv = (const float*)d_in[11];
    const float* Wp = (const float*)d_in[12];
    const float* bp = (const float*)d_in[13];
    float* out = (float*)d_out;

    int N = in_sizes[0] / 2;
    int E = in_sizes[1] / 2;
    const int* src = ei;
    const int* dst = ei + E;
    int NB = (N + 255) >> 8;
    int NP = (N + 3) & ~3;
    int EP = (E + 3) & ~3;
    int chunkP = (E + PBLK2 - 1) / PBLK2;

    size_t needP = ((size_t)22 * NP + 2 * (size_t)EP + 1044) * 4;
    bool histFits = (size_t)2 * PBLK2 * NB <= (size_t)E;

    if (N <= 131072 && NB <= 512 && ws_size >= needP && histFits && chunkP <= PTILE) {
        int* tot    = (int*)d_ws;                   // 512
        int* bbase  = tot + 512;                    // 520 (NB+1 used)
        float* vsum = (float*)(bbase + 520);        // 8
        int* rowst  = (int*)(vsum + 8);             // NP+4 (N+1 used)
        float* dis  = (float*)(rowst + NP + 4);     // NP
        float* v0   = dis + NP;                     // 2NP
        float* uA   = v0 + (size_t)2 * NP;          // 8NP
        float* uB   = uA + (size_t)8 * NP;          // 8NP
        float* uH   = uB + (size_t)8 * NP;          // 2NP
        int* part   = (int*)(uH + (size_t)2 * NP);  // EP
        int* csr    = part + (size_t)EP;            // EP
        int* histB   = csr;                         // scratch inside csr
        int* cursorT = csr + (size_t)PBLK2 * NB;

        hipMemsetAsync(vsum, 0, 4, stream);

        k_histB<<<PBLK2, 256, 0, stream>>>(dst, histB, E, NB);
        k_scanB2<<<NB, 256, 0, stream>>>(histB, cursorT, tot, NB, PBLK2);
        k_bscan<<<1, 512, 0, stream>>>(tot, bbase, rowst, NB, N, E);
        k_partF<<<PBLK2, 256, 0, stream>>>(src, dst, bbase, histB, cursorT, part, E, NB);
        k_build<<<NB, 512, 0, stream>>>(bbase, part, x, rowst, dis, v0, csr, N);

        k_gL1<<<nbi(8LL * N), NT, 0, stream>>>(rowst, csr, dis, v0, W0, b0, W1, uA, N);
        k_gL8<<<nbi(8LL * N), NT, 0, stream>>>(rowst, csr, dis, uA, b1, W2, uB, N);
        k_gL8<<<nbi(8LL * N), NT, 0, stream>>>(rowst, csr, dis, uB, b2, W3, uA, N);
        k_gHead<<<nbi(8LL * N), NT, 0, stream>>>(rowst, csr, dis, uA, b3, Wv, Wp, uH, N);
        k_g2F<<<nbi(8LL * N), NT, 0, stream>>>(rowst, csr, dis, uH, bp, out, vsum, N);
        k_final<<<1, 1, 0, stream>>>(vsum, bv, out + N, N);
    } else {
        // ---- fallback: two-pass exact CSR, same gather kernels ----
        int nblk = (N + CHUNK - 1) / CHUNK;
        int* deg      = (int*)d_ws;                 // N
        int* rowst    = deg + N;                    // N+1
        int* chunkoff = rowst + N + 1;              // nblk
        int* partial  = chunkoff + nblk;            // nblk
        float* dis    = (float*)(partial + nblk);   // N
        float* vsum   = dis + N;                    // 8
        float* v0     = vsum + 8;                   // 2N
        float* uA     = v0 + (size_t)2 * N;         // 8N
        float* uB     = uA + (size_t)8 * N;         // 8N
        float* uH     = uB + (size_t)8 * N;         // 2N
        int* csr      = (int*)(uH + (size_t)2 * N); // E

        hipMemsetAsync(deg, 0, (size_t)N * 4, stream);
        hipMemsetAsync(vsum, 0, 4, stream);

        k_count<<<nbi(E), NT, 0, stream>>>(dst, deg, E);
        k_scanA<<<nblk, NT, 0, stream>>>(deg, partial, N);
        k_scanB<<<1, 64, 0, stream>>>(partial, chunkoff, rowst, nblk, N);
        k_scanC<<<nblk, NT, 0, stream>>>(deg, chunkoff, rowst, dis, N);
        k_fill<<<nbi(E), NT, 0, stream>>>(src, dst, rowst, deg, csr, E);
        k_v0<<<nbi(N), NT, 0, stream>>>(x, dis, v0, N);

        k_gL1<<<nbi(8LL * N), NT, 0, stream>>>(rowst, csr, dis, v0, W0, b0, W1, uA, N);
        k_gL8<<<nbi(8LL * N), NT, 0, stream>>>(rowst, csr, dis, uA, b1, W2, uB, N);
        k_gL8<<<nbi(8LL * N), NT, 0, stream>>>(rowst, csr, dis, uB, b2, W3, uA, N);
        k_gHead<<<nbi(8LL * N), NT, 0, stream>>>(rowst, csr, dis, uA, b3, Wv, Wp, uH, N);
        k_g2F<<<nbi(8LL * N), NT, 0, stream>>>(rowst, csr, dis, uH, bp, out, vsum, N);
        k_final<<<1, 1, 0, stream>>>(vsum, bv, out + N, N);
    }
}